// Round 11
// baseline (1453.115 us; speedup 1.0000x reference)
//
#include <hip/hip_runtime.h>

typedef unsigned short u16;
typedef unsigned int   u32;
typedef short s8v __attribute__((ext_vector_type(8)));   // 8 x bf16 MFMA operand
typedef float f4v __attribute__((ext_vector_type(4)));   // MFMA accumulator

#define DEV __device__ __forceinline__

DEV u16 f2b(float f){
  u32 x = __builtin_bit_cast(u32, f);
  u32 r = x + 0x7fffu + ((x >> 16) & 1u);
  return (u16)(r >> 16);
}
DEV float b2f(u16 u){ u32 x = ((u32)u) << 16; return __builtin_bit_cast(float, x); }
DEV f4v mfma16(s8v a, s8v b, f4v c){ return __builtin_amdgcn_mfma_f32_16x16x32_bf16(a, b, c, 0, 0, 0); }

DEV void segrange(const int* __restrict__ im, int P, int b, int& s0, int& s1){
  int lo = 0, hi = P;
  while (lo < hi){ int m = (lo + hi) >> 1; if (im[m] < b) lo = m + 1; else hi = m; }
  s0 = lo;
  int lo2 = lo; hi = P;
  while (lo2 < hi){ int m = (lo2 + hi) >> 1; if (im[m] < b + 1) lo2 = m + 1; else hi = m; }
  s1 = lo2;
}

DEV void transpose_body(const float* __restrict__ src, u16* __restrict__ dst,
                        int R, int C, int rb, int cb, int t, float* tile){
  int r0 = rb << 6, c0 = cb << 6;
  for (int i = t; i < 4096; i += 256){
    int rl = i >> 6, cl = i & 63;
    tile[rl*65 + cl] = src[(size_t)(r0 + rl)*C + c0 + cl];
  }
  __syncthreads();
  for (int i = t; i < 4096; i += 256){
    int cl = i >> 6, rl = i & 63;
    dst[(size_t)(c0 + cl)*R + r0 + rl] = f2b(tile[rl*65 + cl]);
  }
}

// ============ k_misc: featpool FIRST, then weight transforms ============
// w2f = conv2 weights in MFMA-FRAGMENT-PACKED layout:
//   frag = (tap*16 + og)*4 + kst  (og = oc>>4); element = lane*8 + j
//   value = w_c2[(oc*128 + k)*9 + tap], oc = og*16 + (lane&15), k = kst*32 + (lane>>4)*8 + j
// => a wave's B-load is ONE contiguous 1KB transaction (R9's 16B/256B-stride scatter killed L2).
__global__ __launch_bounds__(256) void k_misc(
    const float* __restrict__ feat, const int* __restrict__ pidx, const int* __restrict__ im_idx,
    const float* __restrict__ w_c1, const float* __restrict__ w_c2, const float* __restrict__ w_u,
    const float* __restrict__ w_vr, const float* __restrict__ w_m1,
    const float* __restrict__ w_subj, const float* __restrict__ w_obj,
    u16* __restrict__ w1tp, u16* __restrict__ w2f, u16* __restrict__ wuT,
    u16* __restrict__ wvrT, u16* __restrict__ wm1T, u16* __restrict__ wsoT,
    u16* __restrict__ pfbf, int P){
  __shared__ float smem[4160];
  int bid = blockIdx.x, t = threadIdx.x;
  if (bid < 200){
    int i = bid; int s = i/100, b = i - s*100;
    int s0, s1; segrange(im_idx, P, b, s0, s1);
    float inv = 1.f / fmaxf((float)(s1 - s0), 1.f);
    f4v a0 = {}, a1 = {};
    for (int p = s0; p < s1; ++p){
      int row = pidx[p*2 + s];
      const f4v* src = (const f4v*)(feat + (size_t)row*2048);
      a0 += src[t]; a1 += src[t+256];
    }
    u16* dst = pfbf + (size_t)(s*100 + b)*2048;
    #pragma unroll
    for (int j = 0; j < 4; ++j){
      dst[4*t + j]        = f2b(a0[j]*inv);
      dst[1024 + 4*t + j] = f2b(a1[j]*inv);
    }
  } else if (bid < 264){
    int i = (bid - 200)*256 + t;           // i = oc*128 + k', k' = ic*64 + ky*8 + kx
    int kp = i & 127;
    int kx = kp & 7, ky = (kp >> 3) & 7, ic = kp >> 6;
    int oc = i >> 7;
    w1tp[i] = f2b((kx < 7 && ky < 7) ? w_c1[oc*98 + ic*49 + ky*7 + kx] : 0.f);
  } else if (bid < 1416){
    int i = (bid - 264)*256 + t;           // fragment-packed conv2 weights
    int frag = i >> 9, r = i & 511;
    int lane = r >> 3, j = r & 7;
    int kst = frag & 3, og = (frag >> 2) & 15, tap = frag >> 6;
    int oc = og*16 + (lane & 15);
    int k  = kst*32 + (lane >> 4)*8 + j;
    w2f[i] = f2b(w_c2[((size_t)(oc*128 + k))*9 + tap]);
  } else if (bid < 2440){
    int i = (bid - 1416)*256 + t;
    wuT[i] = f2b(w_u[i]);
  } else if (bid < 4008){
    int idx = bid - 2440;                  // 196*8
    transpose_body(w_vr, wvrT, 12544, 512, idx >> 3, idx & 7, t, smem);
  } else if (bid < 4776){
    int idx = bid - 4008;                  // 24*32
    transpose_body(w_m1, wm1T, 1536, 2048, idx >> 5, idx & 31, t, smem);
  } else {
    int idx = bid - 4776;                  // 2 * 32*8
    int sel = idx >> 8; idx &= 255;
    transpose_body(sel ? w_obj : w_subj, wsoT + (size_t)sel*512*2048,
                   2048, 512, idx >> 3, idx & 7, t, smem);
  }
}

// ============ k_upool: union segment-mean -> muT[b][49][1024] bf16 (HBM-bound) ============
__global__ __launch_bounds__(256) void k_upool(const float* __restrict__ uf, const int* __restrict__ im_idx,
                                               u16* __restrict__ muT, int P){
  __shared__ float smem[3136];
  int b = blockIdx.x, icb = blockIdx.y, t = threadIdx.x;
  int s0, s1; segrange(im_idx, P, b, s0, s1);
  float inv = 1.f / fmaxf((float)(s1 - s0), 1.f);
  f4v a0 = {}, a1 = {}, a2 = {}, a3 = {};
  int p = s0;
  for (; p + 1 < s1; p += 2){
    const f4v* x = (const f4v*)(uf + (size_t)p*50176 + icb*3136);
    const f4v* y = (const f4v*)(uf + (size_t)(p+1)*50176 + icb*3136);
    a0 += x[t] + y[t]; a1 += x[t+256] + y[t+256]; a2 += x[t+512] + y[t+512];
    if (t < 16) a3 += x[t+768] + y[t+768];
  }
  if (p < s1){
    const f4v* x = (const f4v*)(uf + (size_t)p*50176 + icb*3136);
    a0 += x[t]; a1 += x[t+256]; a2 += x[t+512];
    if (t < 16) a3 += x[t+768];
  }
  *(f4v*)&smem[4*t] = a0;
  *(f4v*)&smem[4*(t+256)] = a1;
  *(f4v*)&smem[4*(t+512)] = a2;
  if (t < 16) *(f4v*)&smem[4*(t+768)] = a3;
  __syncthreads();
  for (int o = t; o < 3136; o += 256){
    int pix = o >> 6, ics = o & 63;
    muT[(size_t)(b*49 + pix)*1024 + (icb<<6) + ics] = f2b(smem[ics*49 + pix]*inv);
  }
}

// ============ conv1 v2 (7x7 s2 p3, 2->128): weight-permuted direct-LDS-read MFMA ============
__global__ __launch_bounds__(256) void k_conv1(const float* __restrict__ masks, const u16* __restrict__ w1tp,
                                               const float* __restrict__ b1,
                                               float* __restrict__ stats1, u16* __restrict__ spool){
  __shared__ u32 lds32[1400];              // in_bf: 2 ch x 680 u32 (+40 slack for ky=7/pad reads)
  __shared__ u16 s1n[64*196];              // this block's 64 oc, post-relu PRE-BN
  int p = blockIdx.x, z = blockIdx.y, t = threadIdx.x;
  int lane = t & 63, w = t >> 6;
  int l15 = lane & 15, lhi = lane >> 4;
  int ocl = w*16 + l15;
  int oc  = z*64 + ocl;
  s8v Bf[4];
  #pragma unroll
  for (int kst = 0; kst < 4; ++kst)
    Bf[kst] = *(const s8v*)&w1tp[(size_t)oc*128 + kst*32 + lhi*8];
  for (int i = t; i < 1400; i += 256) lds32[i] = 0;
  __syncthreads();
  u16* in_bf = (u16*)lds32;
  for (int e = t; e < 1458; e += 256){
    int c = e >= 729; int r = e - c*729;
    int rr = r/27, cc = r - rr*27;
    in_bf[c*1360 + (rr + 3)*40 + cc + 3] = f2b(masks[(size_t)p*1458 + e]);
  }
  int rb[13];
  #pragma unroll
  for (int mt = 0; mt < 13; ++mt){
    int pix = mt*16 + l15;
    int oy = pix/14, ox = pix - oy*14;
    rb[mt] = oy*40 + ox;
  }
  __syncthreads();
  f4v acc[13] = {};
  #pragma unroll
  for (int kst = 0; kst < 4; ++kst){
    int kk = kst*32 + lhi*8;
    int kbase = (kk >> 6)*680 + ((kk >> 3) & 7)*20;
    #pragma unroll
    for (int mt = 0; mt < 13; ++mt){
      int a = kbase + rb[mt];
      union { u32 u[4]; s8v v; } cv;
      cv.u[0] = lds32[a];   cv.u[1] = lds32[a+1];
      cv.u[2] = lds32[a+2]; cv.u[3] = lds32[a+3];
      acc[mt] = mfma16(cv.v, Bf[kst], acc[mt]);
    }
  }
  float bias = b1[oc];
  float ss = 0.f, qq = 0.f;
  #pragma unroll
  for (int mt = 0; mt < 13; ++mt)
    #pragma unroll
    for (int v = 0; v < 4; ++v){
      int pix = mt*16 + lhi*4 + v;
      if (pix < 196){
        float r = fmaxf(acc[mt][v] + bias, 0.f);
        ss += r; qq += r*r;
        s1n[ocl*196 + pix] = f2b(r);
      }
    }
  ss += __shfl_xor(ss, 16); ss += __shfl_xor(ss, 32);
  qq += __shfl_xor(qq, 16); qq += __shfl_xor(qq, 32);
  if (lane < 16){
    atomicAdd(&stats1[z*64 + w*16 + lane], ss);
    atomicAdd(&stats1[128 + z*64 + w*16 + lane], qq);
  }
  __syncthreads();
  {
    int ocp = t & 63, pg = t >> 6;
    const u32* row32 = (const u32*)s1n;
    for (int pp = pg; pp < 49; pp += 4){
      int poy = pp/7, pox = pp - poy*7;
      u32 m = 0;
      #pragma unroll
      for (int dy = 0; dy < 3; ++dy){
        int iy = poy*2 - 1 + dy;
        if (iy < 0 || iy > 13) continue;
        int widx = ocp*98 + iy*7 + pox;
        u32 wB = row32[widx];
        u32 c1 = wB & 0xffffu, c2 = wB >> 16;
        m = c1 > m ? c1 : m;
        m = c2 > m ? c2 : m;
        if (pox > 0){
          u32 c0 = row32[widx - 1] >> 16;
          m = c0 > m ? c0 : m;
        }
      }
      spool[((size_t)p*49 + pp)*128 + z*64 + ocp] = (u16)m;
    }
  }
}

// ============ conv2 v5 (3x3 s1 p1, 128->256): R9 structure + fragment-packed B (coalesced L2) ============
// Single-pair M (conflict-free inT), 4 waves x 64 oc (nt=4: A-read reused 4x), 23KB LDS, 2 blocks/CU.
// B-loads: one contiguous 1KB wave-transaction per (tap,og,kst) -> 2.95GB streams from L2 @full lines.
__global__ __launch_bounds__(256) void k_conv2(const u16* __restrict__ spool, const u16* __restrict__ w2f,
                                               const float* __restrict__ b2,
                                               const float* __restrict__ g1, const float* __restrict__ be1,
                                               const float* __restrict__ stats1, const int* __restrict__ im_idx,
                                               float* __restrict__ segr, float* __restrict__ stats2,
                                               int P, float invN1){
  __shared__ u16 inT[82*136];              // 81 = 9x9 padded grid, row 81 = zero (M-pad); halo zero
  __shared__ float sc1[128], sh1[128];
  int b = blockIdx.x, q = blockIdx.y, t = threadIdx.x;
  int lane = t & 63, w = t >> 6;
  int l15 = lane & 15, lhi = lane >> 4;
  {
    f4v z = {}; f4v* a4 = (f4v*)inT;
    for (int i = t; i < 1394; i += 256) a4[i] = z;
  }
  if (t < 128){                            // folded bnfin1
    float mean = stats1[t]*invN1;
    float var  = stats1[128 + t]*invN1 - mean*mean;
    float sc = g1[t]*rsqrtf(var + 1e-5f);
    sc1[t] = sc; sh1[t] = be1[t] - mean*sc;
  }
  int s0, s1; segrange(im_idx, P, b, s0, s1);
  int cnt = s1 - s0, chunk = (cnt + 4)/5;
  int p0 = s0 + q*chunk, p1 = min(p0 + chunk, s1);
  int ocb4 = w*4;                          // og base for this wave (4 groups of 16 oc)
  int rowm[4]; bool okm[4];
  #pragma unroll
  for (int mt = 0; mt < 4; ++mt){
    int pix = mt*16 + l15;
    okm[mt] = pix < 49;
    int py = pix/7, px = pix - py*7;
    rowm[mt] = okm[mt] ? (py + 1)*9 + px + 1 : 81;
  }
  float bias[4];
  #pragma unroll
  for (int nt = 0; nt < 4; ++nt) bias[nt] = b2[w*64 + nt*16 + l15];
  f4v segacc[4][4] = {};
  float ssum[4] = {0,0,0,0}, ssq[4] = {0,0,0,0};
  for (int p = p0; p < p1; ++p){
    __syncthreads();
    for (int i = t; i < 3136; i += 256){   // stage pair p with BN1 applied
      u32 v = ((const u32*)(spool + (size_t)p*6272))[i];
      int pix = i >> 6, icp = i & 63;
      float lo = b2f((u16)v)*sc1[icp*2]     + sh1[icp*2];
      float hi = b2f((u16)(v >> 16))*sc1[icp*2 + 1] + sh1[icp*2 + 1];
      int py = pix/7, px = pix - py*7;
      ((u32*)inT)[((py + 1)*9 + px + 1)*68 + icp] = (u32)f2b(lo) | ((u32)f2b(hi) << 16);
    }
    __syncthreads();
    f4v pacc[4][4] = {};
    #pragma unroll
    for (int tap = 0; tap < 9; ++tap){
      int doff = (tap/3 - 1)*9 + (tap%3 - 1);
      int ro[4];
      #pragma unroll
      for (int mt = 0; mt < 4; ++mt)
        ro[mt] = (okm[mt] ? rowm[mt] + doff : 81)*136;
      #pragma unroll
      for (int kst = 0; kst < 4; ++kst){
        s8v Bf[4];
        #pragma unroll
        for (int nt = 0; nt < 4; ++nt)
          Bf[nt] = *(const s8v*)&w2f[((((size_t)tap*16 + ocb4 + nt)*4 + kst) << 9) + lane*8];
        int koff = kst*32 + lhi*8;
        #pragma unroll
        for (int mt = 0; mt < 4; ++mt){
          s8v A = *(const s8v*)&inT[ro[mt] + koff];
          #pragma unroll
          for (int nt = 0; nt < 4; ++nt)
            pacc[mt][nt] = mfma16(A, Bf[nt], pacc[mt][nt]);
        }
      }
    }
    #pragma unroll
    for (int nt = 0; nt < 4; ++nt)
      #pragma unroll
      for (int mt = 0; mt < 4; ++mt)
        #pragma unroll
        for (int v = 0; v < 4; ++v){
          int pix = mt*16 + lhi*4 + v;
          float r = fmaxf(pacc[mt][nt][v] + bias[nt], 0.f);
          r = (pix < 49) ? r : 0.f;
          segacc[mt][nt][v] += r;
          ssum[nt] += r; ssq[nt] += r*r;
        }
  }
  #pragma unroll
  for (int nt = 0; nt < 4; ++nt){
    int oc = w*64 + nt*16 + l15;
    #pragma unroll
    for (int mt = 0; mt < 4; ++mt)
      #pragma unroll
      for (int v = 0; v < 4; ++v){
        int pix = mt*16 + lhi*4 + v;
        if (pix < 49)
          atomicAdd(&segr[(size_t)(b*256 + oc)*49 + pix], segacc[mt][nt][v]);
      }
    float s = ssum[nt], qd = ssq[nt];
    s  += __shfl_xor(s, 16);  s  += __shfl_xor(s, 32);
    qd += __shfl_xor(qd, 16); qd += __shfl_xor(qd, 32);
    if (lane < 16){
      atomicAdd(&stats2[w*64 + nt*16 + lane], s);
      atomicAdd(&stats2[256 + w*64 + nt*16 + lane], qd);
    }
  }
}

// ============ combine: union 1x1 conv + bn2(seg-mean relu2) -> tbf ============
__global__ __launch_bounds__(256) void k_combine(const u16* __restrict__ muT, const u16* __restrict__ wuT,
                                                 const float* __restrict__ b_u, const float* __restrict__ segr,
                                                 const float* __restrict__ stats2,
                                                 const float* __restrict__ g2, const float* __restrict__ be2,
                                                 const int* __restrict__ im_idx, u16* __restrict__ tbf,
                                                 int P, float invN2){
  __shared__ float sc2[256], sh2[256];
  int b = blockIdx.x, t = threadIdx.x;
  int lane = t & 63, w = t >> 6;
  int l15 = lane & 15, lhi = lane >> 4;
  {
    float mean = stats2[t]*invN2;
    float var  = stats2[256 + t]*invN2 - mean*mean;
    float sc = g2[t]*rsqrtf(var + 1e-5f);
    sc2[t] = sc; sh2[t] = be2[t] - mean*sc;
  }
  __syncthreads();
  int s0, s1; segrange(im_idx, P, b, s0, s1);
  float inv = 1.f / fmaxf((float)(s1 - s0), 1.f);
  int ocb = w*64;
  const u16* arow[4];
  #pragma unroll
  for (int mt = 0; mt < 4; ++mt){
    int pix = mt*16 + l15;
    arow[mt] = muT + (size_t)(b*49 + (pix < 49 ? pix : 0))*1024;
  }
  f4v acc[4][4] = {};
  for (int kst = 0; kst < 32; ++kst){
    int koff = kst*32 + lhi*8;
    s8v Bf[4];
    #pragma unroll
    for (int nt = 0; nt < 4; ++nt)
      Bf[nt] = *(const s8v*)&wuT[(ocb + nt*16 + l15)*1024 + koff];
    #pragma unroll
    for (int mt = 0; mt < 4; ++mt){
      s8v A = *(const s8v*)&arow[mt][koff];
      #pragma unroll
      for (int nt = 0; nt < 4; ++nt)
        acc[mt][nt] = mfma16(A, Bf[nt], acc[mt][nt]);
    }
  }
  #pragma unroll
  for (int nt = 0; nt < 4; ++nt){
    int oc = ocb + nt*16 + l15;
    float bu = b_u[oc], sc = sc2[oc], sh = sh2[oc];
    #pragma unroll
    for (int mt = 0; mt < 4; ++mt)
      #pragma unroll
      for (int v = 0; v < 4; ++v){
        int pix = mt*16 + lhi*4 + v;
        if (pix < 49){
          float val = acc[mt][nt][v] + bu + sc*segr[(size_t)(b*256 + oc)*49 + pix]*inv + sh;
          tbf[(size_t)b*12544 + oc*49 + pix] = f2b(val);
        }
      }
  }
}

// ============ mega3: vr GEMM (56 blocks) UNION subj/obj GEMM (16 blocks) ============
__global__ __launch_bounds__(256) void k_mega3(const u16* __restrict__ tbf, const u16* __restrict__ wvrT,
                                               const float* __restrict__ b_vr,
                                               const u16* __restrict__ pfbf, const u16* __restrict__ wsoT,
                                               const float* __restrict__ b_subj, const float* __restrict__ b_obj,
                                               float* __restrict__ px, int B){
  int bid = blockIdx.x, t = threadIdx.x;
  int lane = t & 63, w = t >> 6;
  int l15 = lane & 15, lhi = lane >> 4;
  if (bid < 56){
    int nb = bid & 1, kc = bid >> 1;
    int colb = nb*256 + w*64;
    int k0 = kc*448;
    f4v acc[7][4] = {};
    for (int kst = 0; kst < 14; ++kst){
      int koff = k0 + kst*32 + lhi*8;
      s8v Bf[4];
      #pragma unroll
      for (int nt = 0; nt < 4; ++nt)
        Bf[nt] = *(const s8v*)&wvrT[(size_t)(colb + nt*16 + l15)*12544 + koff];
      #pragma unroll
      for (int mt = 0; mt < 7; ++mt){
        s8v A = *(const s8v*)&tbf[(size_t)(mt*16 + l15)*12544 + koff];
        #pragma unroll
        for (int nt = 0; nt < 4; ++nt)
          acc[mt][nt] = mfma16(A, Bf[nt], acc[mt][nt]);
      }
    }
    #pragma unroll
    for (int nt = 0; nt < 4; ++nt){
      int col = colb + nt*16 + l15;
      float bias = (kc == 0) ? b_vr[col] : 0.f;
      #pragma unroll
      for (int mt = 0; mt < 7; ++mt)
        #pragma unroll
        for (int v = 0; v < 4; ++v){
          int row = mt*16 + lhi*4 + v;
          if (row < B) atomicAdd(&px[row*1536 + 1024 + col], acc[mt][nt][v] + bias);
        }
    }
  } else {
    int r = bid - 56;
    int nb = r & 1, s = (r >> 1) & 1, kc = r >> 2;
    int colb = nb*256 + w*64;
    int k0 = kc*512;
    const float* bi = s ? b_obj : b_subj;
    f4v acc[7][4] = {};
    for (int kst = 0; kst < 16; ++kst){
      int koff = k0 + kst*32 + lhi*8;
      s8v Bf[4];
      #pragma unroll
      for (int nt = 0; nt < 4; ++nt)
        Bf[nt] = *(const s8v*)&wsoT[(size_t)(s*512 + colb + nt*16 + l15)*2048 + koff];
      #pragma unroll
      for (int mt = 0; mt < 7; ++mt){
        int row = mt*16 + l15; row = row < B ? row : 0;
        s8v A = *(const s8v*)&pfbf[(size_t)(s*100 + row)*2048 + koff];
        #pragma unroll
        for (int nt = 0; nt < 4; ++nt)
          acc[mt][nt] = mfma16(A, Bf[nt], acc[mt][nt]);
      }
    }
    #pragma unroll
    for (int nt = 0; nt < 4; ++nt){
      int col = colb + nt*16 + l15;
      float bias = (kc == 0) ? bi[col] : 0.f;
      #pragma unroll
      for (int mt = 0; mt < 7; ++mt)
        #pragma unroll
        for (int v = 0; v < 4; ++v){
          int row = mt*16 + lhi*4 + v;
          if (row < B) atomicAdd(&px[row*1536 + s*512 + col], acc[mt][nt][v] + bias);
        }
    }
  }
}

// ============ MLP m1: [112,1536]@[1536,2048], k-split atomics, f32 A inline-cast ============
__global__ __launch_bounds__(256) void k_m1(const float* __restrict__ px, const u16* __restrict__ wm1T,
                                            float* __restrict__ h, int B){
  int nb = blockIdx.x, kc = blockIdx.y, t = threadIdx.x;
  int lane = t & 63, w = t >> 6;
  int l15 = lane & 15, lhi = lane >> 4;
  int colb = nb*256 + w*64;
  int k0 = kc*384;
  f4v acc[7][4] = {};
  for (int kst = 0; kst < 12; ++kst){
    int koff = k0 + kst*32 + lhi*8;
    s8v Bf[4];
    #pragma unroll
    for (int nt = 0; nt < 4; ++nt)
      Bf[nt] = *(const s8v*)&wm1T[(size_t)(colb + nt*16 + l15)*1536 + koff];
    #pragma unroll
    for (int mt = 0; mt < 7; ++mt){
      const float* ap = px + (size_t)(mt*16 + l15)*1536 + koff;
      f4v lo = *(const f4v*)ap;
      f4v hi = *(const f4v*)(ap + 4);
      s8v A;
      A[0] = (short)f2b(lo[0]); A[1] = (short)f2b(lo[1]);
      A[2] = (short)f2b(lo[2]); A[3] = (short)f2b(lo[3]);
      A[4] = (short)f2b(hi[0]); A[5] = (short)f2b(hi[1]);
      A[6] = (short)f2b(hi[2]); A[7] = (short)f2b(hi[3]);
      #pragma unroll
      for (int nt = 0; nt < 4; ++nt)
        acc[mt][nt] = mfma16(A, Bf[nt], acc[mt][nt]);
    }
  }
  #pragma unroll
  for (int nt = 0; nt < 4; ++nt){
    int col = colb + nt*16 + l15;
    #pragma unroll
    for (int mt = 0; mt < 7; ++mt)
      #pragma unroll
      for (int v = 0; v < 4; ++v){
        int row = mt*16 + lhi*4 + v;
        if (row < B) atomicAdd(&h[row*2048 + col], acc[mt][nt][v]);
      }
  }
}

// ============ m2 + bias1/relu + sigmoid, in-block k-split x2 ============
__global__ __launch_bounds__(512) void k_m2(const float* __restrict__ h, const float* __restrict__ bm1,
                                            const float* __restrict__ w_m2, const float* __restrict__ b_m2,
                                            float* __restrict__ out){
  __shared__ float part[160];
  int b = blockIdx.x, t = threadIdx.x;
  int col = t & 255, kg = t >> 8;
  float acc = 0.f;
  if (col < 157){
    const float* hb = h + (size_t)b*2048;
    int k0 = kg*1024;
    for (int k = k0; k < k0 + 1024; ++k)
      acc += fmaxf(hb[k] + bm1[k], 0.f) * w_m2[(size_t)k*157 + col];
  }
  if (kg == 1 && col < 157) part[col] = acc;
  __syncthreads();
  if (kg == 0 && col < 157){
    float s = acc + part[col] + b_m2[col];
    out[b*157 + col] = 1.f/(1.f + expf(-s));
  }
}

extern "C" void kernel_launch(void* const* d_in, const int* in_sizes, int n_in,
                              void* d_out, int out_size, void* d_ws, size_t ws_size,
                              hipStream_t stream){
  const float* features   = (const float*)d_in[0];
  const float* union_feat = (const float*)d_in[1];
  const float* masks      = (const float*)d_in[2];
  const float* w_union    = (const float*)d_in[3];
  const float* b_union    = (const float*)d_in[4];
  const float* w_c1       = (const float*)d_in[5];
  const float* b_c1       = (const float*)d_in[6];
  const float* g_bn1      = (const float*)d_in[7];
  const float* be_bn1     = (const float*)d_in[8];
  const float* w_c2       = (const float*)d_in[9];
  const float* b_c2       = (const float*)d_in[10];
  const float* g_bn2      = (const float*)d_in[11];
  const float* be_bn2     = (const float*)d_in[12];
  const float* w_subj     = (const float*)d_in[13];
  const float* b_subj     = (const float*)d_in[14];
  const float* w_obj      = (const float*)d_in[15];
  const float* b_obj      = (const float*)d_in[16];
  const float* w_vr       = (const float*)d_in[17];
  const float* b_vr       = (const float*)d_in[18];
  const float* w_m1       = (const float*)d_in[19];
  const float* b_m1       = (const float*)d_in[20];
  const float* w_m2       = (const float*)d_in[21];
  const float* b_m2       = (const float*)d_in[22];
  const int* pair_idx     = (const int*)d_in[23];
  const int* im_idx       = (const int*)d_in[24];
  float* out = (float*)d_out;
  const int P = in_sizes[24];
  const int B = out_size/157;

  char* ws = (char*)d_ws;
  size_t off = 0;
  auto alloc = [&](size_t bytes)->size_t{ size_t o = off; off += (bytes + 255) & ~(size_t)255; return o; };
  // zero-region (one memset): stats | segr | px | h
  size_t o_stats= alloc(3072);
  size_t o_segr = alloc((size_t)B*256*49*4);
  size_t o_px   = alloc((size_t)112*1536*4);
  size_t o_h    = alloc((size_t)B*2048*4);
  size_t zero_end = off;
  size_t o_muT  = alloc((size_t)B*49*1024*2);
  size_t o_spool= alloc((size_t)P*49*128*2);
  size_t o_w1t  = alloc(128*128*2);
  size_t o_w2f  = alloc(9*256*128*2);
  size_t o_wuT  = alloc(256*1024*2);
  size_t o_wvrT = alloc((size_t)512*12544*2);
  size_t o_wm1T = alloc((size_t)2048*1536*2);
  size_t o_wsoT = alloc((size_t)1024*2048*2);
  size_t o_pfbf = alloc((size_t)200*2048*2);
  size_t o_tbf  = alloc((size_t)112*12544*2);
  (void)ws_size; (void)n_in;

  float* stats1 = (float*)(ws + o_stats);
  float* stats2 = stats1 + 256;
  u16*   muT    = (u16*)(ws + o_muT);
  u16*   spool  = (u16*)(ws + o_spool);
  u16*   w1tp   = (u16*)(ws + o_w1t);
  u16*   w2f    = (u16*)(ws + o_w2f);
  u16*   wuT    = (u16*)(ws + o_wuT);
  u16*   wvrT   = (u16*)(ws + o_wvrT);
  u16*   wm1T   = (u16*)(ws + o_wm1T);
  u16*   wsoT   = (u16*)(ws + o_wsoT);
  u16*   pfbf   = (u16*)(ws + o_pfbf);
  float* segr   = (float*)(ws + o_segr);
  u16*   tbf    = (u16*)(ws + o_tbf);
  float* px     = (float*)(ws + o_px);
  float* h      = (float*)(ws + o_h);

  hipMemsetAsync(ws, 0, zero_end, stream);

  k_misc<<<5288, dim3(256), 0, stream>>>(features, pair_idx, im_idx, w_c1, w_c2, w_union,
                                         w_vr, w_m1, w_subj, w_obj,
                                         w1tp, w2f, wuT, wvrT, wm1T, wsoT, pfbf, P);
  k_upool<<<dim3(B, 16), dim3(256), 0, stream>>>(union_feat, im_idx, muT, P);
  k_conv1<<<dim3(P, 2), dim3(256), 0, stream>>>(masks, w1tp, b_c1, stats1, spool);
  k_conv2<<<dim3(B, 5), dim3(256), 0, stream>>>(spool, w2f, b_c2, g_bn1, be_bn1, stats1, im_idx,
                                                segr, stats2, P, 1.f/((float)P*196.f));
  k_combine<<<B, dim3(256), 0, stream>>>(muT, wuT, b_union, segr, stats2, g_bn2, be_bn2, im_idx,
                                         tbf, P, 1.f/((float)P*49.f));
  k_mega3<<<72, dim3(256), 0, stream>>>(tbf, wvrT, b_vr, pfbf, wsoT, b_subj, b_obj, px, B);
  k_m1<<<dim3(8, 4), dim3(256), 0, stream>>>(px, wm1T, h, B);
  k_m2<<<B, dim3(512), 0, stream>>>(h, b_m1, w_m2, b_m2, out);
}

// Round 12
// 1336.379 us; speedup vs baseline: 1.0874x; 1.0874x over previous
//
#include <hip/hip_runtime.h>

typedef unsigned short u16;
typedef unsigned int   u32;
typedef short s8v __attribute__((ext_vector_type(8)));   // 8 x bf16 MFMA operand
typedef float f4v __attribute__((ext_vector_type(4)));   // MFMA accumulator

#define DEV __device__ __forceinline__

DEV u16 f2b(float f){
  u32 x = __builtin_bit_cast(u32, f);
  u32 r = x + 0x7fffu + ((x >> 16) & 1u);
  return (u16)(r >> 16);
}
DEV float b2f(u16 u){ u32 x = ((u32)u) << 16; return __builtin_bit_cast(float, x); }
DEV f4v mfma16(s8v a, s8v b, f4v c){ return __builtin_amdgcn_mfma_f32_16x16x32_bf16(a, b, c, 0, 0, 0); }

DEV void segrange(const int* __restrict__ im, int P, int b, int& s0, int& s1){
  int lo = 0, hi = P;
  while (lo < hi){ int m = (lo + hi) >> 1; if (im[m] < b) lo = m + 1; else hi = m; }
  s0 = lo;
  int lo2 = lo; hi = P;
  while (lo2 < hi){ int m = (lo2 + hi) >> 1; if (im[m] < b + 1) lo2 = m + 1; else hi = m; }
  s1 = lo2;
}

DEV void transpose_body(const float* __restrict__ src, u16* __restrict__ dst,
                        int R, int C, int rb, int cb, int t, float* tile){
  int r0 = rb << 6, c0 = cb << 6;
  for (int i = t; i < 4096; i += 256){
    int rl = i >> 6, cl = i & 63;
    tile[rl*65 + cl] = src[(size_t)(r0 + rl)*C + c0 + cl];
  }
  __syncthreads();
  for (int i = t; i < 4096; i += 256){
    int cl = i >> 6, rl = i & 63;
    dst[(size_t)(c0 + cl)*R + r0 + rl] = f2b(tile[rl*65 + cl]);
  }
}

// ============ k_misc: featpool FIRST, then weight transforms ============
// w2f = conv2 weights fragment-packed: frag=(tap*16+og)*4+kst, element=lane*8+j,
// value = w_c2[(oc*128+k)*9+tap], oc=og*16+(lane&15), k=kst*32+(lane>>4)*8+j.
__global__ __launch_bounds__(256) void k_misc(
    const float* __restrict__ feat, const int* __restrict__ pidx, const int* __restrict__ im_idx,
    const float* __restrict__ w_c1, const float* __restrict__ w_c2, const float* __restrict__ w_u,
    const float* __restrict__ w_vr, const float* __restrict__ w_m1,
    const float* __restrict__ w_subj, const float* __restrict__ w_obj,
    u16* __restrict__ w1tp, u16* __restrict__ w2f, u16* __restrict__ wuT,
    u16* __restrict__ wvrT, u16* __restrict__ wm1T, u16* __restrict__ wsoT,
    u16* __restrict__ pfbf, int P){
  __shared__ float smem[4160];
  int bid = blockIdx.x, t = threadIdx.x;
  if (bid < 200){
    int i = bid; int s = i/100, b = i - s*100;
    int s0, s1; segrange(im_idx, P, b, s0, s1);
    float inv = 1.f / fmaxf((float)(s1 - s0), 1.f);
    f4v a0 = {}, a1 = {};
    for (int p = s0; p < s1; ++p){
      int row = pidx[p*2 + s];
      const f4v* src = (const f4v*)(feat + (size_t)row*2048);
      a0 += src[t]; a1 += src[t+256];
    }
    u16* dst = pfbf + (size_t)(s*100 + b)*2048;
    #pragma unroll
    for (int j = 0; j < 4; ++j){
      dst[4*t + j]        = f2b(a0[j]*inv);
      dst[1024 + 4*t + j] = f2b(a1[j]*inv);
    }
  } else if (bid < 264){
    int i = (bid - 200)*256 + t;           // i = oc*128 + k', k' = ic*64 + ky*8 + kx
    int kp = i & 127;
    int kx = kp & 7, ky = (kp >> 3) & 7, ic = kp >> 6;
    int oc = i >> 7;
    w1tp[i] = f2b((kx < 7 && ky < 7) ? w_c1[oc*98 + ic*49 + ky*7 + kx] : 0.f);
  } else if (bid < 1416){
    int i = (bid - 264)*256 + t;           // fragment-packed conv2 weights
    int frag = i >> 9, r = i & 511;
    int lane = r >> 3, j = r & 7;
    int kst = frag & 3, og = (frag >> 2) & 15, tap = frag >> 6;
    int oc = og*16 + (lane & 15);
    int k  = kst*32 + (lane >> 4)*8 + j;
    w2f[i] = f2b(w_c2[((size_t)(oc*128 + k))*9 + tap]);
  } else if (bid < 2440){
    int i = (bid - 1416)*256 + t;
    wuT[i] = f2b(w_u[i]);
  } else if (bid < 4008){
    int idx = bid - 2440;                  // 196*8
    transpose_body(w_vr, wvrT, 12544, 512, idx >> 3, idx & 7, t, smem);
  } else if (bid < 4776){
    int idx = bid - 4008;                  // 24*32
    transpose_body(w_m1, wm1T, 1536, 2048, idx >> 5, idx & 31, t, smem);
  } else {
    int idx = bid - 4776;                  // 2 * 32*8
    int sel = idx >> 8; idx &= 255;
    transpose_body(sel ? w_obj : w_subj, wsoT + (size_t)sel*512*2048,
                   2048, 512, idx >> 3, idx & 7, t, smem);
  }
}

// ============ k_upool: union segment-mean -> muT[b][49][1024] bf16 (HBM-bound) ============
__global__ __launch_bounds__(256) void k_upool(const float* __restrict__ uf, const int* __restrict__ im_idx,
                                               u16* __restrict__ muT, int P){
  __shared__ float smem[3136];
  int b = blockIdx.x, icb = blockIdx.y, t = threadIdx.x;
  int s0, s1; segrange(im_idx, P, b, s0, s1);
  float inv = 1.f / fmaxf((float)(s1 - s0), 1.f);
  f4v a0 = {}, a1 = {}, a2 = {}, a3 = {};
  int p = s0;
  for (; p + 1 < s1; p += 2){
    const f4v* x = (const f4v*)(uf + (size_t)p*50176 + icb*3136);
    const f4v* y = (const f4v*)(uf + (size_t)(p+1)*50176 + icb*3136);
    a0 += x[t] + y[t]; a1 += x[t+256] + y[t+256]; a2 += x[t+512] + y[t+512];
    if (t < 16) a3 += x[t+768] + y[t+768];
  }
  if (p < s1){
    const f4v* x = (const f4v*)(uf + (size_t)p*50176 + icb*3136);
    a0 += x[t]; a1 += x[t+256]; a2 += x[t+512];
    if (t < 16) a3 += x[t+768];
  }
  *(f4v*)&smem[4*t] = a0;
  *(f4v*)&smem[4*(t+256)] = a1;
  *(f4v*)&smem[4*(t+512)] = a2;
  if (t < 16) *(f4v*)&smem[4*(t+768)] = a3;
  __syncthreads();
  for (int o = t; o < 3136; o += 256){
    int pix = o >> 6, ics = o & 63;
    muT[(size_t)(b*49 + pix)*1024 + (icb<<6) + ics] = f2b(smem[ics*49 + pix]*inv);
  }
}

// ============ conv1 v2 (7x7 s2 p3, 2->128): weight-permuted direct-LDS-read MFMA ============
__global__ __launch_bounds__(256) void k_conv1(const float* __restrict__ masks, const u16* __restrict__ w1tp,
                                               const float* __restrict__ b1,
                                               float* __restrict__ stats1, u16* __restrict__ spool){
  __shared__ u32 lds32[1400];              // in_bf: 2 ch x 680 u32 (+40 slack for ky=7/pad reads)
  __shared__ u16 s1n[64*196];              // this block's 64 oc, post-relu PRE-BN
  int p = blockIdx.x, z = blockIdx.y, t = threadIdx.x;
  int lane = t & 63, w = t >> 6;
  int l15 = lane & 15, lhi = lane >> 4;
  int ocl = w*16 + l15;
  int oc  = z*64 + ocl;
  s8v Bf[4];
  #pragma unroll
  for (int kst = 0; kst < 4; ++kst)
    Bf[kst] = *(const s8v*)&w1tp[(size_t)oc*128 + kst*32 + lhi*8];
  for (int i = t; i < 1400; i += 256) lds32[i] = 0;
  __syncthreads();
  u16* in_bf = (u16*)lds32;
  for (int e = t; e < 1458; e += 256){
    int c = e >= 729; int r = e - c*729;
    int rr = r/27, cc = r - rr*27;
    in_bf[c*1360 + (rr + 3)*40 + cc + 3] = f2b(masks[(size_t)p*1458 + e]);
  }
  int rb[13];
  #pragma unroll
  for (int mt = 0; mt < 13; ++mt){
    int pix = mt*16 + l15;
    int oy = pix/14, ox = pix - oy*14;
    rb[mt] = oy*40 + ox;
  }
  __syncthreads();
  f4v acc[13] = {};
  #pragma unroll
  for (int kst = 0; kst < 4; ++kst){
    int kk = kst*32 + lhi*8;
    int kbase = (kk >> 6)*680 + ((kk >> 3) & 7)*20;
    #pragma unroll
    for (int mt = 0; mt < 13; ++mt){
      int a = kbase + rb[mt];
      union { u32 u[4]; s8v v; } cv;
      cv.u[0] = lds32[a];   cv.u[1] = lds32[a+1];
      cv.u[2] = lds32[a+2]; cv.u[3] = lds32[a+3];
      acc[mt] = mfma16(cv.v, Bf[kst], acc[mt]);
    }
  }
  float bias = b1[oc];
  float ss = 0.f, qq = 0.f;
  #pragma unroll
  for (int mt = 0; mt < 13; ++mt)
    #pragma unroll
    for (int v = 0; v < 4; ++v){
      int pix = mt*16 + lhi*4 + v;
      if (pix < 196){
        float r = fmaxf(acc[mt][v] + bias, 0.f);
        ss += r; qq += r*r;
        s1n[ocl*196 + pix] = f2b(r);
      }
    }
  ss += __shfl_xor(ss, 16); ss += __shfl_xor(ss, 32);
  qq += __shfl_xor(qq, 16); qq += __shfl_xor(qq, 32);
  if (lane < 16){
    atomicAdd(&stats1[z*64 + w*16 + lane], ss);
    atomicAdd(&stats1[128 + z*64 + w*16 + lane], qq);
  }
  __syncthreads();
  {
    int ocp = t & 63, pg = t >> 6;
    const u32* row32 = (const u32*)s1n;
    for (int pp = pg; pp < 49; pp += 4){
      int poy = pp/7, pox = pp - poy*7;
      u32 m = 0;
      #pragma unroll
      for (int dy = 0; dy < 3; ++dy){
        int iy = poy*2 - 1 + dy;
        if (iy < 0 || iy > 13) continue;
        int widx = ocp*98 + iy*7 + pox;
        u32 wB = row32[widx];
        u32 c1 = wB & 0xffffu, c2 = wB >> 16;
        m = c1 > m ? c1 : m;
        m = c2 > m ? c2 : m;
        if (pox > 0){
          u32 c0 = row32[widx - 1] >> 16;
          m = c0 > m ? c0 : m;
        }
      }
      spool[((size_t)p*49 + pp)*128 + z*64 + ocp] = (u16)m;
    }
  }
}

// ============ conv2 v6 (3x3 s1 p1, 128->256): REGISTER-resident B (144 VGPR, no spill at 256 thr) ============
// 4 waves x 16 oc = 64 oc/block, grid z=4. B loaded ONCE per block (R10-proven FETCH kill, 155MB),
// single-pair conflict-free inT (R9/R11 structure). Inner loop: zero B-memory-traffic, A = ds_read_b128.
__global__ __launch_bounds__(256) void k_conv2(const u16* __restrict__ spool, const u16* __restrict__ w2f,
                                               const float* __restrict__ b2,
                                               const float* __restrict__ g1, const float* __restrict__ be1,
                                               const float* __restrict__ stats1, const int* __restrict__ im_idx,
                                               float* __restrict__ segr, float* __restrict__ stats2,
                                               int P, float invN1){
  __shared__ u16 inT[82*136];              // 81 = 9x9 padded grid, row 81 = zero (M-pad); halo zero
  __shared__ float sc1[128], sh1[128];
  int b = blockIdx.x, q = blockIdx.y, z = blockIdx.z, t = threadIdx.x;
  int lane = t & 63, w = t >> 6;
  int l15 = lane & 15, lhi = lane >> 4;
  int og = z*4 + w;                        // this wave's 16-oc group
  int oc = og*16 + l15;
  s8v Bf[9][4];                            // whole B panel for this wave: 144 VGPR, loaded once
  #pragma unroll
  for (int tap = 0; tap < 9; ++tap)
    #pragma unroll
    for (int kst = 0; kst < 4; ++kst)
      Bf[tap][kst] = *(const s8v*)&w2f[((((size_t)tap*16 + og)*4 + kst) << 9) + lane*8];
  {
    f4v zv = {}; f4v* a4 = (f4v*)inT;
    for (int i = t; i < 1394; i += 256) a4[i] = zv;
  }
  if (t < 128){                            // folded bnfin1
    float mean = stats1[t]*invN1;
    float var  = stats1[128 + t]*invN1 - mean*mean;
    float sc = g1[t]*rsqrtf(var + 1e-5f);
    sc1[t] = sc; sh1[t] = be1[t] - mean*sc;
  }
  int s0, s1; segrange(im_idx, P, b, s0, s1);
  int cnt = s1 - s0, chunk = (cnt + 4)/5;
  int p0 = s0 + q*chunk, p1 = min(p0 + chunk, s1);
  int rowm[4]; bool okm[4];
  #pragma unroll
  for (int mt = 0; mt < 4; ++mt){
    int pix = mt*16 + l15;
    okm[mt] = pix < 49;
    int py = pix/7, px = pix - py*7;
    rowm[mt] = okm[mt] ? (py + 1)*9 + px + 1 : 81;
  }
  float bias = b2[oc];
  f4v segacc[4] = {};
  float ssum = 0.f, ssq = 0.f;
  for (int p = p0; p < p1; ++p){
    __syncthreads();
    for (int i = t; i < 3136; i += 256){   // stage pair p with BN1 applied
      u32 v = ((const u32*)(spool + (size_t)p*6272))[i];
      int pix = i >> 6, icp = i & 63;
      float lo = b2f((u16)v)*sc1[icp*2]     + sh1[icp*2];
      float hi = b2f((u16)(v >> 16))*sc1[icp*2 + 1] + sh1[icp*2 + 1];
      int py = pix/7, px = pix - py*7;
      ((u32*)inT)[((py + 1)*9 + px + 1)*68 + icp] = (u32)f2b(lo) | ((u32)f2b(hi) << 16);
    }
    __syncthreads();
    f4v pacc[4] = {};
    #pragma unroll
    for (int tap = 0; tap < 9; ++tap){
      int doff = (tap/3 - 1)*9 + (tap%3 - 1);
      int ro[4];
      #pragma unroll
      for (int mt = 0; mt < 4; ++mt)
        ro[mt] = (okm[mt] ? rowm[mt] + doff : 81)*136;
      #pragma unroll
      for (int kst = 0; kst < 4; ++kst){
        int koff = kst*32 + lhi*8;
        #pragma unroll
        for (int mt = 0; mt < 4; ++mt){
          s8v A = *(const s8v*)&inT[ro[mt] + koff];
          pacc[mt] = mfma16(A, Bf[tap][kst], pacc[mt]);
        }
      }
    }
    #pragma unroll
    for (int mt = 0; mt < 4; ++mt)
      #pragma unroll
      for (int v = 0; v < 4; ++v){
        int pix = mt*16 + lhi*4 + v;
        float r = fmaxf(pacc[mt][v] + bias, 0.f);
        r = (pix < 49) ? r : 0.f;
        segacc[mt][v] += r;
        ssum += r; ssq += r*r;
      }
  }
  #pragma unroll
  for (int mt = 0; mt < 4; ++mt)
    #pragma unroll
    for (int v = 0; v < 4; ++v){
      int pix = mt*16 + lhi*4 + v;
      if (pix < 49)
        atomicAdd(&segr[(size_t)(b*256 + oc)*49 + pix], segacc[mt][v]);
    }
  float s = ssum, qd = ssq;
  s  += __shfl_xor(s, 16);  s  += __shfl_xor(s, 32);
  qd += __shfl_xor(qd, 16); qd += __shfl_xor(qd, 32);
  if (lane < 16){
    atomicAdd(&stats2[og*16 + lane], s);
    atomicAdd(&stats2[256 + og*16 + lane], qd);
  }
}

// ============ combine: union 1x1 conv + bn2(seg-mean relu2) -> tbf ============
__global__ __launch_bounds__(256) void k_combine(const u16* __restrict__ muT, const u16* __restrict__ wuT,
                                                 const float* __restrict__ b_u, const float* __restrict__ segr,
                                                 const float* __restrict__ stats2,
                                                 const float* __restrict__ g2, const float* __restrict__ be2,
                                                 const int* __restrict__ im_idx, u16* __restrict__ tbf,
                                                 int P, float invN2){
  __shared__ float sc2[256], sh2[256];
  int b = blockIdx.x, t = threadIdx.x;
  int lane = t & 63, w = t >> 6;
  int l15 = lane & 15, lhi = lane >> 4;
  {
    float mean = stats2[t]*invN2;
    float var  = stats2[256 + t]*invN2 - mean*mean;
    float sc = g2[t]*rsqrtf(var + 1e-5f);
    sc2[t] = sc; sh2[t] = be2[t] - mean*sc;
  }
  __syncthreads();
  int s0, s1; segrange(im_idx, P, b, s0, s1);
  float inv = 1.f / fmaxf((float)(s1 - s0), 1.f);
  int ocb = w*64;
  const u16* arow[4];
  #pragma unroll
  for (int mt = 0; mt < 4; ++mt){
    int pix = mt*16 + l15;
    arow[mt] = muT + (size_t)(b*49 + (pix < 49 ? pix : 0))*1024;
  }
  f4v acc[4][4] = {};
  for (int kst = 0; kst < 32; ++kst){
    int koff = kst*32 + lhi*8;
    s8v Bf[4];
    #pragma unroll
    for (int nt = 0; nt < 4; ++nt)
      Bf[nt] = *(const s8v*)&wuT[(ocb + nt*16 + l15)*1024 + koff];
    #pragma unroll
    for (int mt = 0; mt < 4; ++mt){
      s8v A = *(const s8v*)&arow[mt][koff];
      #pragma unroll
      for (int nt = 0; nt < 4; ++nt)
        acc[mt][nt] = mfma16(A, Bf[nt], acc[mt][nt]);
    }
  }
  #pragma unroll
  for (int nt = 0; nt < 4; ++nt){
    int oc = ocb + nt*16 + l15;
    float bu = b_u[oc], sc = sc2[oc], sh = sh2[oc];
    #pragma unroll
    for (int mt = 0; mt < 4; ++mt)
      #pragma unroll
      for (int v = 0; v < 4; ++v){
        int pix = mt*16 + lhi*4 + v;
        if (pix < 49){
          float val = acc[mt][nt][v] + bu + sc*segr[(size_t)(b*256 + oc)*49 + pix]*inv + sh;
          tbf[(size_t)b*12544 + oc*49 + pix] = f2b(val);
        }
      }
  }
}

// ============ mega3: vr GEMM (56 blocks) UNION subj/obj GEMM (16 blocks) ============
__global__ __launch_bounds__(256) void k_mega3(const u16* __restrict__ tbf, const u16* __restrict__ wvrT,
                                               const float* __restrict__ b_vr,
                                               const u16* __restrict__ pfbf, const u16* __restrict__ wsoT,
                                               const float* __restrict__ b_subj, const float* __restrict__ b_obj,
                                               float* __restrict__ px, int B){
  int bid = blockIdx.x, t = threadIdx.x;
  int lane = t & 63, w = t >> 6;
  int l15 = lane & 15, lhi = lane >> 4;
  if (bid < 56){
    int nb = bid & 1, kc = bid >> 1;
    int colb = nb*256 + w*64;
    int k0 = kc*448;
    f4v acc[7][4] = {};
    for (int kst = 0; kst < 14; ++kst){
      int koff = k0 + kst*32 + lhi*8;
      s8v Bf[4];
      #pragma unroll
      for (int nt = 0; nt < 4; ++nt)
        Bf[nt] = *(const s8v*)&wvrT[(size_t)(colb + nt*16 + l15)*12544 + koff];
      #pragma unroll
      for (int mt = 0; mt < 7; ++mt){
        s8v A = *(const s8v*)&tbf[(size_t)(mt*16 + l15)*12544 + koff];
        #pragma unroll
        for (int nt = 0; nt < 4; ++nt)
          acc[mt][nt] = mfma16(A, Bf[nt], acc[mt][nt]);
      }
    }
    #pragma unroll
    for (int nt = 0; nt < 4; ++nt){
      int col = colb + nt*16 + l15;
      float bias = (kc == 0) ? b_vr[col] : 0.f;
      #pragma unroll
      for (int mt = 0; mt < 7; ++mt)
        #pragma unroll
        for (int v = 0; v < 4; ++v){
          int row = mt*16 + lhi*4 + v;
          if (row < B) atomicAdd(&px[row*1536 + 1024 + col], acc[mt][nt][v] + bias);
        }
    }
  } else {
    int r = bid - 56;
    int nb = r & 1, s = (r >> 1) & 1, kc = r >> 2;
    int colb = nb*256 + w*64;
    int k0 = kc*512;
    const float* bi = s ? b_obj : b_subj;
    f4v acc[7][4] = {};
    for (int kst = 0; kst < 16; ++kst){
      int koff = k0 + kst*32 + lhi*8;
      s8v Bf[4];
      #pragma unroll
      for (int nt = 0; nt < 4; ++nt)
        Bf[nt] = *(const s8v*)&wsoT[(size_t)(s*512 + colb + nt*16 + l15)*2048 + koff];
      #pragma unroll
      for (int mt = 0; mt < 7; ++mt){
        int row = mt*16 + l15; row = row < B ? row : 0;
        s8v A = *(const s8v*)&pfbf[(size_t)(s*100 + row)*2048 + koff];
        #pragma unroll
        for (int nt = 0; nt < 4; ++nt)
          acc[mt][nt] = mfma16(A, Bf[nt], acc[mt][nt]);
      }
    }
    #pragma unroll
    for (int nt = 0; nt < 4; ++nt){
      int col = colb + nt*16 + l15;
      float bias = (kc == 0) ? bi[col] : 0.f;
      #pragma unroll
      for (int mt = 0; mt < 7; ++mt)
        #pragma unroll
        for (int v = 0; v < 4; ++v){
          int row = mt*16 + lhi*4 + v;
          if (row < B) atomicAdd(&px[row*1536 + s*512 + col], acc[mt][nt][v] + bias);
        }
    }
  }
}

// ============ MLP m1: [112,1536]@[1536,2048], k-split atomics, f32 A inline-cast ============
__global__ __launch_bounds__(256) void k_m1(const float* __restrict__ px, const u16* __restrict__ wm1T,
                                            float* __restrict__ h, int B){
  int nb = blockIdx.x, kc = blockIdx.y, t = threadIdx.x;
  int lane = t & 63, w = t >> 6;
  int l15 = lane & 15, lhi = lane >> 4;
  int colb = nb*256 + w*64;
  int k0 = kc*384;
  f4v acc[7][4] = {};
  for (int kst = 0; kst < 12; ++kst){
    int koff = k0 + kst*32 + lhi*8;
    s8v Bf[4];
    #pragma unroll
    for (int nt = 0; nt < 4; ++nt)
      Bf[nt] = *(const s8v*)&wm1T[(size_t)(colb + nt*16 + l15)*1536 + koff];
    #pragma unroll
    for (int mt = 0; mt < 7; ++mt){
      const float* ap = px + (size_t)(mt*16 + l15)*1536 + koff;
      f4v lo = *(const f4v*)ap;
      f4v hi = *(const f4v*)(ap + 4);
      s8v A;
      A[0] = (short)f2b(lo[0]); A[1] = (short)f2b(lo[1]);
      A[2] = (short)f2b(lo[2]); A[3] = (short)f2b(lo[3]);
      A[4] = (short)f2b(hi[0]); A[5] = (short)f2b(hi[1]);
      A[6] = (short)f2b(hi[2]); A[7] = (short)f2b(hi[3]);
      #pragma unroll
      for (int nt = 0; nt < 4; ++nt)
        acc[mt][nt] = mfma16(A, Bf[nt], acc[mt][nt]);
    }
  }
  #pragma unroll
  for (int nt = 0; nt < 4; ++nt){
    int col = colb + nt*16 + l15;
    #pragma unroll
    for (int mt = 0; mt < 7; ++mt)
      #pragma unroll
      for (int v = 0; v < 4; ++v){
        int row = mt*16 + lhi*4 + v;
        if (row < B) atomicAdd(&h[row*2048 + col], acc[mt][nt][v]);
      }
  }
}

// ============ m2 + bias1/relu + sigmoid, in-block k-split x2 ============
__global__ __launch_bounds__(512) void k_m2(const float* __restrict__ h, const float* __restrict__ bm1,
                                            const float* __restrict__ w_m2, const float* __restrict__ b_m2,
                                            float* __restrict__ out){
  __shared__ float part[160];
  int b = blockIdx.x, t = threadIdx.x;
  int col = t & 255, kg = t >> 8;
  float acc = 0.f;
  if (col < 157){
    const float* hb = h + (size_t)b*2048;
    int k0 = kg*1024;
    for (int k = k0; k < k0 + 1024; ++k)
      acc += fmaxf(hb[k] + bm1[k], 0.f) * w_m2[(size_t)k*157 + col];
  }
  if (kg == 1 && col < 157) part[col] = acc;
  __syncthreads();
  if (kg == 0 && col < 157){
    float s = acc + part[col] + b_m2[col];
    out[b*157 + col] = 1.f/(1.f + expf(-s));
  }
}

extern "C" void kernel_launch(void* const* d_in, const int* in_sizes, int n_in,
                              void* d_out, int out_size, void* d_ws, size_t ws_size,
                              hipStream_t stream){
  const float* features   = (const float*)d_in[0];
  const float* union_feat = (const float*)d_in[1];
  const float* masks      = (const float*)d_in[2];
  const float* w_union    = (const float*)d_in[3];
  const float* b_union    = (const float*)d_in[4];
  const float* w_c1       = (const float*)d_in[5];
  const float* b_c1       = (const float*)d_in[6];
  const float* g_bn1      = (const float*)d_in[7];
  const float* be_bn1     = (const float*)d_in[8];
  const float* w_c2       = (const float*)d_in[9];
  const float* b_c2       = (const float*)d_in[10];
  const float* g_bn2      = (const float*)d_in[11];
  const float* be_bn2     = (const float*)d_in[12];
  const float* w_subj     = (const float*)d_in[13];
  const float* b_subj     = (const float*)d_in[14];
  const float* w_obj      = (const float*)d_in[15];
  const float* b_obj      = (const float*)d_in[16];
  const float* w_vr       = (const float*)d_in[17];
  const float* b_vr       = (const float*)d_in[18];
  const float* w_m1       = (const float*)d_in[19];
  const float* b_m1       = (const float*)d_in[20];
  const float* w_m2       = (const float*)d_in[21];
  const float* b_m2       = (const float*)d_in[22];
  const int* pair_idx     = (const int*)d_in[23];
  const int* im_idx       = (const int*)d_in[24];
  float* out = (float*)d_out;
  const int P = in_sizes[24];
  const int B = out_size/157;

  char* ws = (char*)d_ws;
  size_t off = 0;
  auto alloc = [&](size_t bytes)->size_t{ size_t o = off; off += (bytes + 255) & ~(size_t)255; return o; };
  // zero-region (one memset): stats | segr | px | h
  size_t o_stats= alloc(3072);
  size_t o_segr = alloc((size_t)B*256*49*4);
  size_t o_px   = alloc((size_t)112*1536*4);
  size_t o_h    = alloc((size_t)B*2048*4);
  size_t zero_end = off;
  size_t o_muT  = alloc((size_t)B*49*1024*2);
  size_t o_spool= alloc((size_t)P*49*128*2);
  size_t o_w1t  = alloc(128*128*2);
  size_t o_w2f  = alloc(9*256*128*2);
  size_t o_wuT  = alloc(256*1024*2);
  size_t o_wvrT = alloc((size_t)512*12544*2);
  size_t o_wm1T = alloc((size_t)2048*1536*2);
  size_t o_wsoT = alloc((size_t)1024*2048*2);
  size_t o_pfbf = alloc((size_t)200*2048*2);
  size_t o_tbf  = alloc((size_t)112*12544*2);
  (void)ws_size; (void)n_in;

  float* stats1 = (float*)(ws + o_stats);
  float* stats2 = stats1 + 256;
  u16*   muT    = (u16*)(ws + o_muT);
  u16*   spool  = (u16*)(ws + o_spool);
  u16*   w1tp   = (u16*)(ws + o_w1t);
  u16*   w2f    = (u16*)(ws + o_w2f);
  u16*   wuT    = (u16*)(ws + o_wuT);
  u16*   wvrT   = (u16*)(ws + o_wvrT);
  u16*   wm1T   = (u16*)(ws + o_wm1T);
  u16*   wsoT   = (u16*)(ws + o_wsoT);
  u16*   pfbf   = (u16*)(ws + o_pfbf);
  float* segr   = (float*)(ws + o_segr);
  u16*   tbf    = (u16*)(ws + o_tbf);
  float* px     = (float*)(ws + o_px);
  float* h      = (float*)(ws + o_h);

  hipMemsetAsync(ws, 0, zero_end, stream);

  k_misc<<<5288, dim3(256), 0, stream>>>(features, pair_idx, im_idx, w_c1, w_c2, w_union,
                                         w_vr, w_m1, w_subj, w_obj,
                                         w1tp, w2f, wuT, wvrT, wm1T, wsoT, pfbf, P);
  k_upool<<<dim3(B, 16), dim3(256), 0, stream>>>(union_feat, im_idx, muT, P);
  k_conv1<<<dim3(P, 2), dim3(256), 0, stream>>>(masks, w1tp, b_c1, stats1, spool);
  k_conv2<<<dim3(B, 5, 4), dim3(256), 0, stream>>>(spool, w2f, b_c2, g_bn1, be_bn1, stats1, im_idx,
                                                   segr, stats2, P, 1.f/((float)P*196.f));
  k_combine<<<B, dim3(256), 0, stream>>>(muT, wuT, b_union, segr, stats2, g_bn2, be_bn2, im_idx,
                                         tbf, P, 1.f/((float)P*49.f));
  k_mega3<<<72, dim3(256), 0, stream>>>(tbf, wvrT, b_vr, pfbf, wsoT, b_subj, b_obj, px, B);
  k_m1<<<dim3(8, 4), dim3(256), 0, stream>>>(px, wm1T, h, B);
  k_m2<<<B, dim3(512), 0, stream>>>(h, b_m1, w_m2, b_m2, out);
}

// Round 14
// 1273.909 us; speedup vs baseline: 1.1407x; 1.0490x over previous
//
#include <hip/hip_runtime.h>

typedef unsigned short u16;
typedef unsigned int   u32;
typedef short s8v __attribute__((ext_vector_type(8)));   // 8 x bf16 MFMA operand
typedef float f4v __attribute__((ext_vector_type(4)));   // MFMA accumulator

#define DEV __device__ __forceinline__

DEV u16 f2b(float f){
  u32 x = __builtin_bit_cast(u32, f);
  u32 r = x + 0x7fffu + ((x >> 16) & 1u);
  return (u16)(r >> 16);
}
DEV float b2f(u16 u){ u32 x = ((u32)u) << 16; return __builtin_bit_cast(float, x); }
DEV f4v mfma16(s8v a, s8v b, f4v c){ return __builtin_amdgcn_mfma_f32_16x16x32_bf16(a, b, c, 0, 0, 0); }

DEV void segrange(const int* __restrict__ im, int P, int b, int& s0, int& s1){
  int lo = 0, hi = P;
  while (lo < hi){ int m = (lo + hi) >> 1; if (im[m] < b) lo = m + 1; else hi = m; }
  s0 = lo;
  int lo2 = lo; hi = P;
  while (lo2 < hi){ int m = (lo2 + hi) >> 1; if (im[m] < b + 1) lo2 = m + 1; else hi = m; }
  s1 = lo2;
}

DEV void transpose_body(const float* __restrict__ src, u16* __restrict__ dst,
                        int R, int C, int rb, int cb, int t, float* tile){
  int r0 = rb << 6, c0 = cb << 6;
  for (int i = t; i < 4096; i += 256){
    int rl = i >> 6, cl = i & 63;
    tile[rl*65 + cl] = src[(size_t)(r0 + rl)*C + c0 + cl];
  }
  __syncthreads();
  for (int i = t; i < 4096; i += 256){
    int cl = i >> 6, rl = i & 63;
    dst[(size_t)(c0 + cl)*R + r0 + rl] = f2b(tile[rl*65 + cl]);
  }
}

// ============ k_misc: featpool FIRST, then weight transforms ============
// w2f = conv2 weights fragment-packed: frag=(tap*16+og)*4+kst, element=lane*8+j,
// value = w_c2[(oc*128+k)*9+tap], oc=og*16+(lane&15), k=kst*32+(lane>>4)*8+j.
__global__ __launch_bounds__(256) void k_misc(
    const float* __restrict__ feat, const int* __restrict__ pidx, const int* __restrict__ im_idx,
    const float* __restrict__ w_c1, const float* __restrict__ w_c2, const float* __restrict__ w_u,
    const float* __restrict__ w_vr, const float* __restrict__ w_m1,
    const float* __restrict__ w_subj, const float* __restrict__ w_obj,
    u16* __restrict__ w1tp, u16* __restrict__ w2f, u16* __restrict__ wuT,
    u16* __restrict__ wvrT, u16* __restrict__ wm1T, u16* __restrict__ wsoT,
    u16* __restrict__ pfbf, int P){
  __shared__ float smem[4160];
  int bid = blockIdx.x, t = threadIdx.x;
  if (bid < 200){
    int i = bid; int s = i/100, b = i - s*100;
    int s0, s1; segrange(im_idx, P, b, s0, s1);
    float inv = 1.f / fmaxf((float)(s1 - s0), 1.f);
    f4v a0 = {}, a1 = {};
    for (int p = s0; p < s1; ++p){
      int row = pidx[p*2 + s];
      const f4v* src = (const f4v*)(feat + (size_t)row*2048);
      a0 += src[t]; a1 += src[t+256];
    }
    u16* dst = pfbf + (size_t)(s*100 + b)*2048;
    #pragma unroll
    for (int j = 0; j < 4; ++j){
      dst[4*t + j]        = f2b(a0[j]*inv);
      dst[1024 + 4*t + j] = f2b(a1[j]*inv);
    }
  } else if (bid < 264){
    int i = (bid - 200)*256 + t;           // i = oc*128 + k', k' = ic*64 + ky*8 + kx
    int kp = i & 127;
    int kx = kp & 7, ky = (kp >> 3) & 7, ic = kp >> 6;
    int oc = i >> 7;
    w1tp[i] = f2b((kx < 7 && ky < 7) ? w_c1[oc*98 + ic*49 + ky*7 + kx] : 0.f);
  } else if (bid < 1416){
    int i = (bid - 264)*256 + t;           // fragment-packed conv2 weights
    int frag = i >> 9, r = i & 511;
    int lane = r >> 3, j = r & 7;
    int kst = frag & 3, og = (frag >> 2) & 15, tap = frag >> 6;
    int oc = og*16 + (lane & 15);
    int k  = kst*32 + (lane >> 4)*8 + j;
    w2f[i] = f2b(w_c2[((size_t)(oc*128 + k))*9 + tap]);
  } else if (bid < 2440){
    int i = (bid - 1416)*256 + t;
    wuT[i] = f2b(w_u[i]);
  } else if (bid < 4008){
    int idx = bid - 2440;                  // 196*8
    transpose_body(w_vr, wvrT, 12544, 512, idx >> 3, idx & 7, t, smem);
  } else if (bid < 4776){
    int idx = bid - 4008;                  // 24*32
    transpose_body(w_m1, wm1T, 1536, 2048, idx >> 5, idx & 31, t, smem);
  } else {
    int idx = bid - 4776;                  // 2 * 32*8
    int sel = idx >> 8; idx &= 255;
    transpose_body(sel ? w_obj : w_subj, wsoT + (size_t)sel*512*2048,
                   2048, 512, idx >> 3, idx & 7, t, smem);
  }
}

// ============ k_upool: union segment-mean -> muT[b][49][1024] bf16 (HBM-bound) ============
__global__ __launch_bounds__(256) void k_upool(const float* __restrict__ uf, const int* __restrict__ im_idx,
                                               u16* __restrict__ muT, int P){
  __shared__ float smem[3136];
  int b = blockIdx.x, icb = blockIdx.y, t = threadIdx.x;
  int s0, s1; segrange(im_idx, P, b, s0, s1);
  float inv = 1.f / fmaxf((float)(s1 - s0), 1.f);
  f4v a0 = {}, a1 = {}, a2 = {}, a3 = {};
  int p = s0;
  for (; p + 1 < s1; p += 2){
    const f4v* x = (const f4v*)(uf + (size_t)p*50176 + icb*3136);
    const f4v* y = (const f4v*)(uf + (size_t)(p+1)*50176 + icb*3136);
    a0 += x[t] + y[t]; a1 += x[t+256] + y[t+256]; a2 += x[t+512] + y[t+512];
    if (t < 16) a3 += x[t+768] + y[t+768];
  }
  if (p < s1){
    const f4v* x = (const f4v*)(uf + (size_t)p*50176 + icb*3136);
    a0 += x[t]; a1 += x[t+256]; a2 += x[t+512];
    if (t < 16) a3 += x[t+768];
  }
  *(f4v*)&smem[4*t] = a0;
  *(f4v*)&smem[4*(t+256)] = a1;
  *(f4v*)&smem[4*(t+512)] = a2;
  if (t < 16) *(f4v*)&smem[4*(t+768)] = a3;
  __syncthreads();
  for (int o = t; o < 3136; o += 256){
    int pix = o >> 6, ics = o & 63;
    muT[(size_t)(b*49 + pix)*1024 + (icb<<6) + ics] = f2b(smem[ics*49 + pix]*inv);
  }
}

// ============ conv1 v2 (7x7 s2 p3, 2->128): weight-permuted direct-LDS-read MFMA ============
__global__ __launch_bounds__(256) void k_conv1(const float* __restrict__ masks, const u16* __restrict__ w1tp,
                                               const float* __restrict__ b1,
                                               float* __restrict__ stats1, u16* __restrict__ spool){
  __shared__ u32 lds32[1400];              // in_bf: 2 ch x 680 u32 (+40 slack for ky=7/pad reads)
  __shared__ u16 s1n[64*196];              // this block's 64 oc, post-relu PRE-BN
  int p = blockIdx.x, z = blockIdx.y, t = threadIdx.x;
  int lane = t & 63, w = t >> 6;
  int l15 = lane & 15, lhi = lane >> 4;
  int ocl = w*16 + l15;
  int oc  = z*64 + ocl;
  s8v Bf[4];
  #pragma unroll
  for (int kst = 0; kst < 4; ++kst)
    Bf[kst] = *(const s8v*)&w1tp[(size_t)oc*128 + kst*32 + lhi*8];
  for (int i = t; i < 1400; i += 256) lds32[i] = 0;
  __syncthreads();
  u16* in_bf = (u16*)lds32;
  for (int e = t; e < 1458; e += 256){
    int c = e >= 729; int r = e - c*729;
    int rr = r/27, cc = r - rr*27;
    in_bf[c*1360 + (rr + 3)*40 + cc + 3] = f2b(masks[(size_t)p*1458 + e]);
  }
  int rb[13];
  #pragma unroll
  for (int mt = 0; mt < 13; ++mt){
    int pix = mt*16 + l15;
    int oy = pix/14, ox = pix - oy*14;
    rb[mt] = oy*40 + ox;
  }
  __syncthreads();
  f4v acc[13] = {};
  #pragma unroll
  for (int kst = 0; kst < 4; ++kst){
    int kk = kst*32 + lhi*8;
    int kbase = (kk >> 6)*680 + ((kk >> 3) & 7)*20;
    #pragma unroll
    for (int mt = 0; mt < 13; ++mt){
      int a = kbase + rb[mt];
      union { u32 u[4]; s8v v; } cv;
      cv.u[0] = lds32[a];   cv.u[1] = lds32[a+1];
      cv.u[2] = lds32[a+2]; cv.u[3] = lds32[a+3];
      acc[mt] = mfma16(cv.v, Bf[kst], acc[mt]);
    }
  }
  float bias = b1[oc];
  float ss = 0.f, qq = 0.f;
  #pragma unroll
  for (int mt = 0; mt < 13; ++mt)
    #pragma unroll
    for (int v = 0; v < 4; ++v){
      int pix = mt*16 + lhi*4 + v;
      if (pix < 196){
        float r = fmaxf(acc[mt][v] + bias, 0.f);
        ss += r; qq += r*r;
        s1n[ocl*196 + pix] = f2b(r);
      }
    }
  ss += __shfl_xor(ss, 16); ss += __shfl_xor(ss, 32);
  qq += __shfl_xor(qq, 16); qq += __shfl_xor(qq, 32);
  if (lane < 16){
    atomicAdd(&stats1[z*64 + w*16 + lane], ss);
    atomicAdd(&stats1[128 + z*64 + w*16 + lane], qq);
  }
  __syncthreads();
  {
    int ocp = t & 63, pg = t >> 6;
    const u32* row32 = (const u32*)s1n;
    for (int pp = pg; pp < 49; pp += 4){
      int poy = pp/7, pox = pp - poy*7;
      u32 m = 0;
      #pragma unroll
      for (int dy = 0; dy < 3; ++dy){
        int iy = poy*2 - 1 + dy;
        if (iy < 0 || iy > 13) continue;
        int widx = ocp*98 + iy*7 + pox;
        u32 wB = row32[widx];
        u32 c1 = wB & 0xffffu, c2 = wB >> 16;
        m = c1 > m ? c1 : m;
        m = c2 > m ? c2 : m;
        if (pox > 0){
          u32 c0 = row32[widx - 1] >> 16;
          m = c0 > m ? c0 : m;
        }
      }
      spool[((size_t)p*49 + pp)*128 + z*64 + ocp] = (u16)m;
    }
  }
}

// ============ conv2 v8: register-B + BIJECTIVE XOR-swizzled dbuf inT (row stride 128 u16 = 256B) ============
// Stride 256B is power-of-2-aligned: byte ^ ((row&7)<<4) stays inside the row -> bijective (R13's 272B
// stride leaked across rows -> collisions). Banks: (o/4)^((row&7)<<2) spreads 16 lanes over 8 banks x2 = free.
__global__ __launch_bounds__(256) void k_conv2(const u16* __restrict__ spool, const u16* __restrict__ w2f,
                                               const float* __restrict__ b2,
                                               const float* __restrict__ g1, const float* __restrict__ be1,
                                               const float* __restrict__ stats1, const int* __restrict__ im_idx,
                                               float* __restrict__ segr, float* __restrict__ stats2,
                                               int P, float invN1){
  __shared__ u16 inT[2][82*128];           // dbuf; row 81 = zero (M-pad); halos zero; XOR-swizzled
  __shared__ float sc1[128], sh1[128];
  int b = blockIdx.x, q = blockIdx.y, z = blockIdx.z, t = threadIdx.x;
  int lane = t & 63, w = t >> 6;
  int l15 = lane & 15, lhi = lane >> 4;
  int og = z*4 + w;                        // this wave's 16-oc group
  int oc = og*16 + l15;
  s8v Bf[9][4];                            // whole B panel for this wave: 144 VGPR, loaded once
  #pragma unroll
  for (int tap = 0; tap < 9; ++tap)
    #pragma unroll
    for (int kst = 0; kst < 4; ++kst)
      Bf[tap][kst] = *(const s8v*)&w2f[((((size_t)tap*16 + og)*4 + kst) << 9) + lane*8];
  {
    f4v zv = {}; f4v* a4 = (f4v*)inT;
    for (int i = t; i < 2624; i += 256) a4[i] = zv;
  }
  if (t < 128){                            // folded bnfin1
    float mean = stats1[t]*invN1;
    float var  = stats1[128 + t]*invN1 - mean*mean;
    float sc = g1[t]*rsqrtf(var + 1e-5f);
    sc1[t] = sc; sh1[t] = be1[t] - mean*sc;
  }
  int s0, s1; segrange(im_idx, P, b, s0, s1);
  int cnt = s1 - s0, chunk = (cnt + 4)/5;
  int p0 = s0 + q*chunk, p1 = min(p0 + chunk, s1);
  if (p0 >= p1) return;
  int rowm[4]; bool okm[4];
  #pragma unroll
  for (int mt = 0; mt < 4; ++mt){
    int pix = mt*16 + l15;
    okm[mt] = pix < 49;
    int py = pix/7, px = pix - py*7;
    rowm[mt] = okm[mt] ? (py + 1)*9 + px + 1 : 81;
  }
  float bias = b2[oc];
  f4v segacc[4] = {};
  float ssum = 0.f, ssq = 0.f;
  u32 r13[13];
  const u32* sp32 = (const u32*)spool;
  auto LOADR = [&](int p){
    #pragma unroll
    for (int j = 0; j < 13; ++j){
      int i = j*256 + t;
      r13[j] = (i < 3136) ? sp32[(size_t)p*3136 + i] : 0u;
    }
  };
  auto WRITE = [&](int bb){
    u32* d = (u32*)&inT[bb][0];
    #pragma unroll
    for (int j = 0; j < 13; ++j){
      int i = j*256 + t;
      if (i < 3136){
        int pix = i >> 6, icp = i & 63;
        u32 v = r13[j];
        float lo = b2f((u16)v)*sc1[icp*2]          + sh1[icp*2];
        float hi = b2f((u16)(v >> 16))*sc1[icp*2+1] + sh1[icp*2+1];
        int py = pix/7;
        int row = (py + 1)*9 + (pix - py*7) + 1;
        d[(row*64 + icp) ^ ((row & 7) << 2)] = (u32)f2b(lo) | ((u32)f2b(hi) << 16);
      }
    }
  };
  LOADR(p0);
  __syncthreads();                         // zero-init + sc1 visible before first WRITE
  WRITE(0);
  int cur = 0;
  for (int p = p0; p < p1; ++p){
    __syncthreads();                       // buf[cur] writes visible to all
    if (p + 1 < p1) LOADR(p + 1);          // issue global prefetch: hides under MFMA
    f4v pacc[4] = {};
    const u16* buf = &inT[cur][0];
    #pragma unroll
    for (int tap = 0; tap < 9; ++tap){
      int doff = (tap/3 - 1)*9 + (tap%3 - 1);
      int rr[4];
      #pragma unroll
      for (int mt = 0; mt < 4; ++mt)
        rr[mt] = okm[mt] ? rowm[mt] + doff : 81;
      #pragma unroll
      for (int kst = 0; kst < 4; ++kst){
        int koff = kst*32 + lhi*8;
        #pragma unroll
        for (int mt = 0; mt < 4; ++mt){
          s8v A = *(const s8v*)&buf[(rr[mt]*128 + koff) ^ ((rr[mt] & 7) << 3)];
          pacc[mt] = mfma16(A, Bf[tap][kst], pacc[mt]);
        }
      }
    }
    #pragma unroll
    for (int mt = 0; mt < 4; ++mt)
      #pragma unroll
      for (int v = 0; v < 4; ++v){
        int pix = mt*16 + lhi*4 + v;
        float r = fmaxf(pacc[mt][v] + bias, 0.f);
        r = (pix < 49) ? r : 0.f;
        segacc[mt][v] += r;
        ssum += r; ssq += r*r;
      }
    if (p + 1 < p1) WRITE(cur ^ 1);        // other buffer: safe, readers passed barrier
    cur ^= 1;
  }
  #pragma unroll
  for (int mt = 0; mt < 4; ++mt)
    #pragma unroll
    for (int v = 0; v < 4; ++v){
      int pix = mt*16 + lhi*4 + v;
      if (pix < 49)
        atomicAdd(&segr[(size_t)(b*256 + oc)*49 + pix], segacc[mt][v]);
    }
  float s = ssum, qd = ssq;
  s  += __shfl_xor(s, 16);  s  += __shfl_xor(s, 32);
  qd += __shfl_xor(qd, 16); qd += __shfl_xor(qd, 32);
  if (lane < 16){
    atomicAdd(&stats2[og*16 + lane], s);
    atomicAdd(&stats2[256 + og*16 + lane], qd);
  }
}

// ============ combine: union 1x1 conv + bn2(seg-mean relu2) -> tbf ============
__global__ __launch_bounds__(256) void k_combine(const u16* __restrict__ muT, const u16* __restrict__ wuT,
                                                 const float* __restrict__ b_u, const float* __restrict__ segr,
                                                 const float* __restrict__ stats2,
                                                 const float* __restrict__ g2, const float* __restrict__ be2,
                                                 const int* __restrict__ im_idx, u16* __restrict__ tbf,
                                                 int P, float invN2){
  __shared__ float sc2[256], sh2[256];
  int b = blockIdx.x, t = threadIdx.x;
  int lane = t & 63, w = t >> 6;
  int l15 = lane & 15, lhi = lane >> 4;
  {
    float mean = stats2[t]*invN2;
    float var  = stats2[256 + t]*invN2 - mean*mean;
    float sc = g2[t]*rsqrtf(var + 1e-5f);
    sc2[t] = sc; sh2[t] = be2[t] - mean*sc;
  }
  __syncthreads();
  int s0, s1; segrange(im_idx, P, b, s0, s1);
  float inv = 1.f / fmaxf((float)(s1 - s0), 1.f);
  int ocb = w*64;
  const u16* arow[4];
  #pragma unroll
  for (int mt = 0; mt < 4; ++mt){
    int pix = mt*16 + l15;
    arow[mt] = muT + (size_t)(b*49 + (pix < 49 ? pix : 0))*1024;
  }
  f4v acc[4][4] = {};
  for (int kst = 0; kst < 32; ++kst){
    int koff = kst*32 + lhi*8;
    s8v Bf[4];
    #pragma unroll
    for (int nt = 0; nt < 4; ++nt)
      Bf[nt] = *(const s8v*)&wuT[(ocb + nt*16 + l15)*1024 + koff];
    #pragma unroll
    for (int mt = 0; mt < 4; ++mt){
      s8v A = *(const s8v*)&arow[mt][koff];
      #pragma unroll
      for (int nt = 0; nt < 4; ++nt)
        acc[mt][nt] = mfma16(A, Bf[nt], acc[mt][nt]);
    }
  }
  #pragma unroll
  for (int nt = 0; nt < 4; ++nt){
    int oc = ocb + nt*16 + l15;
    float bu = b_u[oc], sc = sc2[oc], sh = sh2[oc];
    #pragma unroll
    for (int mt = 0; mt < 4; ++mt)
      #pragma unroll
      for (int v = 0; v < 4; ++v){
        int pix = mt*16 + lhi*4 + v;
        if (pix < 49){
          float val = acc[mt][nt][v] + bu + sc*segr[(size_t)(b*256 + oc)*49 + pix]*inv + sh;
          tbf[(size_t)b*12544 + oc*49 + pix] = f2b(val);
        }
      }
  }
}

// ============ mega3: vr GEMM (56 blocks) UNION subj/obj GEMM (16 blocks) ============
__global__ __launch_bounds__(256) void k_mega3(const u16* __restrict__ tbf, const u16* __restrict__ wvrT,
                                               const float* __restrict__ b_vr,
                                               const u16* __restrict__ pfbf, const u16* __restrict__ wsoT,
                                               const float* __restrict__ b_subj, const float* __restrict__ b_obj,
                                               float* __restrict__ px, int B){
  int bid = blockIdx.x, t = threadIdx.x;
  int lane = t & 63, w = t >> 6;
  int l15 = lane & 15, lhi = lane >> 4;
  if (bid < 56){
    int nb = bid & 1, kc = bid >> 1;
    int colb = nb*256 + w*64;
    int k0 = kc*448;
    f4v acc[7][4] = {};
    for (int kst = 0; kst < 14; ++kst){
      int koff = k0 + kst*32 + lhi*8;
      s8v Bf[4];
      #pragma unroll
      for (int nt = 0; nt < 4; ++nt)
        Bf[nt] = *(const s8v*)&wvrT[(size_t)(colb + nt*16 + l15)*12544 + koff];
      #pragma unroll
      for (int mt = 0; mt < 7; ++mt){
        s8v A = *(const s8v*)&tbf[(size_t)(mt*16 + l15)*12544 + koff];
        #pragma unroll
        for (int nt = 0; nt < 4; ++nt)
          acc[mt][nt] = mfma16(A, Bf[nt], acc[mt][nt]);
      }
    }
    #pragma unroll
    for (int nt = 0; nt < 4; ++nt){
      int col = colb + nt*16 + l15;
      float bias = (kc == 0) ? b_vr[col] : 0.f;
      #pragma unroll
      for (int mt = 0; mt < 7; ++mt)
        #pragma unroll
        for (int v = 0; v < 4; ++v){
          int row = mt*16 + lhi*4 + v;
          if (row < B) atomicAdd(&px[row*1536 + 1024 + col], acc[mt][nt][v] + bias);
        }
    }
  } else {
    int r = bid - 56;
    int nb = r & 1, s = (r >> 1) & 1, kc = r >> 2;
    int colb = nb*256 + w*64;
    int k0 = kc*512;
    const float* bi = s ? b_obj : b_subj;
    f4v acc[7][4] = {};
    for (int kst = 0; kst < 16; ++kst){
      int koff = k0 + kst*32 + lhi*8;
      s8v Bf[4];
      #pragma unroll
      for (int nt = 0; nt < 4; ++nt)
        Bf[nt] = *(const s8v*)&wsoT[(size_t)(s*512 + colb + nt*16 + l15)*2048 + koff];
      #pragma unroll
      for (int mt = 0; mt < 7; ++mt){
        int row = mt*16 + l15; row = row < B ? row : 0;
        s8v A = *(const s8v*)&pfbf[(size_t)(s*100 + row)*2048 + koff];
        #pragma unroll
        for (int nt = 0; nt < 4; ++nt)
          acc[mt][nt] = mfma16(A, Bf[nt], acc[mt][nt]);
      }
    }
    #pragma unroll
    for (int nt = 0; nt < 4; ++nt){
      int col = colb + nt*16 + l15;
      float bias = (kc == 0) ? bi[col] : 0.f;
      #pragma unroll
      for (int mt = 0; mt < 7; ++mt)
        #pragma unroll
        for (int v = 0; v < 4; ++v){
          int row = mt*16 + lhi*4 + v;
          if (row < B) atomicAdd(&px[row*1536 + s*512 + col], acc[mt][nt][v] + bias);
        }
    }
  }
}

// ============ MLP m1: [112,1536]@[1536,2048], k-split atomics, f32 A inline-cast ============
__global__ __launch_bounds__(256) void k_m1(const float* __restrict__ px, const u16* __restrict__ wm1T,
                                            float* __restrict__ h, int B){
  int nb = blockIdx.x, kc = blockIdx.y, t = threadIdx.x;
  int lane = t & 63, w = t >> 6;
  int l15 = lane & 15, lhi = lane >> 4;
  int colb = nb*256 + w*64;
  int k0 = kc*384;
  f4v acc[7][4] = {};
  for (int kst = 0; kst < 12; ++kst){
    int koff = k0 + kst*32 + lhi*8;
    s8v Bf[4];
    #pragma unroll
    for (int nt = 0; nt < 4; ++nt)
      Bf[nt] = *(const s8v*)&wm1T[(size_t)(colb + nt*16 + l15)*1536 + koff];
    #pragma unroll
    for (int mt = 0; mt < 7; ++mt){
      const float* ap = px + (size_t)(mt*16 + l15)*1536 + koff;
      f4v lo = *(const f4v*)ap;
      f4v hi = *(const f4v*)(ap + 4);
      s8v A;
      A[0] = (short)f2b(lo[0]); A[1] = (short)f2b(lo[1]);
      A[2] = (short)f2b(lo[2]); A[3] = (short)f2b(lo[3]);
      A[4] = (short)f2b(hi[0]); A[5] = (short)f2b(hi[1]);
      A[6] = (short)f2b(hi[2]); A[7] = (short)f2b(hi[3]);
      #pragma unroll
      for (int nt = 0; nt < 4; ++nt)
        acc[mt][nt] = mfma16(A, Bf[nt], acc[mt][nt]);
    }
  }
  #pragma unroll
  for (int nt = 0; nt < 4; ++nt){
    int col = colb + nt*16 + l15;
    #pragma unroll
    for (int mt = 0; mt < 7; ++mt)
      #pragma unroll
      for (int v = 0; v < 4; ++v){
        int row = mt*16 + lhi*4 + v;
        if (row < B) atomicAdd(&h[row*2048 + col], acc[mt][nt][v]);
      }
  }
}

// ============ m2 + bias1/relu + sigmoid, in-block k-split x2 ============
__global__ __launch_bounds__(512) void k_m2(const float* __restrict__ h, const float* __restrict__ bm1,
                                            const float* __restrict__ w_m2, const float* __restrict__ b_m2,
                                            float* __restrict__ out){
  __shared__ float part[160];
  int b = blockIdx.x, t = threadIdx.x;
  int col = t & 255, kg = t >> 8;
  float acc = 0.f;
  if (col < 157){
    const float* hb = h + (size_t)b*2048;
    int k0 = kg*1024;
    for (int k = k0; k < k0 + 1024; ++k)
      acc += fmaxf(hb[k] + bm1[k], 0.f) * w_m2[(size_t)k*157 + col];
  }
  if (kg == 1 && col < 157) part[col] = acc;
  __syncthreads();
  if (kg == 0 && col < 157){
    float s = acc + part[col] + b_m2[col];
    out[b*157 + col] = 1.f/(1.f + expf(-s));
  }
}

extern "C" void kernel_launch(void* const* d_in, const int* in_sizes, int n_in,
                              void* d_out, int out_size, void* d_ws, size_t ws_size,
                              hipStream_t stream){
  const float* features   = (const float*)d_in[0];
  const float* union_feat = (const float*)d_in[1];
  const float* masks      = (const float*)d_in[2];
  const float* w_union    = (const float*)d_in[3];
  const float* b_union    = (const float*)d_in[4];
  const float* w_c1       = (const float*)d_in[5];
  const float* b_c1       = (const float*)d_in[6];
  const float* g_bn1      = (const float*)d_in[7];
  const float* be_bn1     = (const float*)d_in[8];
  const float* w_c2       = (const float*)d_in[9];
  const float* b_c2       = (const float*)d_in[10];
  const float* g_bn2      = (const float*)d_in[11];
  const float* be_bn2     = (const float*)d_in[12];
  const float* w_subj     = (const float*)d_in[13];
  const float* b_subj     = (const float*)d_in[14];
  const float* w_obj      = (const float*)d_in[15];
  const float* b_obj      = (const float*)d_in[16];
  const float* w_vr       = (const float*)d_in[17];
  const float* b_vr       = (const float*)d_in[18];
  const float* w_m1       = (const float*)d_in[19];
  const float* b_m1       = (const float*)d_in[20];
  const float* w_m2       = (const float*)d_in[21];
  const float* b_m2       = (const float*)d_in[22];
  const int* pair_idx     = (const int*)d_in[23];
  const int* im_idx       = (const int*)d_in[24];
  float* out = (float*)d_out;
  const int P = in_sizes[24];
  const int B = out_size/157;

  char* ws = (char*)d_ws;
  size_t off = 0;
  auto alloc = [&](size_t bytes)->size_t{ size_t o = off; off += (bytes + 255) & ~(size_t)255; return o; };
  // zero-region (one memset): stats | segr | px | h
  size_t o_stats= alloc(3072);
  size_t o_segr = alloc((size_t)B*256*49*4);
  size_t o_px   = alloc((size_t)112*1536*4);
  size_t o_h    = alloc((size_t)B*2048*4);
  size_t zero_end = off;
  size_t o_muT  = alloc((size_t)B*49*1024*2);
  size_t o_spool= alloc((size_t)P*49*128*2);
  size_t o_w1t  = alloc(128*128*2);
  size_t o_w2f  = alloc(9*256*128*2);
  size_t o_wuT  = alloc(256*1024*2);
  size_t o_wvrT = alloc((size_t)512*12544*2);
  size_t o_wm1T = alloc((size_t)2048*1536*2);
  size_t o_wsoT = alloc((size_t)1024*2048*2);
  size_t o_pfbf = alloc((size_t)200*2048*2);
  size_t o_tbf  = alloc((size_t)112*12544*2);
  (void)ws_size; (void)n_in;

  float* stats1 = (float*)(ws + o_stats);
  float* stats2 = stats1 + 256;
  u16*   muT    = (u16*)(ws + o_muT);
  u16*   spool  = (u16*)(ws + o_spool);
  u16*   w1tp   = (u16*)(ws + o_w1t);
  u16*   w2f    = (u16*)(ws + o_w2f);
  u16*   wuT    = (u16*)(ws + o_wuT);
  u16*   wvrT   = (u16*)(ws + o_wvrT);
  u16*   wm1T   = (u16*)(ws + o_wm1T);
  u16*   wsoT   = (u16*)(ws + o_wsoT);
  u16*   pfbf   = (u16*)(ws + o_pfbf);
  float* segr   = (float*)(ws + o_segr);
  u16*   tbf    = (u16*)(ws + o_tbf);
  float* px     = (float*)(ws + o_px);
  float* h      = (float*)(ws + o_h);

  hipMemsetAsync(ws, 0, zero_end, stream);

  k_misc<<<5288, dim3(256), 0, stream>>>(features, pair_idx, im_idx, w_c1, w_c2, w_union,
                                         w_vr, w_m1, w_subj, w_obj,
                                         w1tp, w2f, wuT, wvrT, wm1T, wsoT, pfbf, P);
  k_upool<<<dim3(B, 16), dim3(256), 0, stream>>>(union_feat, im_idx, muT, P);
  k_conv1<<<dim3(P, 2), dim3(256), 0, stream>>>(masks, w1tp, b_c1, stats1, spool);
  k_conv2<<<dim3(B, 5, 4), dim3(256), 0, stream>>>(spool, w2f, b_c2, g_bn1, be_bn1, stats1, im_idx,
                                                   segr, stats2, P, 1.f/((float)P*196.f));
  k_combine<<<B, dim3(256), 0, stream>>>(muT, wuT, b_union, segr, stats2, g_bn2, be_bn2, im_idx,
                                         tbf, P, 1.f/((float)P*49.f));
  k_mega3<<<72, dim3(256), 0, stream>>>(tbf, wvrT, b_vr, pfbf, wsoT, b_subj, b_obj, px, B);
  k_m1<<<dim3(8, 4), dim3(256), 0, stream>>>(px, wm1T, h, B);
  k_m2<<<B, dim3(512), 0, stream>>>(h, b_m1, w_m2, b_m2, out);
}

// Round 15
// 1168.619 us; speedup vs baseline: 1.2434x; 1.0901x over previous
//
#include <hip/hip_runtime.h>

typedef unsigned short u16;
typedef unsigned int   u32;
typedef short s8v __attribute__((ext_vector_type(8)));   // 8 x bf16 MFMA operand
typedef float f4v __attribute__((ext_vector_type(4)));   // MFMA accumulator

#define DEV __device__ __forceinline__

DEV u16 f2b(float f){
  u32 x = __builtin_bit_cast(u32, f);
  u32 r = x + 0x7fffu + ((x >> 16) & 1u);
  return (u16)(r >> 16);
}
DEV float b2f(u16 u){ u32 x = ((u32)u) << 16; return __builtin_bit_cast(float, x); }
DEV f4v mfma16(s8v a, s8v b, f4v c){ return __builtin_amdgcn_mfma_f32_16x16x32_bf16(a, b, c, 0, 0, 0); }

DEV void segrange(const int* __restrict__ im, int P, int b, int& s0, int& s1){
  int lo = 0, hi = P;
  while (lo < hi){ int m = (lo + hi) >> 1; if (im[m] < b) lo = m + 1; else hi = m; }
  s0 = lo;
  int lo2 = lo; hi = P;
  while (lo2 < hi){ int m = (lo2 + hi) >> 1; if (im[m] < b + 1) lo2 = m + 1; else hi = m; }
  s1 = lo2;
}

DEV void transpose_body(const float* __restrict__ src, u16* __restrict__ dst,
                        int R, int C, int rb, int cb, int t, float* tile){
  int r0 = rb << 6, c0 = cb << 6;
  for (int i = t; i < 4096; i += 256){
    int rl = i >> 6, cl = i & 63;
    tile[rl*65 + cl] = src[(size_t)(r0 + rl)*C + c0 + cl];
  }
  __syncthreads();
  for (int i = t; i < 4096; i += 256){
    int cl = i >> 6, rl = i & 63;
    dst[(size_t)(c0 + cl)*R + r0 + rl] = f2b(tile[rl*65 + cl]);
  }
}

// ============ k_misc: featpool FIRST, then weight transforms ============
__global__ __launch_bounds__(256) void k_misc(
    const float* __restrict__ feat, const int* __restrict__ pidx, const int* __restrict__ im_idx,
    const float* __restrict__ w_c1, const float* __restrict__ w_c2, const float* __restrict__ w_u,
    const float* __restrict__ w_vr, const float* __restrict__ w_m1,
    const float* __restrict__ w_subj, const float* __restrict__ w_obj,
    u16* __restrict__ w1tp, u16* __restrict__ w2f, u16* __restrict__ wuT,
    u16* __restrict__ wvrT, u16* __restrict__ wm1T, u16* __restrict__ wsoT,
    u16* __restrict__ pfbf, int P){
  __shared__ float smem[4160];
  int bid = blockIdx.x, t = threadIdx.x;
  if (bid < 200){
    int i = bid; int s = i/100, b = i - s*100;
    int s0, s1; segrange(im_idx, P, b, s0, s1);
    float inv = 1.f / fmaxf((float)(s1 - s0), 1.f);
    f4v a0 = {}, a1 = {};
    for (int p = s0; p < s1; ++p){
      int row = pidx[p*2 + s];
      const f4v* src = (const f4v*)(feat + (size_t)row*2048);
      a0 += src[t]; a1 += src[t+256];
    }
    u16* dst = pfbf + (size_t)(s*100 + b)*2048;
    #pragma unroll
    for (int j = 0; j < 4; ++j){
      dst[4*t + j]        = f2b(a0[j]*inv);
      dst[1024 + 4*t + j] = f2b(a1[j]*inv);
    }
  } else if (bid < 264){
    int i = (bid - 200)*256 + t;           // i = oc*128 + k', k' = ic*64 + ky*8 + kx
    int kp = i & 127;
    int kx = kp & 7, ky = (kp >> 3) & 7, ic = kp >> 6;
    int oc = i >> 7;
    w1tp[i] = f2b((kx < 7 && ky < 7) ? w_c1[oc*98 + ic*49 + ky*7 + kx] : 0.f);
  } else if (bid < 1416){
    int i = (bid - 264)*256 + t;           // fragment-packed conv2 weights
    int frag = i >> 9, r = i & 511;
    int lane = r >> 3, j = r & 7;
    int kst = frag & 3, og = (frag >> 2) & 15, tap = frag >> 6;
    int oc = og*16 + (lane & 15);
    int k  = kst*32 + (lane >> 4)*8 + j;
    w2f[i] = f2b(w_c2[((size_t)(oc*128 + k))*9 + tap]);
  } else if (bid < 2440){
    int i = (bid - 1416)*256 + t;
    wuT[i] = f2b(w_u[i]);
  } else if (bid < 4008){
    int idx = bid - 2440;                  // 196*8
    transpose_body(w_vr, wvrT, 12544, 512, idx >> 3, idx & 7, t, smem);
  } else if (bid < 4776){
    int idx = bid - 4008;                  // 24*32
    transpose_body(w_m1, wm1T, 1536, 2048, idx >> 5, idx & 31, t, smem);
  } else {
    int idx = bid - 4776;                  // 2 * 32*8
    int sel = idx >> 8; idx &= 255;
    transpose_body(sel ? w_obj : w_subj, wsoT + (size_t)sel*512*2048,
                   2048, 512, idx >> 3, idx & 7, t, smem);
  }
}

// ============ conv1 v2 (7x7 s2 p3, 2->128): weight-permuted direct-LDS-read MFMA ============
__global__ __launch_bounds__(256) void k_conv1(const float* __restrict__ masks, const u16* __restrict__ w1tp,
                                               const float* __restrict__ b1,
                                               float* __restrict__ stats1, u16* __restrict__ spool){
  __shared__ u32 lds32[1400];              // in_bf: 2 ch x 680 u32 (+40 slack for ky=7/pad reads)
  __shared__ u16 s1n[64*196];              // this block's 64 oc, post-relu PRE-BN
  int p = blockIdx.x, z = blockIdx.y, t = threadIdx.x;
  int lane = t & 63, w = t >> 6;
  int l15 = lane & 15, lhi = lane >> 4;
  int ocl = w*16 + l15;
  int oc  = z*64 + ocl;
  s8v Bf[4];
  #pragma unroll
  for (int kst = 0; kst < 4; ++kst)
    Bf[kst] = *(const s8v*)&w1tp[(size_t)oc*128 + kst*32 + lhi*8];
  for (int i = t; i < 1400; i += 256) lds32[i] = 0;
  __syncthreads();
  u16* in_bf = (u16*)lds32;
  for (int e = t; e < 1458; e += 256){
    int c = e >= 729; int r = e - c*729;
    int rr = r/27, cc = r - rr*27;
    in_bf[c*1360 + (rr + 3)*40 + cc + 3] = f2b(masks[(size_t)p*1458 + e]);
  }
  int rb[13];
  #pragma unroll
  for (int mt = 0; mt < 13; ++mt){
    int pix = mt*16 + l15;
    int oy = pix/14, ox = pix - oy*14;
    rb[mt] = oy*40 + ox;
  }
  __syncthreads();
  f4v acc[13] = {};
  #pragma unroll
  for (int kst = 0; kst < 4; ++kst){
    int kk = kst*32 + lhi*8;
    int kbase = (kk >> 6)*680 + ((kk >> 3) & 7)*20;
    #pragma unroll
    for (int mt = 0; mt < 13; ++mt){
      int a = kbase + rb[mt];
      union { u32 u[4]; s8v v; } cv;
      cv.u[0] = lds32[a];   cv.u[1] = lds32[a+1];
      cv.u[2] = lds32[a+2]; cv.u[3] = lds32[a+3];
      acc[mt] = mfma16(cv.v, Bf[kst], acc[mt]);
    }
  }
  float bias = b1[oc];
  float ss = 0.f, qq = 0.f;
  #pragma unroll
  for (int mt = 0; mt < 13; ++mt)
    #pragma unroll
    for (int v = 0; v < 4; ++v){
      int pix = mt*16 + lhi*4 + v;
      if (pix < 196){
        float r = fmaxf(acc[mt][v] + bias, 0.f);
        ss += r; qq += r*r;
        s1n[ocl*196 + pix] = f2b(r);
      }
    }
  ss += __shfl_xor(ss, 16); ss += __shfl_xor(ss, 32);
  qq += __shfl_xor(qq, 16); qq += __shfl_xor(qq, 32);
  if (lane < 16){
    atomicAdd(&stats1[z*64 + w*16 + lane], ss);
    atomicAdd(&stats1[128 + z*64 + w*16 + lane], qq);
  }
  __syncthreads();
  {
    int ocp = t & 63, pg = t >> 6;
    const u32* row32 = (const u32*)s1n;
    for (int pp = pg; pp < 49; pp += 4){
      int poy = pp/7, pox = pp - poy*7;
      u32 m = 0;
      #pragma unroll
      for (int dy = 0; dy < 3; ++dy){
        int iy = poy*2 - 1 + dy;
        if (iy < 0 || iy > 13) continue;
        int widx = ocp*98 + iy*7 + pox;
        u32 wB = row32[widx];
        u32 c1 = wB & 0xffffu, c2 = wB >> 16;
        m = c1 > m ? c1 : m;
        m = c2 > m ? c2 : m;
        if (pox > 0){
          u32 c0 = row32[widx - 1] >> 16;
          m = c0 > m ? c0 : m;
        }
      }
      spool[((size_t)p*49 + pp)*128 + z*64 + ocp] = (u16)m;
    }
  }
}

// ============ k_c2up: conv2 v8 (latency/LDS-bound) UNION upool (HBM-bound), 4:9 interleave ============
// bid%9<4 -> upool (u=g*4+r, 1600 blocks); else conv2 (idx=g*5+(r-4), 2000 blocks). HBM stream runs
// under conv2's latency bubbles. conv2 body = R14-verified (register-B, bijective swizzle, dbuf).
__global__ __launch_bounds__(256) void k_c2up(
    const u16* __restrict__ spool, const u16* __restrict__ w2f, const float* __restrict__ b2,
    const float* __restrict__ g1, const float* __restrict__ be1,
    const float* __restrict__ stats1, const int* __restrict__ im_idx,
    float* __restrict__ segr, float* __restrict__ stats2, int P, float invN1,
    const float* __restrict__ uf, u16* __restrict__ muT){
  __shared__ u16 raw[2*82*128 + 512];      // conv2: inT dbuf + sc1/sh1 | upool: 3136 f32
  int bid = blockIdx.x, t = threadIdx.x;
  int g = bid/9, r9 = bid - g*9;

  if (r9 < 4){
    // ---------- upool: u = g*4 + r9; block (b, icb) pools 64 channels ----------
    float* smem = (float*)raw;
    int u = g*4 + r9;
    int b = u >> 4, icb = u & 15;
    int s0, s1; segrange(im_idx, P, b, s0, s1);
    float inv = 1.f / fmaxf((float)(s1 - s0), 1.f);
    f4v a0 = {}, a1 = {}, a2 = {}, a3 = {};
    int p = s0;
    for (; p + 1 < s1; p += 2){
      const f4v* x = (const f4v*)(uf + (size_t)p*50176 + icb*3136);
      const f4v* y = (const f4v*)(uf + (size_t)(p+1)*50176 + icb*3136);
      a0 += x[t] + y[t]; a1 += x[t+256] + y[t+256]; a2 += x[t+512] + y[t+512];
      if (t < 16) a3 += x[t+768] + y[t+768];
    }
    if (p < s1){
      const f4v* x = (const f4v*)(uf + (size_t)p*50176 + icb*3136);
      a0 += x[t]; a1 += x[t+256]; a2 += x[t+512];
      if (t < 16) a3 += x[t+768];
    }
    *(f4v*)&smem[4*t] = a0;
    *(f4v*)&smem[4*(t+256)] = a1;
    *(f4v*)&smem[4*(t+512)] = a2;
    if (t < 16) *(f4v*)&smem[4*(t+768)] = a3;
    __syncthreads();
    for (int o = t; o < 3136; o += 256){
      int pix = o >> 6, ics = o & 63;
      muT[(size_t)(b*49 + pix)*1024 + (icb<<6) + ics] = f2b(smem[ics*49 + pix]*inv);
    }
    return;
  }

  // ---------- conv2: idx = g*5 + (r9-4); b = idx/20, q = (idx%20)>>2, z = idx&3 ----------
  int idx = g*5 + (r9 - 4);
  int b = idx/20, rem = idx - b*20;
  int q = rem >> 2, z = rem & 3;
  float* sc1 = (float*)&raw[2*82*128];
  float* sh1 = sc1 + 128;
  int lane = t & 63, w = t >> 6;
  int l15 = lane & 15, lhi = lane >> 4;
  int og = z*4 + w;                        // this wave's 16-oc group
  int oc = og*16 + l15;
  s8v Bf[9][4];                            // whole B panel for this wave: 144 VGPR, loaded once
  #pragma unroll
  for (int tap = 0; tap < 9; ++tap)
    #pragma unroll
    for (int kst = 0; kst < 4; ++kst)
      Bf[tap][kst] = *(const s8v*)&w2f[((((size_t)tap*16 + og)*4 + kst) << 9) + lane*8];
  {
    f4v zv = {}; f4v* a4 = (f4v*)raw;
    for (int i = t; i < 2624; i += 256) a4[i] = zv;
  }
  if (t < 128){                            // folded bnfin1
    float mean = stats1[t]*invN1;
    float var  = stats1[128 + t]*invN1 - mean*mean;
    float sc = g1[t]*rsqrtf(var + 1e-5f);
    sc1[t] = sc; sh1[t] = be1[t] - mean*sc;
  }
  int s0, s1; segrange(im_idx, P, b, s0, s1);
  int cnt = s1 - s0, chunk = (cnt + 4)/5;
  int p0 = s0 + q*chunk, p1 = min(p0 + chunk, s1);
  if (p0 >= p1) return;
  int rowm[4]; bool okm[4];
  #pragma unroll
  for (int mt = 0; mt < 4; ++mt){
    int pix = mt*16 + l15;
    okm[mt] = pix < 49;
    int py = pix/7, px = pix - py*7;
    rowm[mt] = okm[mt] ? (py + 1)*9 + px + 1 : 81;
  }
  float bias = b2[oc];
  f4v segacc[4] = {};
  float ssum = 0.f, ssq = 0.f;
  u32 r13[13];
  const u32* sp32 = (const u32*)spool;
  auto LOADR = [&](int p){
    #pragma unroll
    for (int j = 0; j < 13; ++j){
      int i = j*256 + t;
      r13[j] = (i < 3136) ? sp32[(size_t)p*3136 + i] : 0u;
    }
  };
  auto WRITE = [&](int bb){
    u32* d = (u32*)&raw[bb*82*128];
    #pragma unroll
    for (int j = 0; j < 13; ++j){
      int i = j*256 + t;
      if (i < 3136){
        int pix = i >> 6, icp = i & 63;
        u32 v = r13[j];
        float lo = b2f((u16)v)*sc1[icp*2]          + sh1[icp*2];
        float hi = b2f((u16)(v >> 16))*sc1[icp*2+1] + sh1[icp*2+1];
        int py = pix/7;
        int row = (py + 1)*9 + (pix - py*7) + 1;
        d[(row*64 + icp) ^ ((row & 7) << 2)] = (u32)f2b(lo) | ((u32)f2b(hi) << 16);
      }
    }
  };
  LOADR(p0);
  __syncthreads();                         // zero-init + sc1 visible before first WRITE
  WRITE(0);
  int cur = 0;
  for (int p = p0; p < p1; ++p){
    __syncthreads();                       // buf[cur] writes visible to all
    if (p + 1 < p1) LOADR(p + 1);          // issue global prefetch: hides under MFMA
    f4v pacc[4] = {};
    const u16* buf = &raw[cur*82*128];
    #pragma unroll
    for (int tap = 0; tap < 9; ++tap){
      int doff = (tap/3 - 1)*9 + (tap%3 - 1);
      int rr[4];
      #pragma unroll
      for (int mt = 0; mt < 4; ++mt)
        rr[mt] = okm[mt] ? rowm[mt] + doff : 81;
      #pragma unroll
      for (int kst = 0; kst < 4; ++kst){
        int koff = kst*32 + lhi*8;
        #pragma unroll
        for (int mt = 0; mt < 4; ++mt){
          s8v A = *(const s8v*)&buf[(rr[mt]*128 + koff) ^ ((rr[mt] & 7) << 3)];
          pacc[mt] = mfma16(A, Bf[tap][kst], pacc[mt]);
        }
      }
    }
    #pragma unroll
    for (int mt = 0; mt < 4; ++mt)
      #pragma unroll
      for (int v = 0; v < 4; ++v){
        int pix = mt*16 + lhi*4 + v;
        float r = fmaxf(pacc[mt][v] + bias, 0.f);
        r = (pix < 49) ? r : 0.f;
        segacc[mt][v] += r;
        ssum += r; ssq += r*r;
      }
    if (p + 1 < p1) WRITE(cur ^ 1);        // other buffer: safe, readers passed barrier
    cur ^= 1;
  }
  #pragma unroll
  for (int mt = 0; mt < 4; ++mt)
    #pragma unroll
    for (int v = 0; v < 4; ++v){
      int pix = mt*16 + lhi*4 + v;
      if (pix < 49)
        atomicAdd(&segr[(size_t)(b*256 + oc)*49 + pix], segacc[mt][v]);
    }
  float s = ssum, qd = ssq;
  s  += __shfl_xor(s, 16);  s  += __shfl_xor(s, 32);
  qd += __shfl_xor(qd, 16); qd += __shfl_xor(qd, 32);
  if (lane < 16){
    atomicAdd(&stats2[og*16 + lane], s);
    atomicAdd(&stats2[256 + og*16 + lane], qd);
  }
}

// ============ combine: union 1x1 conv + bn2(seg-mean relu2) -> tbf ============
__global__ __launch_bounds__(256) void k_combine(const u16* __restrict__ muT, const u16* __restrict__ wuT,
                                                 const float* __restrict__ b_u, const float* __restrict__ segr,
                                                 const float* __restrict__ stats2,
                                                 const float* __restrict__ g2, const float* __restrict__ be2,
                                                 const int* __restrict__ im_idx, u16* __restrict__ tbf,
                                                 int P, float invN2){
  __shared__ float sc2[256], sh2[256];
  int b = blockIdx.x, t = threadIdx.x;
  int lane = t & 63, w = t >> 6;
  int l15 = lane & 15, lhi = lane >> 4;
  {
    float mean = stats2[t]*invN2;
    float var  = stats2[256 + t]*invN2 - mean*mean;
    float sc = g2[t]*rsqrtf(var + 1e-5f);
    sc2[t] = sc; sh2[t] = be2[t] - mean*sc;
  }
  __syncthreads();
  int s0, s1; segrange(im_idx, P, b, s0, s1);
  float inv = 1.f / fmaxf((float)(s1 - s0), 1.f);
  int ocb = w*64;
  const u16* arow[4];
  #pragma unroll
  for (int mt = 0; mt < 4; ++mt){
    int pix = mt*16 + l15;
    arow[mt] = muT + (size_t)(b*49 + (pix < 49 ? pix : 0))*1024;
  }
  f4v acc[4][4] = {};
  for (int kst = 0; kst < 32; ++kst){
    int koff = kst*32 + lhi*8;
    s8v Bf[4];
    #pragma unroll
    for (int nt = 0; nt < 4; ++nt)
      Bf[nt] = *(const s8v*)&wuT[(ocb + nt*16 + l15)*1024 + koff];
    #pragma unroll
    for (int mt = 0; mt < 4; ++mt){
      s8v A = *(const s8v*)&arow[mt][koff];
      #pragma unroll
      for (int nt = 0; nt < 4; ++nt)
        acc[mt][nt] = mfma16(A, Bf[nt], acc[mt][nt]);
    }
  }
  #pragma unroll
  for (int nt = 0; nt < 4; ++nt){
    int oc = ocb + nt*16 + l15;
    float bu = b_u[oc], sc = sc2[oc], sh = sh2[oc];
    #pragma unroll
    for (int mt = 0; mt < 4; ++mt)
      #pragma unroll
      for (int v = 0; v < 4; ++v){
        int pix = mt*16 + lhi*4 + v;
        if (pix < 49){
          float val = acc[mt][nt][v] + bu + sc*segr[(size_t)(b*256 + oc)*49 + pix]*inv + sh;
          tbf[(size_t)b*12544 + oc*49 + pix] = f2b(val);
        }
      }
  }
}

// ============ mega3: vr GEMM (56 blocks) UNION subj/obj GEMM (16 blocks) ============
__global__ __launch_bounds__(256) void k_mega3(const u16* __restrict__ tbf, const u16* __restrict__ wvrT,
                                               const float* __restrict__ b_vr,
                                               const u16* __restrict__ pfbf, const u16* __restrict__ wsoT,
                                               const float* __restrict__ b_subj, const float* __restrict__ b_obj,
                                               float* __restrict__ px, int B){
  int bid = blockIdx.x, t = threadIdx.x;
  int lane = t & 63, w = t >> 6;
  int l15 = lane & 15, lhi = lane >> 4;
  if (bid < 56){
    int nb = bid & 1, kc = bid >> 1;
    int colb = nb*256 + w*64;
    int k0 = kc*448;
    f4v acc[7][4] = {};
    for (int kst = 0; kst < 14; ++kst){
      int koff = k0 + kst*32 + lhi*8;
      s8v Bf[4];
      #pragma unroll
      for (int nt = 0; nt < 4; ++nt)
        Bf[nt] = *(const s8v*)&wvrT[(size_t)(colb + nt*16 + l15)*12544 + koff];
      #pragma unroll
      for (int mt = 0; mt < 7; ++mt){
        s8v A = *(const s8v*)&tbf[(size_t)(mt*16 + l15)*12544 + koff];
        #pragma unroll
        for (int nt = 0; nt < 4; ++nt)
          acc[mt][nt] = mfma16(A, Bf[nt], acc[mt][nt]);
      }
    }
    #pragma unroll
    for (int nt = 0; nt < 4; ++nt){
      int col = colb + nt*16 + l15;
      float bias = (kc == 0) ? b_vr[col] : 0.f;
      #pragma unroll
      for (int mt = 0; mt < 7; ++mt)
        #pragma unroll
        for (int v = 0; v < 4; ++v){
          int row = mt*16 + lhi*4 + v;
          if (row < B) atomicAdd(&px[row*1536 + 1024 + col], acc[mt][nt][v] + bias);
        }
    }
  } else {
    int r = bid - 56;
    int nb = r & 1, s = (r >> 1) & 1, kc = r >> 2;
    int colb = nb*256 + w*64;
    int k0 = kc*512;
    const float* bi = s ? b_obj : b_subj;
    f4v acc[7][4] = {};
    for (int kst = 0; kst < 16; ++kst){
      int koff = k0 + kst*32 + lhi*8;
      s8v Bf[4];
      #pragma unroll
      for (int nt = 0; nt < 4; ++nt)
        Bf[nt] = *(const s8v*)&wsoT[(size_t)(s*512 + colb + nt*16 + l15)*2048 + koff];
      #pragma unroll
      for (int mt = 0; mt < 7; ++mt){
        int row = mt*16 + l15; row = row < B ? row : 0;
        s8v A = *(const s8v*)&pfbf[(size_t)(s*100 + row)*2048 + koff];
        #pragma unroll
        for (int nt = 0; nt < 4; ++nt)
          acc[mt][nt] = mfma16(A, Bf[nt], acc[mt][nt]);
      }
    }
    #pragma unroll
    for (int nt = 0; nt < 4; ++nt){
      int col = colb + nt*16 + l15;
      float bias = (kc == 0) ? bi[col] : 0.f;
      #pragma unroll
      for (int mt = 0; mt < 7; ++mt)
        #pragma unroll
        for (int v = 0; v < 4; ++v){
          int row = mt*16 + lhi*4 + v;
          if (row < B) atomicAdd(&px[row*1536 + s*512 + col], acc[mt][nt][v] + bias);
        }
    }
  }
}

// ============ MLP m1: [112,1536]@[1536,2048], k-split atomics, f32 A inline-cast ============
__global__ __launch_bounds__(256) void k_m1(const float* __restrict__ px, const u16* __restrict__ wm1T,
                                            float* __restrict__ h, int B){
  int nb = blockIdx.x, kc = blockIdx.y, t = threadIdx.x;
  int lane = t & 63, w = t >> 6;
  int l15 = lane & 15, lhi = lane >> 4;
  int colb = nb*256 + w*64;
  int k0 = kc*384;
  f4v acc[7][4] = {};
  for (int kst = 0; kst < 12; ++kst){
    int koff = k0 + kst*32 + lhi*8;
    s8v Bf[4];
    #pragma unroll
    for (int nt = 0; nt < 4; ++nt)
      Bf[nt] = *(const s8v*)&wm1T[(size_t)(colb + nt*16 + l15)*1536 + koff];
    #pragma unroll
    for (int mt = 0; mt < 7; ++mt){
      const float* ap = px + (size_t)(mt*16 + l15)*1536 + koff;
      f4v lo = *(const f4v*)ap;
      f4v hi = *(const f4v*)(ap + 4);
      s8v A;
      A[0] = (short)f2b(lo[0]); A[1] = (short)f2b(lo[1]);
      A[2] = (short)f2b(lo[2]); A[3] = (short)f2b(lo[3]);
      A[4] = (short)f2b(hi[0]); A[5] = (short)f2b(hi[1]);
      A[6] = (short)f2b(hi[2]); A[7] = (short)f2b(hi[3]);
      #pragma unroll
      for (int nt = 0; nt < 4; ++nt)
        acc[mt][nt] = mfma16(A, Bf[nt], acc[mt][nt]);
    }
  }
  #pragma unroll
  for (int nt = 0; nt < 4; ++nt){
    int col = colb + nt*16 + l15;
    #pragma unroll
    for (int mt = 0; mt < 7; ++mt)
      #pragma unroll
      for (int v = 0; v < 4; ++v){
        int row = mt*16 + lhi*4 + v;
        if (row < B) atomicAdd(&h[row*2048 + col], acc[mt][nt][v]);
      }
  }
}

// ============ m2 + bias1/relu + sigmoid, in-block k-split x2 ============
__global__ __launch_bounds__(512) void k_m2(const float* __restrict__ h, const float* __restrict__ bm1,
                                            const float* __restrict__ w_m2, const float* __restrict__ b_m2,
                                            float* __restrict__ out){
  __shared__ float part[160];
  int b = blockIdx.x, t = threadIdx.x;
  int col = t & 255, kg = t >> 8;
  float acc = 0.f;
  if (col < 157){
    const float* hb = h + (size_t)b*2048;
    int k0 = kg*1024;
    for (int k = k0; k < k0 + 1024; ++k)
      acc += fmaxf(hb[k] + bm1[k], 0.f) * w_m2[(size_t)k*157 + col];
  }
  if (kg == 1 && col < 157) part[col] = acc;
  __syncthreads();
  if (kg == 0 && col < 157){
    float s = acc + part[col] + b_m2[col];
    out[b*157 + col] = 1.f/(1.f + expf(-s));
  }
}

extern "C" void kernel_launch(void* const* d_in, const int* in_sizes, int n_in,
                              void* d_out, int out_size, void* d_ws, size_t ws_size,
                              hipStream_t stream){
  const float* features   = (const float*)d_in[0];
  const float* union_feat = (const float*)d_in[1];
  const float* masks      = (const float*)d_in[2];
  const float* w_union    = (const float*)d_in[3];
  const float* b_union    = (const float*)d_in[4];
  const float* w_c1       = (const float*)d_in[5];
  const float* b_c1       = (const float*)d_in[6];
  const float* g_bn1      = (const float*)d_in[7];
  const float* be_bn1     = (const float*)d_in[8];
  const float* w_c2       = (const float*)d_in[9];
  const float* b_c2       = (const float*)d_in[10];
  const float* g_bn2      = (const float*)d_in[11];
  const float* be_bn2     = (const float*)d_in[12];
  const float* w_subj     = (const float*)d_in[13];
  const float* b_subj     = (const float*)d_in[14];
  const float* w_obj      = (const float*)d_in[15];
  const float* b_obj      = (const float*)d_in[16];
  const float* w_vr       = (const float*)d_in[17];
  const float* b_vr       = (const float*)d_in[18];
  const float* w_m1       = (const float*)d_in[19];
  const float* b_m1       = (const float*)d_in[20];
  const float* w_m2       = (const float*)d_in[21];
  const float* b_m2       = (const float*)d_in[22];
  const int* pair_idx     = (const int*)d_in[23];
  const int* im_idx       = (const int*)d_in[24];
  float* out = (float*)d_out;
  const int P = in_sizes[24];
  const int B = out_size/157;

  char* ws = (char*)d_ws;
  size_t off = 0;
  auto alloc = [&](size_t bytes)->size_t{ size_t o = off; off += (bytes + 255) & ~(size_t)255; return o; };
  // zero-region (one memset): stats | segr | px | h
  size_t o_stats= alloc(3072);
  size_t o_segr = alloc((size_t)B*256*49*4);
  size_t o_px   = alloc((size_t)112*1536*4);
  size_t o_h    = alloc((size_t)B*2048*4);
  size_t zero_end = off;
  size_t o_muT  = alloc((size_t)B*49*1024*2);
  size_t o_spool= alloc((size_t)P*49*128*2);
  size_t o_w1t  = alloc(128*128*2);
  size_t o_w2f  = alloc(9*256*128*2);
  size_t o_wuT  = alloc(256*1024*2);
  size_t o_wvrT = alloc((size_t)512*12544*2);
  size_t o_wm1T = alloc((size_t)2048*1536*2);
  size_t o_wsoT = alloc((size_t)1024*2048*2);
  size_t o_pfbf = alloc((size_t)200*2048*2);
  size_t o_tbf  = alloc((size_t)112*12544*2);
  (void)ws_size; (void)n_in;

  float* stats1 = (float*)(ws + o_stats);
  float* stats2 = stats1 + 256;
  u16*   muT    = (u16*)(ws + o_muT);
  u16*   spool  = (u16*)(ws + o_spool);
  u16*   w1tp   = (u16*)(ws + o_w1t);
  u16*   w2f    = (u16*)(ws + o_w2f);
  u16*   wuT    = (u16*)(ws + o_wuT);
  u16*   wvrT   = (u16*)(ws + o_wvrT);
  u16*   wm1T   = (u16*)(ws + o_wm1T);
  u16*   wsoT   = (u16*)(ws + o_wsoT);
  u16*   pfbf   = (u16*)(ws + o_pfbf);
  float* segr   = (float*)(ws + o_segr);
  u16*   tbf    = (u16*)(ws + o_tbf);
  float* px     = (float*)(ws + o_px);
  float* h      = (float*)(ws + o_h);

  hipMemsetAsync(ws, 0, zero_end, stream);

  k_misc<<<5288, dim3(256), 0, stream>>>(features, pair_idx, im_idx, w_c1, w_c2, w_union,
                                         w_vr, w_m1, w_subj, w_obj,
                                         w1tp, w2f, wuT, wvrT, wm1T, wsoT, pfbf, P);
  k_conv1<<<dim3(P, 2), dim3(256), 0, stream>>>(masks, w1tp, b_c1, stats1, spool);
  k_c2up<<<3600, dim3(256), 0, stream>>>(spool, w2f, b_c2, g_bn1, be_bn1, stats1, im_idx,
                                         segr, stats2, P, 1.f/((float)P*196.f),
                                         union_feat, muT);
  k_combine<<<B, dim3(256), 0, stream>>>(muT, wuT, b_union, segr, stats2, g_bn2, be_bn2, im_idx,
                                         tbf, P, 1.f/((float)P*49.f));
  k_mega3<<<72, dim3(256), 0, stream>>>(tbf, wvrT, b_vr, pfbf, wsoT, b_subj, b_obj, px, B);
  k_m1<<<dim3(8, 4), dim3(256), 0, stream>>>(px, wm1T, h, B);
  k_m2<<<B, dim3(512), 0, stream>>>(h, b_m1, w_m2, b_m2, out);
}

// Round 17
// 1167.218 us; speedup vs baseline: 1.2449x; 1.0012x over previous
//
#include <hip/hip_runtime.h>

typedef unsigned short u16;
typedef unsigned int   u32;
typedef short s8v __attribute__((ext_vector_type(8)));   // 8 x bf16 MFMA operand
typedef float f4v __attribute__((ext_vector_type(4)));   // MFMA accumulator

#define DEV __device__ __forceinline__

DEV u16 f2b(float f){
  u32 x = __builtin_bit_cast(u32, f);
  u32 r = x + 0x7fffu + ((x >> 16) & 1u);
  return (u16)(r >> 16);
}
DEV float b2f(u16 u){ u32 x = ((u32)u) << 16; return __builtin_bit_cast(float, x); }
DEV f4v mfma16(s8v a, s8v b, f4v c){ return __builtin_amdgcn_mfma_f32_16x16x32_bf16(a, b, c, 0, 0, 0); }

DEV void segrange(const int* __restrict__ im, int P, int b, int& s0, int& s1){
  int lo = 0, hi = P;
  while (lo < hi){ int m = (lo + hi) >> 1; if (im[m] < b) lo = m + 1; else hi = m; }
  s0 = lo;
  int lo2 = lo; hi = P;
  while (lo2 < hi){ int m = (lo2 + hi) >> 1; if (im[m] < b + 1) lo2 = m + 1; else hi = m; }
  s1 = lo2;
}

DEV void transpose_body(const float* __restrict__ src, u16* __restrict__ dst,
                        int R, int C, int rb, int cb, int t, float* tile){
  int r0 = rb << 6, c0 = cb << 6;
  for (int i = t; i < 4096; i += 256){
    int rl = i >> 6, cl = i & 63;
    tile[rl*65 + cl] = src[(size_t)(r0 + rl)*C + c0 + cl];
  }
  __syncthreads();
  for (int i = t; i < 4096; i += 256){
    int cl = i >> 6, rl = i & 63;
    dst[(size_t)(c0 + cl)*R + r0 + rl] = f2b(tile[rl*65 + cl]);
  }
}

// ============ k_misc: conv1 [0,2P) + featpool + weight transforms (block segments shifted) ============
// conv1 computes its B-panel inline from w_c1 (50KB, L1-hot): k'=ic*64+ky*8+kx maps a fragment to
// 7 contiguous floats (kx=j); ic=kst>>1, ky=(kst*4+lhi)&7, bf[7]=0 pad. No w1tp pass.
__global__ __launch_bounds__(256) void k_misc(
    const float* __restrict__ feat, const int* __restrict__ pidx, const int* __restrict__ im_idx,
    const float* __restrict__ w_c1, const float* __restrict__ w_c2, const float* __restrict__ w_u,
    const float* __restrict__ w_vr, const float* __restrict__ w_m1,
    const float* __restrict__ w_subj, const float* __restrict__ w_obj,
    const float* __restrict__ masks, const float* __restrict__ b1,
    float* __restrict__ stats1, u16* __restrict__ spool,
    u16* __restrict__ w2f, u16* __restrict__ wuT,
    u16* __restrict__ wvrT, u16* __restrict__ wm1T, u16* __restrict__ wsoT,
    u16* __restrict__ pfbf, int P){
  __shared__ u32 smem32[8192];             // conv1: lds32[1400] + s1n 25KB | transpose: 16.6KB
  int bid = blockIdx.x, t = threadIdx.x;
  int c1n = 2*P;                           // conv1 block count (10000)
  if (bid < c1n){
    // ---------------- conv1 v2 (7x7 s2 p3, 2->128), weights inline from w_c1 ----------------
    u32* lds32 = smem32;                   // in_bf [2][34][40] u16 (1360 u32 + 40 slack)
    u16* s1n = (u16*)&smem32[1408];        // [64 oc][196 pix], post-relu PRE-BN
    int p = bid >> 1, z = bid & 1;
    int lane = t & 63, w = t >> 6;
    int l15 = lane & 15, lhi = lane >> 4;
    int ocl = w*16 + l15;
    int oc  = z*64 + ocl;
    s8v Bf[4];
    #pragma unroll
    for (int kst = 0; kst < 4; ++kst){
      int ic = kst >> 1;
      int ky = (kst*4 + lhi) & 7;
      s8v bf = {};
      if (ky < 7){
        const float* wsrc = w_c1 + oc*98 + ic*49 + ky*7;
        #pragma unroll
        for (int j = 0; j < 7; ++j) bf[j] = (short)f2b(wsrc[j]);
      }
      Bf[kst] = bf;
    }
    for (int i = t; i < 1400; i += 256) lds32[i] = 0;
    __syncthreads();
    u16* in_bf = (u16*)lds32;
    for (int e = t; e < 1458; e += 256){
      int c = e >= 729; int r = e - c*729;
      int rr = r/27, cc = r - rr*27;
      in_bf[c*1360 + (rr + 3)*40 + cc + 3] = f2b(masks[(size_t)p*1458 + e]);
    }
    int rb[13];
    #pragma unroll
    for (int mt = 0; mt < 13; ++mt){
      int pix = mt*16 + l15;
      int oy = pix/14, ox = pix - oy*14;
      rb[mt] = oy*40 + ox;
    }
    __syncthreads();
    f4v acc[13] = {};
    #pragma unroll
    for (int kst = 0; kst < 4; ++kst){
      int kk = kst*32 + lhi*8;
      int kbase = (kk >> 6)*680 + ((kk >> 3) & 7)*20;
      #pragma unroll
      for (int mt = 0; mt < 13; ++mt){
        int a = kbase + rb[mt];
        union { u32 u[4]; s8v v; } cv;
        cv.u[0] = lds32[a];   cv.u[1] = lds32[a+1];
        cv.u[2] = lds32[a+2]; cv.u[3] = lds32[a+3];
        acc[mt] = mfma16(cv.v, Bf[kst], acc[mt]);
      }
    }
    float bias = b1[oc];
    float ss = 0.f, qq = 0.f;
    #pragma unroll
    for (int mt = 0; mt < 13; ++mt)
      #pragma unroll
      for (int v = 0; v < 4; ++v){
        int pix = mt*16 + lhi*4 + v;
        if (pix < 196){
          float r = fmaxf(acc[mt][v] + bias, 0.f);
          ss += r; qq += r*r;
          s1n[ocl*196 + pix] = f2b(r);
        }
      }
    ss += __shfl_xor(ss, 16); ss += __shfl_xor(ss, 32);
    qq += __shfl_xor(qq, 16); qq += __shfl_xor(qq, 32);
    if (lane < 16){
      atomicAdd(&stats1[z*64 + w*16 + lane], ss);
      atomicAdd(&stats1[128 + z*64 + w*16 + lane], qq);
    }
    __syncthreads();
    {  // maxpool 3x3 s2 p1, u16-bit-compare (relu => monotone), u32-pair reads
      int ocp = t & 63, pg = t >> 6;
      const u32* row32 = (const u32*)s1n;
      for (int pp = pg; pp < 49; pp += 4){
        int poy = pp/7, pox = pp - poy*7;
        u32 m = 0;
        #pragma unroll
        for (int dy = 0; dy < 3; ++dy){
          int iy = poy*2 - 1 + dy;
          if (iy < 0 || iy > 13) continue;
          int widx = ocp*98 + iy*7 + pox;
          u32 wB = row32[widx];
          u32 c1 = wB & 0xffffu, c2 = wB >> 16;
          m = c1 > m ? c1 : m;
          m = c2 > m ? c2 : m;
          if (pox > 0){
            u32 c0 = row32[widx - 1] >> 16;
            m = c0 > m ? c0 : m;
          }
        }
        spool[((size_t)p*49 + pp)*128 + z*64 + ocp] = (u16)m;
      }
    }
  } else if (bid < c1n + 200){
    int i = bid - c1n; int s = i/100, b = i - s*100;
    int s0, s1; segrange(im_idx, P, b, s0, s1);
    float inv = 1.f / fmaxf((float)(s1 - s0), 1.f);
    f4v a0 = {}, a1 = {};
    for (int p = s0; p < s1; ++p){
      int row = pidx[p*2 + s];
      const f4v* src = (const f4v*)(feat + (size_t)row*2048);
      a0 += src[t]; a1 += src[t+256];
    }
    u16* dst = pfbf + (size_t)(s*100 + b)*2048;
    #pragma unroll
    for (int j = 0; j < 4; ++j){
      dst[4*t + j]        = f2b(a0[j]*inv);
      dst[1024 + 4*t + j] = f2b(a1[j]*inv);
    }
  } else if (bid < c1n + 1352){
    int i = (bid - (c1n + 200))*256 + t;   // fragment-packed conv2 weights
    int frag = i >> 9, r = i & 511;
    int lane = r >> 3, j = r & 7;
    int kst = frag & 3, og = (frag >> 2) & 15, tap = frag >> 6;
    int oc = og*16 + (lane & 15);
    int k  = kst*32 + (lane >> 4)*8 + j;
    w2f[i] = f2b(w_c2[((size_t)(oc*128 + k))*9 + tap]);
  } else if (bid < c1n + 2376){
    int i = (bid - (c1n + 1352))*256 + t;
    wuT[i] = f2b(w_u[i]);
  } else if (bid < c1n + 3944){
    int idx = bid - (c1n + 2376);          // 196*8
    transpose_body(w_vr, wvrT, 12544, 512, idx >> 3, idx & 7, t, (float*)smem32);
  } else if (bid < c1n + 4712){
    int idx = bid - (c1n + 3944);          // 24*32
    transpose_body(w_m1, wm1T, 1536, 2048, idx >> 5, idx & 31, t, (float*)smem32);
  } else {
    int idx = bid - (c1n + 4712);          // 2 * 32*8
    int sel = idx >> 8; idx &= 255;
    transpose_body(sel ? w_obj : w_subj, wsoT + (size_t)sel*512*2048,
                   2048, 512, idx >> 3, idx & 7, t, (float*)smem32);
  }
}

// ============ k_c2up: conv2 v8 UNION upool, q=10 (5-pair blocks: less tail), 2:7 interleave ============
__global__ __launch_bounds__(256) void k_c2up(
    const u16* __restrict__ spool, const u16* __restrict__ w2f, const float* __restrict__ b2,
    const float* __restrict__ g1, const float* __restrict__ be1,
    const float* __restrict__ stats1, const int* __restrict__ im_idx,
    float* __restrict__ segr, float* __restrict__ stats2, int P, float invN1,
    const float* __restrict__ uf, u16* __restrict__ muT){
  __shared__ u16 raw[2*82*128 + 512];      // conv2: inT dbuf + sc1/sh1 | upool: 3136 f32
  int bid = blockIdx.x, t = threadIdx.x;
  int g = bid/7, r7 = bid - g*7;

  if (r7 < 2){
    // ---------- upool: u = g*2 + r7; block (b, icb) pools 64 channels ----------
    float* smem = (float*)raw;
    int u = g*2 + r7;
    int b = u >> 4, icb = u & 15;
    int s0, s1; segrange(im_idx, P, b, s0, s1);
    float inv = 1.f / fmaxf((float)(s1 - s0), 1.f);
    f4v a0 = {}, a1 = {}, a2 = {}, a3 = {};
    int p = s0;
    for (; p + 1 < s1; p += 2){
      const f4v* x = (const f4v*)(uf + (size_t)p*50176 + icb*3136);
      const f4v* y = (const f4v*)(uf + (size_t)(p+1)*50176 + icb*3136);
      a0 += x[t] + y[t]; a1 += x[t+256] + y[t+256]; a2 += x[t+512] + y[t+512];
      if (t < 16) a3 += x[t+768] + y[t+768];
    }
    if (p < s1){
      const f4v* x = (const f4v*)(uf + (size_t)p*50176 + icb*3136);
      a0 += x[t]; a1 += x[t+256]; a2 += x[t+512];
      if (t < 16) a3 += x[t+768];
    }
    *(f4v*)&smem[4*t] = a0;
    *(f4v*)&smem[4*(t+256)] = a1;
    *(f4v*)&smem[4*(t+512)] = a2;
    if (t < 16) *(f4v*)&smem[4*(t+768)] = a3;
    __syncthreads();
    for (int o = t; o < 3136; o += 256){
      int pix = o >> 6, ics = o & 63;
      muT[(size_t)(b*49 + pix)*1024 + (icb<<6) + ics] = f2b(smem[ics*49 + pix]*inv);
    }
    return;
  }

  // ---------- conv2: idx = g*5 + (r7-2); b = idx/40, q = (idx%40)>>2 (0..9), z = idx&3 ----------
  int idx = g*5 + (r7 - 2);
  int b = idx/40, rem = idx - b*40;
  int q = rem >> 2, z = rem & 3;
  float* sc1 = (float*)&raw[2*82*128];
  float* sh1 = sc1 + 128;
  int lane = t & 63, w = t >> 6;
  int l15 = lane & 15, lhi = lane >> 4;
  int og = z*4 + w;                        // this wave's 16-oc group
  int oc = og*16 + l15;
  s8v Bf[9][4];                            // whole B panel for this wave: 144 VGPR, loaded once
  #pragma unroll
  for (int tap = 0; tap < 9; ++tap)
    #pragma unroll
    for (int kst = 0; kst < 4; ++kst)
      Bf[tap][kst] = *(const s8v*)&w2f[((((size_t)tap*16 + og)*4 + kst) << 9) + lane*8];
  {
    f4v zv = {}; f4v* a4 = (f4v*)raw;
    for (int i = t; i < 2624; i += 256) a4[i] = zv;
  }
  if (t < 128){                            // folded bnfin1
    float mean = stats1[t]*invN1;
    float var  = stats1[128 + t]*invN1 - mean*mean;
    float sc = g1[t]*rsqrtf(var + 1e-5f);
    sc1[t] = sc; sh1[t] = be1[t] - mean*sc;
  }
  int s0, s1; segrange(im_idx, P, b, s0, s1);
  int cnt = s1 - s0, chunk = (cnt + 9)/10;
  int p0 = s0 + q*chunk, p1 = min(p0 + chunk, s1);
  if (p0 >= p1) return;
  int rowm[4]; bool okm[4];
  #pragma unroll
  for (int mt = 0; mt < 4; ++mt){
    int pix = mt*16 + l15;
    okm[mt] = pix < 49;
    int py = pix/7, px = pix - py*7;
    rowm[mt] = okm[mt] ? (py + 1)*9 + px + 1 : 81;
  }
  float bias = b2[oc];
  f4v segacc[4] = {};
  float ssum = 0.f, ssq = 0.f;
  u32 r13[13];
  const u32* sp32 = (const u32*)spool;
  auto LOADR = [&](int p){
    #pragma unroll
    for (int j = 0; j < 13; ++j){
      int i = j*256 + t;
      r13[j] = (i < 3136) ? sp32[(size_t)p*3136 + i] : 0u;
    }
  };
  auto WRITE = [&](int bb){
    u32* d = (u32*)&raw[bb*82*128];
    #pragma unroll
    for (int j = 0; j < 13; ++j){
      int i = j*256 + t;
      if (i < 3136){
        int pix = i >> 6, icp = i & 63;
        u32 v = r13[j];
        float lo = b2f((u16)v)*sc1[icp*2]          + sh1[icp*2];
        float hi = b2f((u16)(v >> 16))*sc1[icp*2+1] + sh1[icp*2+1];
        int py = pix/7;
        int row = (py + 1)*9 + (pix - py*7) + 1;
        d[(row*64 + icp) ^ ((row & 7) << 2)] = (u32)f2b(lo) | ((u32)f2b(hi) << 16);
      }
    }
  };
  LOADR(p0);
  __syncthreads();                         // zero-init + sc1 visible before first WRITE
  WRITE(0);
  int cur = 0;
  for (int p = p0; p < p1; ++p){
    __syncthreads();                       // buf[cur] writes visible to all
    if (p + 1 < p1) LOADR(p + 1);          // issue global prefetch: hides under MFMA
    f4v pacc[4] = {};
    const u16* buf = &raw[cur*82*128];
    #pragma unroll
    for (int tap = 0; tap < 9; ++tap){
      int doff = (tap/3 - 1)*9 + (tap%3 - 1);
      int rr[4];
      #pragma unroll
      for (int mt = 0; mt < 4; ++mt)
        rr[mt] = okm[mt] ? rowm[mt] + doff : 81;
      #pragma unroll
      for (int kst = 0; kst < 4; ++kst){
        int koff = kst*32 + lhi*8;
        #pragma unroll
        for (int mt = 0; mt < 4; ++mt){
          s8v A = *(const s8v*)&buf[(rr[mt]*128 + koff) ^ ((rr[mt] & 7) << 3)];
          pacc[mt] = mfma16(A, Bf[tap][kst], pacc[mt]);
        }
      }
    }
    #pragma unroll
    for (int mt = 0; mt < 4; ++mt)
      #pragma unroll
      for (int v = 0; v < 4; ++v){
        int pix = mt*16 + lhi*4 + v;
        float r = fmaxf(pacc[mt][v] + bias, 0.f);
        r = (pix < 49) ? r : 0.f;
        segacc[mt][v] += r;
        ssum += r; ssq += r*r;
      }
    if (p + 1 < p1) WRITE(cur ^ 1);        // other buffer: safe, readers passed barrier
    cur ^= 1;
  }
  #pragma unroll
  for (int mt = 0; mt < 4; ++mt)
    #pragma unroll
    for (int v = 0; v < 4; ++v){
      int pix = mt*16 + lhi*4 + v;
      if (pix < 49)
        atomicAdd(&segr[(size_t)(b*256 + oc)*49 + pix], segacc[mt][v]);
    }
  float s = ssum, qd = ssq;
  s  += __shfl_xor(s, 16);  s  += __shfl_xor(s, 32);
  qd += __shfl_xor(qd, 16); qd += __shfl_xor(qd, 32);
  if (lane < 16){
    atomicAdd(&stats2[og*16 + lane], s);
    atomicAdd(&stats2[256 + og*16 + lane], qd);
  }
}

// ============ combine: union 1x1 conv + bn2(seg-mean relu2) -> tbf ============
__global__ __launch_bounds__(256) void k_combine(const u16* __restrict__ muT, const u16* __restrict__ wuT,
                                                 const float* __restrict__ b_u, const float* __restrict__ segr,
                                                 const float* __restrict__ stats2,
                                                 const float* __restrict__ g2, const float* __restrict__ be2,
                                                 const int* __restrict__ im_idx, u16* __restrict__ tbf,
                                                 int P, float invN2){
  __shared__ float sc2[256], sh2[256];
  int b = blockIdx.x, t = threadIdx.x;
  int lane = t & 63, w = t >> 6;
  int l15 = lane & 15, lhi = lane >> 4;
  {
    float mean = stats2[t]*invN2;
    float var  = stats2[256 + t]*invN2 - mean*mean;
    float sc = g2[t]*rsqrtf(var + 1e-5f);
    sc2[t] = sc; sh2[t] = be2[t] - mean*sc;
  }
  __syncthreads();
  int s0, s1; segrange(im_idx, P, b, s0, s1);
  float inv = 1.f / fmaxf((float)(s1 - s0), 1.f);
  int ocb = w*64;
  const u16* arow[4];
  #pragma unroll
  for (int mt = 0; mt < 4; ++mt){
    int pix = mt*16 + l15;
    arow[mt] = muT + (size_t)(b*49 + (pix < 49 ? pix : 0))*1024;
  }
  f4v acc[4][4] = {};
  for (int kst = 0; kst < 32; ++kst){
    int koff = kst*32 + lhi*8;
    s8v Bf[4];
    #pragma unroll
    for (int nt = 0; nt < 4; ++nt)
      Bf[nt] = *(const s8v*)&wuT[(ocb + nt*16 + l15)*1024 + koff];
    #pragma unroll
    for (int mt = 0; mt < 4; ++mt){
      s8v A = *(const s8v*)&arow[mt][koff];
      #pragma unroll
      for (int nt = 0; nt < 4; ++nt)
        acc[mt][nt] = mfma16(A, Bf[nt], acc[mt][nt]);
    }
  }
  #pragma unroll
  for (int nt = 0; nt < 4; ++nt){
    int oc = ocb + nt*16 + l15;
    float bu = b_u[oc], sc = sc2[oc], sh = sh2[oc];
    #pragma unroll
    for (int mt = 0; mt < 4; ++mt)
      #pragma unroll
      for (int v = 0; v < 4; ++v){
        int pix = mt*16 + lhi*4 + v;
        if (pix < 49){
          float val = acc[mt][nt][v] + bu + sc*segr[(size_t)(b*256 + oc)*49 + pix]*inv + sh;
          tbf[(size_t)b*12544 + oc*49 + pix] = f2b(val);
        }
      }
  }
}

// ============ mega3: vr GEMM (56 blocks) UNION subj/obj GEMM (16 blocks) ============
__global__ __launch_bounds__(256) void k_mega3(const u16* __restrict__ tbf, const u16* __restrict__ wvrT,
                                               const float* __restrict__ b_vr,
                                               const u16* __restrict__ pfbf, const u16* __restrict__ wsoT,
                                               const float* __restrict__ b_subj, const float* __restrict__ b_obj,
                                               float* __restrict__ px, int B){
  int bid = blockIdx.x, t = threadIdx.x;
  int lane = t & 63, w = t >> 6;
  int l15 = lane & 15, lhi = lane >> 4;
  if (bid < 56){
    int nb = bid & 1, kc = bid >> 1;
    int colb = nb*256 + w*64;
    int k0 = kc*448;
    f4v acc[7][4] = {};
    for (int kst = 0; kst < 14; ++kst){
      int koff = k0 + kst*32 + lhi*8;
      s8v Bf[4];
      #pragma unroll
      for (int nt = 0; nt < 4; ++nt)
        Bf[nt] = *(const s8v*)&wvrT[(size_t)(colb + nt*16 + l15)*12544 + koff];
      #pragma unroll
      for (int mt = 0; mt < 7; ++mt){
        s8v A = *(const s8v*)&tbf[(size_t)(mt*16 + l15)*12544 + koff];
        #pragma unroll
        for (int nt = 0; nt < 4; ++nt)
          acc[mt][nt] = mfma16(A, Bf[nt], acc[mt][nt]);
      }
    }
    #pragma unroll
    for (int nt = 0; nt < 4; ++nt){
      int col = colb + nt*16 + l15;
      float bias = (kc == 0) ? b_vr[col] : 0.f;
      #pragma unroll
      for (int mt = 0; mt < 7; ++mt)
        #pragma unroll
        for (int v = 0; v < 4; ++v){
          int row = mt*16 + lhi*4 + v;
          if (row < B) atomicAdd(&px[row*1536 + 1024 + col], acc[mt][nt][v] + bias);
        }
    }
  } else {
    int r = bid - 56;
    int nb = r & 1, s = (r >> 1) & 1, kc = r >> 2;
    int colb = nb*256 + w*64;
    int k0 = kc*512;
    const float* bi = s ? b_obj : b_subj;
    f4v acc[7][4] = {};
    for (int kst = 0; kst < 16; ++kst){
      int koff = k0 + kst*32 + lhi*8;
      s8v Bf[4];
      #pragma unroll
      for (int nt = 0; nt < 4; ++nt)
        Bf[nt] = *(const s8v*)&wsoT[(size_t)(s*512 + colb + nt*16 + l15)*2048 + koff];
      #pragma unroll
      for (int mt = 0; mt < 7; ++mt){
        int row = mt*16 + l15; row = row < B ? row : 0;
        s8v A = *(const s8v*)&pfbf[(size_t)(s*100 + row)*2048 + koff];
        #pragma unroll
        for (int nt = 0; nt < 4; ++nt)
          acc[mt][nt] = mfma16(A, Bf[nt], acc[mt][nt]);
      }
    }
    #pragma unroll
    for (int nt = 0; nt < 4; ++nt){
      int col = colb + nt*16 + l15;
      float bias = (kc == 0) ? bi[col] : 0.f;
      #pragma unroll
      for (int mt = 0; mt < 7; ++mt)
        #pragma unroll
        for (int v = 0; v < 4; ++v){
          int row = mt*16 + lhi*4 + v;
          if (row < B) atomicAdd(&px[row*1536 + s*512 + col], acc[mt][nt][v] + bias);
        }
    }
  }
}

// ============ MLP m1: [112,1536]@[1536,2048], k-split atomics, f32 A inline-cast ============
__global__ __launch_bounds__(256) void k_m1(const float* __restrict__ px, const u16* __restrict__ wm1T,
                                            float* __restrict__ h, int B){
  int nb = blockIdx.x, kc = blockIdx.y, t = threadIdx.x;
  int lane = t & 63, w = t >> 6;
  int l15 = lane & 15, lhi = lane >> 4;
  int colb = nb*256 + w*64;
  int k0 = kc*384;
  f4v acc[7][4] = {};
  for (int kst = 0; kst < 12; ++kst){
    int koff = k0 + kst*32 + lhi*8;
    s8v Bf[4];
    #pragma unroll
    for (int nt = 0; nt < 4; ++nt)
      Bf[nt] = *(const s8v*)&wm1T[(size_t)(colb + nt*16 + l15)*1536 + koff];
    #pragma unroll
    for (int mt = 0; mt < 7; ++mt){
      const float* ap = px + (size_t)(mt*16 + l15)*1536 + koff;
      f4v lo = *(const f4v*)ap;
      f4v hi = *(const f4v*)(ap + 4);
      s8v A;
      A[0] = (short)f2b(lo[0]); A[1] = (short)f2b(lo[1]);
      A[2] = (short)f2b(lo[2]); A[3] = (short)f2b(lo[3]);
      A[4] = (short)f2b(hi[0]); A[5] = (short)f2b(hi[1]);
      A[6] = (short)f2b(hi[2]); A[7] = (short)f2b(hi[3]);
      #pragma unroll
      for (int nt = 0; nt < 4; ++nt)
        acc[mt][nt] = mfma16(A, Bf[nt], acc[mt][nt]);
    }
  }
  #pragma unroll
  for (int nt = 0; nt < 4; ++nt){
    int col = colb + nt*16 + l15;
    #pragma unroll
    for (int mt = 0; mt < 7; ++mt)
      #pragma unroll
      for (int v = 0; v < 4; ++v){
        int row = mt*16 + lhi*4 + v;
        if (row < B) atomicAdd(&h[row*2048 + col], acc[mt][nt][v]);
      }
  }
}

// ============ m2 + bias1/relu + sigmoid, in-block k-split x2 ============
__global__ __launch_bounds__(512) void k_m2(const float* __restrict__ h, const float* __restrict__ bm1,
                                            const float* __restrict__ w_m2, const float* __restrict__ b_m2,
                                            float* __restrict__ out){
  __shared__ float part[160];
  int b = blockIdx.x, t = threadIdx.x;
  int col = t & 255, kg = t >> 8;
  float acc = 0.f;
  if (col < 157){
    const float* hb = h + (size_t)b*2048;
    int k0 = kg*1024;
    for (int k = k0; k < k0 + 1024; ++k)
      acc += fmaxf(hb[k] + bm1[k], 0.f) * w_m2[(size_t)k*157 + col];
  }
  if (kg == 1 && col < 157) part[col] = acc;
  __syncthreads();
  if (kg == 0 && col < 157){
    float s = acc + part[col] + b_m2[col];
    out[b*157 + col] = 1.f/(1.f + expf(-s));
  }
}

extern "C" void kernel_launch(void* const* d_in, const int* in_sizes, int n_in,
                              void* d_out, int out_size, void* d_ws, size_t ws_size,
                              hipStream_t stream){
  const float* features   = (const float*)d_in[0];
  const float* union_feat = (const float*)d_in[1];
  const float* masks      = (const float*)d_in[2];
  const float* w_union    = (const float*)d_in[3];
  const float* b_union    = (const float*)d_in[4];
  const float* w_c1       = (const float*)d_in[5];
  const float* b_c1       = (const float*)d_in[6];
  const float* g_bn1      = (const float*)d_in[7];
  const float* be_bn1     = (const float*)d_in[8];
  const float* w_c2       = (const float*)d_in[9];
  const float* b_c2       = (const float*)d_in[10];
  const float* g_bn2      = (const float*)d_in[11];
  const float* be_bn2     = (const float*)d_in[12];
  const float* w_subj     = (const float*)d_in[13];
  const float* b_subj     = (const float*)d_in[14];
  const float* w_obj      = (const float*)d_in[15];
  const float* b_obj      = (const float*)d_in[16];
  const float* w_vr       = (const float*)d_in[17];
  const float* b_vr       = (const float*)d_in[18];
  const float* w_m1       = (const float*)d_in[19];
  const float* b_m1       = (const float*)d_in[20];
  const float* w_m2       = (const float*)d_in[21];
  const float* b_m2       = (const float*)d_in[22];
  const int* pair_idx     = (const int*)d_in[23];
  const int* im_idx       = (const int*)d_in[24];
  float* out = (float*)d_out;
  const int P = in_sizes[24];
  const int B = out_size/157;

  char* ws = (char*)d_ws;
  size_t off = 0;
  auto alloc = [&](size_t bytes)->size_t{ size_t o = off; off += (bytes + 255) & ~(size_t)255; return o; };
  // zero-region (one memset): stats | segr | px | h
  size_t o_stats= alloc(3072);
  size_t o_segr = alloc((size_t)B*256*49*4);
  size_t o_px   = alloc((size_t)112*1536*4);
  size_t o_h    = alloc((size_t)B*2048*4);
  size_t zero_end = off;
  size_t o_muT  = alloc((size_t)B*49*1024*2);
  size_t o_spool= alloc((size_t)P*49*128*2);
  size_t o_w2f  = alloc(9*256*128*2);
  size_t o_wuT  = alloc(256*1024*2);
  size_t o_wvrT = alloc((size_t)512*12544*2);
  size_t o_wm1T = alloc((size_t)2048*1536*2);
  size_t o_wsoT = alloc((size_t)1024*2048*2);
  size_t o_pfbf = alloc((size_t)200*2048*2);
  size_t o_tbf  = alloc((size_t)112*12544*2);
  (void)ws_size; (void)n_in;

  float* stats1 = (float*)(ws + o_stats);
  float* stats2 = stats1 + 256;
  u16*   muT    = (u16*)(ws + o_muT);
  u16*   spool  = (u16*)(ws + o_spool);
  u16*   w2f    = (u16*)(ws + o_w2f);
  u16*   wuT    = (u16*)(ws + o_wuT);
  u16*   wvrT   = (u16*)(ws + o_wvrT);
  u16*   wm1T   = (u16*)(ws + o_wm1T);
  u16*   wsoT   = (u16*)(ws + o_wsoT);
  u16*   pfbf   = (u16*)(ws + o_pfbf);
  float* segr   = (float*)(ws + o_segr);
  u16*   tbf    = (u16*)(ws + o_tbf);
  float* px     = (float*)(ws + o_px);
  float* h      = (float*)(ws + o_h);

  hipMemsetAsync(ws, 0, zero_end, stream);

  k_misc<<<2*P + 5224, dim3(256), 0, stream>>>(features, pair_idx, im_idx, w_c1, w_c2, w_union,
                                               w_vr, w_m1, w_subj, w_obj,
                                               masks, b_c1, stats1, spool,
                                               w2f, wuT, wvrT, wm1T, wsoT, pfbf, P);
  k_c2up<<<5600, dim3(256), 0, stream>>>(spool, w2f, b_c2, g_bn1, be_bn1, stats1, im_idx,
                                         segr, stats2, P, 1.f/((float)P*196.f),
                                         union_feat, muT);
  k_combine<<<B, dim3(256), 0, stream>>>(muT, wuT, b_union, segr, stats2, g_bn2, be_bn2, im_idx,
                                         tbf, P, 1.f/((float)P*49.f));
  k_mega3<<<72, dim3(256), 0, stream>>>(tbf, wvrT, b_vr, pfbf, wsoT, b_subj, b_obj, px, B);
  k_m1<<<dim3(8, 4), dim3(256), 0, stream>>>(px, wm1T, h, B);
  k_m2<<<B, dim3(512), 0, stream>>>(h, b_m1, w_m2, b_m2, out);
}

// Round 18
// 1108.210 us; speedup vs baseline: 1.3112x; 1.0532x over previous
//
#include <hip/hip_runtime.h>

typedef unsigned short u16;
typedef unsigned int   u32;
typedef short s8v __attribute__((ext_vector_type(8)));   // 8 x bf16 MFMA operand
typedef float f4v __attribute__((ext_vector_type(4)));   // MFMA accumulator

#define DEV __device__ __forceinline__

DEV u16 f2b(float f){
  u32 x = __builtin_bit_cast(u32, f);
  u32 r = x + 0x7fffu + ((x >> 16) & 1u);
  return (u16)(r >> 16);
}
DEV float b2f(u16 u){ u32 x = ((u32)u) << 16; return __builtin_bit_cast(float, x); }
DEV f4v mfma16(s8v a, s8v b, f4v c){ return __builtin_amdgcn_mfma_f32_16x16x32_bf16(a, b, c, 0, 0, 0); }

DEV void segrange(const int* __restrict__ im, int P, int b, int& s0, int& s1){
  int lo = 0, hi = P;
  while (lo < hi){ int m = (lo + hi) >> 1; if (im[m] < b) lo = m + 1; else hi = m; }
  s0 = lo;
  int lo2 = lo; hi = P;
  while (lo2 < hi){ int m = (lo2 + hi) >> 1; if (im[m] < b + 1) lo2 = m + 1; else hi = m; }
  s1 = lo2;
}

DEV void transpose_body(const float* __restrict__ src, u16* __restrict__ dst,
                        int R, int C, int rb, int cb, int t, float* tile){
  int r0 = rb << 6, c0 = cb << 6;
  for (int i = t; i < 4096; i += 256){
    int rl = i >> 6, cl = i & 63;
    tile[rl*65 + cl] = src[(size_t)(r0 + rl)*C + c0 + cl];
  }
  __syncthreads();
  for (int i = t; i < 4096; i += 256){
    int cl = i >> 6, rl = i & 63;
    dst[(size_t)(c0 + cl)*R + r0 + rl] = f2b(tile[rl*65 + cl]);
  }
}

// ============ k_misc: conv1 [0,2P) + featpool + weight transforms ============
// conv1 computes its B-panel inline from w_c1 (50KB, L1-hot): k'=ic*64+ky*8+kx maps a fragment to
// 7 contiguous floats (kx=j); ic=kst>>1, ky=(kst*4+lhi)&7, bf[7]=0 pad. No w1tp pass.
__global__ __launch_bounds__(256) void k_misc(
    const float* __restrict__ feat, const int* __restrict__ pidx, const int* __restrict__ im_idx,
    const float* __restrict__ w_c1, const float* __restrict__ w_c2, const float* __restrict__ w_u,
    const float* __restrict__ w_vr, const float* __restrict__ w_m1,
    const float* __restrict__ w_subj, const float* __restrict__ w_obj,
    const float* __restrict__ masks, const float* __restrict__ b1,
    float* __restrict__ stats1, u16* __restrict__ spool,
    u16* __restrict__ w2f, u16* __restrict__ wuT,
    u16* __restrict__ wvrT, u16* __restrict__ wm1T, u16* __restrict__ wsoT,
    u16* __restrict__ pfbf, int P){
  __shared__ u32 smem32[8192];             // conv1: lds32[1400] + s1n 25KB | transpose: 16.6KB
  int bid = blockIdx.x, t = threadIdx.x;
  int c1n = 2*P;                           // conv1 block count (10000)
  if (bid < c1n){
    // ---------------- conv1 v2 (7x7 s2 p3, 2->128), weights inline from w_c1 ----------------
    u32* lds32 = smem32;                   // in_bf [2][34][40] u16 (1360 u32 + 40 slack)
    u16* s1n = (u16*)&smem32[1408];        // [64 oc][196 pix], post-relu PRE-BN
    int p = bid >> 1, z = bid & 1;
    int lane = t & 63, w = t >> 6;
    int l15 = lane & 15, lhi = lane >> 4;
    int ocl = w*16 + l15;
    int oc  = z*64 + ocl;
    s8v Bf[4];
    #pragma unroll
    for (int kst = 0; kst < 4; ++kst){
      int ic = kst >> 1;
      int ky = (kst*4 + lhi) & 7;
      s8v bf = {};
      if (ky < 7){
        const float* wsrc = w_c1 + oc*98 + ic*49 + ky*7;
        #pragma unroll
        for (int j = 0; j < 7; ++j) bf[j] = (short)f2b(wsrc[j]);
      }
      Bf[kst] = bf;
    }
    for (int i = t; i < 1400; i += 256) lds32[i] = 0;
    __syncthreads();
    u16* in_bf = (u16*)lds32;
    for (int e = t; e < 1458; e += 256){
      int c = e >= 729; int r = e - c*729;
      int rr = r/27, cc = r - rr*27;
      in_bf[c*1360 + (rr + 3)*40 + cc + 3] = f2b(masks[(size_t)p*1458 + e]);
    }
    int rb[13];
    #pragma unroll
    for (int mt = 0; mt < 13; ++mt){
      int pix = mt*16 + l15;
      int oy = pix/14, ox = pix - oy*14;
      rb[mt] = oy*40 + ox;
    }
    __syncthreads();
    f4v acc[13] = {};
    #pragma unroll
    for (int kst = 0; kst < 4; ++kst){
      int kk = kst*32 + lhi*8;
      int kbase = (kk >> 6)*680 + ((kk >> 3) & 7)*20;
      #pragma unroll
      for (int mt = 0; mt < 13; ++mt){
        int a = kbase + rb[mt];
        union { u32 u[4]; s8v v; } cv;
        cv.u[0] = lds32[a];   cv.u[1] = lds32[a+1];
        cv.u[2] = lds32[a+2]; cv.u[3] = lds32[a+3];
        acc[mt] = mfma16(cv.v, Bf[kst], acc[mt]);
      }
    }
    float bias = b1[oc];
    float ss = 0.f, qq = 0.f;
    #pragma unroll
    for (int mt = 0; mt < 13; ++mt)
      #pragma unroll
      for (int v = 0; v < 4; ++v){
        int pix = mt*16 + lhi*4 + v;
        if (pix < 196){
          float r = fmaxf(acc[mt][v] + bias, 0.f);
          ss += r; qq += r*r;
          s1n[ocl*196 + pix] = f2b(r);
        }
      }
    ss += __shfl_xor(ss, 16); ss += __shfl_xor(ss, 32);
    qq += __shfl_xor(qq, 16); qq += __shfl_xor(qq, 32);
    if (lane < 16){
      atomicAdd(&stats1[z*64 + w*16 + lane], ss);
      atomicAdd(&stats1[128 + z*64 + w*16 + lane], qq);
    }
    __syncthreads();
    {  // maxpool 3x3 s2 p1, u16-bit-compare (relu => monotone), u32-pair reads
      int ocp = t & 63, pg = t >> 6;
      const u32* row32 = (const u32*)s1n;
      for (int pp = pg; pp < 49; pp += 4){
        int poy = pp/7, pox = pp - poy*7;
        u32 m = 0;
        #pragma unroll
        for (int dy = 0; dy < 3; ++dy){
          int iy = poy*2 - 1 + dy;
          if (iy < 0 || iy > 13) continue;
          int widx = ocp*98 + iy*7 + pox;
          u32 wB = row32[widx];
          u32 c1 = wB & 0xffffu, c2 = wB >> 16;
          m = c1 > m ? c1 : m;
          m = c2 > m ? c2 : m;
          if (pox > 0){
            u32 c0 = row32[widx - 1] >> 16;
            m = c0 > m ? c0 : m;
          }
        }
        spool[((size_t)p*49 + pp)*128 + z*64 + ocp] = (u16)m;
      }
    }
  } else if (bid < c1n + 200){
    int i = bid - c1n; int s = i/100, b = i - s*100;
    int s0, s1; segrange(im_idx, P, b, s0, s1);
    float inv = 1.f / fmaxf((float)(s1 - s0), 1.f);
    f4v a0 = {}, a1 = {};
    for (int p = s0; p < s1; ++p){
      int row = pidx[p*2 + s];
      const f4v* src = (const f4v*)(feat + (size_t)row*2048);
      a0 += src[t]; a1 += src[t+256];
    }
    u16* dst = pfbf + (size_t)(s*100 + b)*2048;
    #pragma unroll
    for (int j = 0; j < 4; ++j){
      dst[4*t + j]        = f2b(a0[j]*inv);
      dst[1024 + 4*t + j] = f2b(a1[j]*inv);
    }
  } else if (bid < c1n + 1352){
    int i = (bid - (c1n + 200))*256 + t;   // fragment-packed conv2 weights
    int frag = i >> 9, r = i & 511;
    int lane = r >> 3, j = r & 7;
    int kst = frag & 3, og = (frag >> 2) & 15, tap = frag >> 6;
    int oc = og*16 + (lane & 15);
    int k  = kst*32 + (lane >> 4)*8 + j;
    w2f[i] = f2b(w_c2[((size_t)(oc*128 + k))*9 + tap]);
  } else if (bid < c1n + 2376){
    int i = (bid - (c1n + 1352))*256 + t;
    wuT[i] = f2b(w_u[i]);
  } else if (bid < c1n + 3944){
    int idx = bid - (c1n + 2376);          // 196*8
    transpose_body(w_vr, wvrT, 12544, 512, idx >> 3, idx & 7, t, (float*)smem32);
  } else if (bid < c1n + 4712){
    int idx = bid - (c1n + 3944);          // 24*32
    transpose_body(w_m1, wm1T, 1536, 2048, idx >> 5, idx & 31, t, (float*)smem32);
  } else {
    int idx = bid - (c1n + 4712);          // 2 * 32*8
    int sel = idx >> 8; idx &= 255;
    transpose_body(sel ? w_obj : w_subj, wsoT + (size_t)sel*512*2048,
                   2048, 512, idx >> 3, idx & 7, t, (float*)smem32);
  }
}

// ============ k_c2up: conv2 v8 UNION upool — R15-measured geometry (q=5, 4:9 interleave) ============
__global__ __launch_bounds__(256) void k_c2up(
    const u16* __restrict__ spool, const u16* __restrict__ w2f, const float* __restrict__ b2,
    const float* __restrict__ g1, const float* __restrict__ be1,
    const float* __restrict__ stats1, const int* __restrict__ im_idx,
    float* __restrict__ segr, float* __restrict__ stats2, int P, float invN1,
    const float* __restrict__ uf, u16* __restrict__ muT){
  __shared__ u16 raw[2*82*128 + 512];      // conv2: inT dbuf + sc1/sh1 | upool: 3136 f32
  int bid = blockIdx.x, t = threadIdx.x;
  int g = bid/9, r9 = bid - g*9;

  if (r9 < 4){
    // ---------- upool: u = g*4 + r9; block (b, icb) pools 64 channels ----------
    float* smem = (float*)raw;
    int u = g*4 + r9;
    int b = u >> 4, icb = u & 15;
    int s0, s1; segrange(im_idx, P, b, s0, s1);
    float inv = 1.f / fmaxf((float)(s1 - s0), 1.f);
    f4v a0 = {}, a1 = {}, a2 = {}, a3 = {};
    int p = s0;
    for (; p + 1 < s1; p += 2){
      const f4v* x = (const f4v*)(uf + (size_t)p*50176 + icb*3136);
      const f4v* y = (const f4v*)(uf + (size_t)(p+1)*50176 + icb*3136);
      a0 += x[t] + y[t]; a1 += x[t+256] + y[t+256]; a2 += x[t+512] + y[t+512];
      if (t < 16) a3 += x[t+768] + y[t+768];
    }
    if (p < s1){
      const f4v* x = (const f4v*)(uf + (size_t)p*50176 + icb*3136);
      a0 += x[t]; a1 += x[t+256]; a2 += x[t+512];
      if (t < 16) a3 += x[t+768];
    }
    *(f4v*)&smem[4*t] = a0;
    *(f4v*)&smem[4*(t+256)] = a1;
    *(f4v*)&smem[4*(t+512)] = a2;
    if (t < 16) *(f4v*)&smem[4*(t+768)] = a3;
    __syncthreads();
    for (int o = t; o < 3136; o += 256){
      int pix = o >> 6, ics = o & 63;
      muT[(size_t)(b*49 + pix)*1024 + (icb<<6) + ics] = f2b(smem[ics*49 + pix]*inv);
    }
    return;
  }

  // ---------- conv2: idx = g*5 + (r9-4); b = idx/20, q = (idx%20)>>2 (0..4), z = idx&3 ----------
  int idx = g*5 + (r9 - 4);
  int b = idx/20, rem = idx - b*20;
  int q = rem >> 2, z = rem & 3;
  float* sc1 = (float*)&raw[2*82*128];
  float* sh1 = sc1 + 128;
  int lane = t & 63, w = t >> 6;
  int l15 = lane & 15, lhi = lane >> 4;
  int og = z*4 + w;                        // this wave's 16-oc group
  int oc = og*16 + l15;
  s8v Bf[9][4];                            // whole B panel for this wave: 144 VGPR, loaded once
  #pragma unroll
  for (int tap = 0; tap < 9; ++tap)
    #pragma unroll
    for (int kst = 0; kst < 4; ++kst)
      Bf[tap][kst] = *(const s8v*)&w2f[((((size_t)tap*16 + og)*4 + kst) << 9) + lane*8];
  {
    f4v zv = {}; f4v* a4 = (f4v*)raw;
    for (int i = t; i < 2624; i += 256) a4[i] = zv;
  }
  if (t < 128){                            // folded bnfin1
    float mean = stats1[t]*invN1;
    float var  = stats1[128 + t]*invN1 - mean*mean;
    float sc = g1[t]*rsqrtf(var + 1e-5f);
    sc1[t] = sc; sh1[t] = be1[t] - mean*sc;
  }
  int s0, s1; segrange(im_idx, P, b, s0, s1);
  int cnt = s1 - s0, chunk = (cnt + 4)/5;
  int p0 = s0 + q*chunk, p1 = min(p0 + chunk, s1);
  if (p0 >= p1) return;
  int rowm[4]; bool okm[4];
  #pragma unroll
  for (int mt = 0; mt < 4; ++mt){
    int pix = mt*16 + l15;
    okm[mt] = pix < 49;
    int py = pix/7, px = pix - py*7;
    rowm[mt] = okm[mt] ? (py + 1)*9 + px + 1 : 81;
  }
  float bias = b2[oc];
  f4v segacc[4] = {};
  float ssum = 0.f, ssq = 0.f;
  u32 r13[13];
  const u32* sp32 = (const u32*)spool;
  auto LOADR = [&](int p){
    #pragma unroll
    for (int j = 0; j < 13; ++j){
      int i = j*256 + t;
      r13[j] = (i < 3136) ? sp32[(size_t)p*3136 + i] : 0u;
    }
  };
  auto WRITE = [&](int bb){
    u32* d = (u32*)&raw[bb*82*128];
    #pragma unroll
    for (int j = 0; j < 13; ++j){
      int i = j*256 + t;
      if (i < 3136){
        int pix = i >> 6, icp = i & 63;
        u32 v = r13[j];
        float lo = b2f((u16)v)*sc1[icp*2]          + sh1[icp*2];
        float hi = b2f((u16)(v >> 16))*sc1[icp*2+1] + sh1[icp*2+1];
        int py = pix/7;
        int row = (py + 1)*9 + (pix - py*7) + 1;
        d[(row*64 + icp) ^ ((row & 7) << 2)] = (u32)f2b(lo) | ((u32)f2b(hi) << 16);
      }
    }
  };
  LOADR(p0);
  __syncthreads();                         // zero-init + sc1 visible before first WRITE
  WRITE(0);
  int cur = 0;
  for (int p = p0; p < p1; ++p){
    __syncthreads();                       // buf[cur] writes visible to all
    if (p + 1 < p1) LOADR(p + 1);          // issue global prefetch: hides under MFMA
    f4v pacc[4] = {};
    const u16* buf = &raw[cur*82*128];
    #pragma unroll
    for (int tap = 0; tap < 9; ++tap){
      int doff = (tap/3 - 1)*9 + (tap%3 - 1);
      int rr[4];
      #pragma unroll
      for (int mt = 0; mt < 4; ++mt)
        rr[mt] = okm[mt] ? rowm[mt] + doff : 81;
      #pragma unroll
      for (int kst = 0; kst < 4; ++kst){
        int koff = kst*32 + lhi*8;
        #pragma unroll
        for (int mt = 0; mt < 4; ++mt){
          s8v A = *(const s8v*)&buf[(rr[mt]*128 + koff) ^ ((rr[mt] & 7) << 3)];
          pacc[mt] = mfma16(A, Bf[tap][kst], pacc[mt]);
        }
      }
    }
    #pragma unroll
    for (int mt = 0; mt < 4; ++mt)
      #pragma unroll
      for (int v = 0; v < 4; ++v){
        int pix = mt*16 + lhi*4 + v;
        float r = fmaxf(pacc[mt][v] + bias, 0.f);
        r = (pix < 49) ? r : 0.f;
        segacc[mt][v] += r;
        ssum += r; ssq += r*r;
      }
    if (p + 1 < p1) WRITE(cur ^ 1);        // other buffer: safe, readers passed barrier
    cur ^= 1;
  }
  #pragma unroll
  for (int mt = 0; mt < 4; ++mt)
    #pragma unroll
    for (int v = 0; v < 4; ++v){
      int pix = mt*16 + lhi*4 + v;
      if (pix < 49)
        atomicAdd(&segr[(size_t)(b*256 + oc)*49 + pix], segacc[mt][v]);
    }
  float s = ssum, qd = ssq;
  s  += __shfl_xor(s, 16);  s  += __shfl_xor(s, 32);
  qd += __shfl_xor(qd, 16); qd += __shfl_xor(qd, 32);
  if (lane < 16){
    atomicAdd(&stats2[og*16 + lane], s);
    atomicAdd(&stats2[256 + og*16 + lane], qd);
  }
}

// ============ combine: union 1x1 conv + bn2(seg-mean relu2) -> tbf ============
__global__ __launch_bounds__(256) void k_combine(const u16* __restrict__ muT, const u16* __restrict__ wuT,
                                                 const float* __restrict__ b_u, const float* __restrict__ segr,
                                                 const float* __restrict__ stats2,
                                                 const float* __restrict__ g2, const float* __restrict__ be2,
                                                 const int* __restrict__ im_idx, u16* __restrict__ tbf,
                                                 int P, float invN2){
  __shared__ float sc2[256], sh2[256];
  int b = blockIdx.x, t = threadIdx.x;
  int lane = t & 63, w = t >> 6;
  int l15 = lane & 15, lhi = lane >> 4;
  {
    float mean = stats2[t]*invN2;
    float var  = stats2[256 + t]*invN2 - mean*mean;
    float sc = g2[t]*rsqrtf(var + 1e-5f);
    sc2[t] = sc; sh2[t] = be2[t] - mean*sc;
  }
  __syncthreads();
  int s0, s1; segrange(im_idx, P, b, s0, s1);
  float inv = 1.f / fmaxf((float)(s1 - s0), 1.f);
  int ocb = w*64;
  const u16* arow[4];
  #pragma unroll
  for (int mt = 0; mt < 4; ++mt){
    int pix = mt*16 + l15;
    arow[mt] = muT + (size_t)(b*49 + (pix < 49 ? pix : 0))*1024;
  }
  f4v acc[4][4] = {};
  for (int kst = 0; kst < 32; ++kst){
    int koff = kst*32 + lhi*8;
    s8v Bf[4];
    #pragma unroll
    for (int nt = 0; nt < 4; ++nt)
      Bf[nt] = *(const s8v*)&wuT[(ocb + nt*16 + l15)*1024 + koff];
    #pragma unroll
    for (int mt = 0; mt < 4; ++mt){
      s8v A = *(const s8v*)&arow[mt][koff];
      #pragma unroll
      for (int nt = 0; nt < 4; ++nt)
        acc[mt][nt] = mfma16(A, Bf[nt], acc[mt][nt]);
    }
  }
  #pragma unroll
  for (int nt = 0; nt < 4; ++nt){
    int oc = ocb + nt*16 + l15;
    float bu = b_u[oc], sc = sc2[oc], sh = sh2[oc];
    #pragma unroll
    for (int mt = 0; mt < 4; ++mt)
      #pragma unroll
      for (int v = 0; v < 4; ++v){
        int pix = mt*16 + lhi*4 + v;
        if (pix < 49){
          float val = acc[mt][nt][v] + bu + sc*segr[(size_t)(b*256 + oc)*49 + pix]*inv + sh;
          tbf[(size_t)b*12544 + oc*49 + pix] = f2b(val);
        }
      }
  }
}

// ============ mega3: vr GEMM (56 blocks) UNION subj/obj GEMM (16 blocks) ============
__global__ __launch_bounds__(256) void k_mega3(const u16* __restrict__ tbf, const u16* __restrict__ wvrT,
                                               const float* __restrict__ b_vr,
                                               const u16* __restrict__ pfbf, const u16* __restrict__ wsoT,
                                               const float* __restrict__ b_subj, const float* __restrict__ b_obj,
                                               float* __restrict__ px, int B){
  int bid = blockIdx.x, t = threadIdx.x;
  int lane = t & 63, w = t >> 6;
  int l15 = lane & 15, lhi = lane >> 4;
  if (bid < 56){
    int nb = bid & 1, kc = bid >> 1;
    int colb = nb*256 + w*64;
    int k0 = kc*448;
    f4v acc[7][4] = {};
    for (int kst = 0; kst < 14; ++kst){
      int koff = k0 + kst*32 + lhi*8;
      s8v Bf[4];
      #pragma unroll
      for (int nt = 0; nt < 4; ++nt)
        Bf[nt] = *(const s8v*)&wvrT[(size_t)(colb + nt*16 + l15)*12544 + koff];
      #pragma unroll
      for (int mt = 0; mt < 7; ++mt){
        s8v A = *(const s8v*)&tbf[(size_t)(mt*16 + l15)*12544 + koff];
        #pragma unroll
        for (int nt = 0; nt < 4; ++nt)
          acc[mt][nt] = mfma16(A, Bf[nt], acc[mt][nt]);
      }
    }
    #pragma unroll
    for (int nt = 0; nt < 4; ++nt){
      int col = colb + nt*16 + l15;
      float bias = (kc == 0) ? b_vr[col] : 0.f;
      #pragma unroll
      for (int mt = 0; mt < 7; ++mt)
        #pragma unroll
        for (int v = 0; v < 4; ++v){
          int row = mt*16 + lhi*4 + v;
          if (row < B) atomicAdd(&px[row*1536 + 1024 + col], acc[mt][nt][v] + bias);
        }
    }
  } else {
    int r = bid - 56;
    int nb = r & 1, s = (r >> 1) & 1, kc = r >> 2;
    int colb = nb*256 + w*64;
    int k0 = kc*512;
    const float* bi = s ? b_obj : b_subj;
    f4v acc[7][4] = {};
    for (int kst = 0; kst < 16; ++kst){
      int koff = k0 + kst*32 + lhi*8;
      s8v Bf[4];
      #pragma unroll
      for (int nt = 0; nt < 4; ++nt)
        Bf[nt] = *(const s8v*)&wsoT[(size_t)(s*512 + colb + nt*16 + l15)*2048 + koff];
      #pragma unroll
      for (int mt = 0; mt < 7; ++mt){
        int row = mt*16 + l15; row = row < B ? row : 0;
        s8v A = *(const s8v*)&pfbf[(size_t)(s*100 + row)*2048 + koff];
        #pragma unroll
        for (int nt = 0; nt < 4; ++nt)
          acc[mt][nt] = mfma16(A, Bf[nt], acc[mt][nt]);
      }
    }
    #pragma unroll
    for (int nt = 0; nt < 4; ++nt){
      int col = colb + nt*16 + l15;
      float bias = (kc == 0) ? bi[col] : 0.f;
      #pragma unroll
      for (int mt = 0; mt < 7; ++mt)
        #pragma unroll
        for (int v = 0; v < 4; ++v){
          int row = mt*16 + lhi*4 + v;
          if (row < B) atomicAdd(&px[row*1536 + s*512 + col], acc[mt][nt][v] + bias);
        }
    }
  }
}

// ============ MLP m1: [112,1536]@[1536,2048], k-split atomics, f32 A inline-cast ============
__global__ __launch_bounds__(256) void k_m1(const float* __restrict__ px, const u16* __restrict__ wm1T,
                                            float* __restrict__ h, int B){
  int nb = blockIdx.x, kc = blockIdx.y, t = threadIdx.x;
  int lane = t & 63, w = t >> 6;
  int l15 = lane & 15, lhi = lane >> 4;
  int colb = nb*256 + w*64;
  int k0 = kc*384;
  f4v acc[7][4] = {};
  for (int kst = 0; kst < 12; ++kst){
    int koff = k0 + kst*32 + lhi*8;
    s8v Bf[4];
    #pragma unroll
    for (int nt = 0; nt < 4; ++nt)
      Bf[nt] = *(const s8v*)&wm1T[(size_t)(colb + nt*16 + l15)*1536 + koff];
    #pragma unroll
    for (int mt = 0; mt < 7; ++mt){
      const float* ap = px + (size_t)(mt*16 + l15)*1536 + koff;
      f4v lo = *(const f4v*)ap;
      f4v hi = *(const f4v*)(ap + 4);
      s8v A;
      A[0] = (short)f2b(lo[0]); A[1] = (short)f2b(lo[1]);
      A[2] = (short)f2b(lo[2]); A[3] = (short)f2b(lo[3]);
      A[4] = (short)f2b(hi[0]); A[5] = (short)f2b(hi[1]);
      A[6] = (short)f2b(hi[2]); A[7] = (short)f2b(hi[3]);
      #pragma unroll
      for (int nt = 0; nt < 4; ++nt)
        acc[mt][nt] = mfma16(A, Bf[nt], acc[mt][nt]);
    }
  }
  #pragma unroll
  for (int nt = 0; nt < 4; ++nt){
    int col = colb + nt*16 + l15;
    #pragma unroll
    for (int mt = 0; mt < 7; ++mt)
      #pragma unroll
      for (int v = 0; v < 4; ++v){
        int row = mt*16 + lhi*4 + v;
        if (row < B) atomicAdd(&h[row*2048 + col], acc[mt][nt][v]);
      }
  }
}

// ============ m2 + bias1/relu + sigmoid, in-block k-split x2 ============
__global__ __launch_bounds__(512) void k_m2(const float* __restrict__ h, const float* __restrict__ bm1,
                                            const float* __restrict__ w_m2, const float* __restrict__ b_m2,
                                            float* __restrict__ out){
  __shared__ float part[160];
  int b = blockIdx.x, t = threadIdx.x;
  int col = t & 255, kg = t >> 8;
  float acc = 0.f;
  if (col < 157){
    const float* hb = h + (size_t)b*2048;
    int k0 = kg*1024;
    for (int k = k0; k < k0 + 1024; ++k)
      acc += fmaxf(hb[k] + bm1[k], 0.f) * w_m2[(size_t)k*157 + col];
  }
  if (kg == 1 && col < 157) part[col] = acc;
  __syncthreads();
  if (kg == 0 && col < 157){
    float s = acc + part[col] + b_m2[col];
    out[b*157 + col] = 1.f/(1.f + expf(-s));
  }
}

extern "C" void kernel_launch(void* const* d_in, const int* in_sizes, int n_in,
                              void* d_out, int out_size, void* d_ws, size_t ws_size,
                              hipStream_t stream){
  const float* features   = (const float*)d_in[0];
  const float* union_feat = (const float*)d_in[1];
  const float* masks      = (const float*)d_in[2];
  const float* w_union    = (const float*)d_in[3];
  const float* b_union    = (const float*)d_in[4];
  const float* w_c1       = (const float*)d_in[5];
  const float* b_c1       = (const float*)d_in[6];
  const float* g_bn1      = (const float*)d_in[7];
  const float* be_bn1     = (const float*)d_in[8];
  const float* w_c2       = (const float*)d_in[9];
  const float* b_c2       = (const float*)d_in[10];
  const float* g_bn2      = (const float*)d_in[11];
  const float* be_bn2     = (const float*)d_in[12];
  const float* w_subj     = (const float*)d_in[13];
  const float* b_subj     = (const float*)d_in[14];
  const float* w_obj      = (const float*)d_in[15];
  const float* b_obj      = (const float*)d_in[16];
  const float* w_vr       = (const float*)d_in[17];
  const float* b_vr       = (const float*)d_in[18];
  const float* w_m1       = (const float*)d_in[19];
  const float* b_m1       = (const float*)d_in[20];
  const float* w_m2       = (const float*)d_in[21];
  const float* b_m2       = (const float*)d_in[22];
  const int* pair_idx     = (const int*)d_in[23];
  const int* im_idx       = (const int*)d_in[24];
  float* out = (float*)d_out;
  const int P = in_sizes[24];
  const int B = out_size/157;

  char* ws = (char*)d_ws;
  size_t off = 0;
  auto alloc = [&](size_t bytes)->size_t{ size_t o = off; off += (bytes + 255) & ~(size_t)255; return o; };
  // zero-region (one memset): stats | segr | px | h
  size_t o_stats= alloc(3072);
  size_t o_segr = alloc((size_t)B*256*49*4);
  size_t o_px   = alloc((size_t)112*1536*4);
  size_t o_h    = alloc((size_t)B*2048*4);
  size_t zero_end = off;
  size_t o_muT  = alloc((size_t)B*49*1024*2);
  size_t o_spool= alloc((size_t)P*49*128*2);
  size_t o_w2f  = alloc(9*256*128*2);
  size_t o_wuT  = alloc(256*1024*2);
  size_t o_wvrT = alloc((size_t)512*12544*2);
  size_t o_wm1T = alloc((size_t)2048*1536*2);
  size_t o_wsoT = alloc((size_t)1024*2048*2);
  size_t o_pfbf = alloc((size_t)200*2048*2);
  size_t o_tbf  = alloc((size_t)112*12544*2);
  (void)ws_size; (void)n_in;

  float* stats1 = (float*)(ws + o_stats);
  float* stats2 = stats1 + 256;
  u16*   muT    = (u16*)(ws + o_muT);
  u16*   spool  = (u16*)(ws + o_spool);
  u16*   w2f    = (u16*)(ws + o_w2f);
  u16*   wuT    = (u16*)(ws + o_wuT);
  u16*   wvrT   = (u16*)(ws + o_wvrT);
  u16*   wm1T   = (u16*)(ws + o_wm1T);
  u16*   wsoT   = (u16*)(ws + o_wsoT);
  u16*   pfbf   = (u16*)(ws + o_pfbf);
  float* segr   = (float*)(ws + o_segr);
  u16*   tbf    = (u16*)(ws + o_tbf);
  float* px     = (float*)(ws + o_px);
  float* h      = (float*)(ws + o_h);

  hipMemsetAsync(ws, 0, zero_end, stream);

  k_misc<<<2*P + 5224, dim3(256), 0, stream>>>(features, pair_idx, im_idx, w_c1, w_c2, w_union,
                                               w_vr, w_m1, w_subj, w_obj,
                                               masks, b_c1, stats1, spool,
                                               w2f, wuT, wvrT, wm1T, wsoT, pfbf, P);
  k_c2up<<<3600, dim3(256), 0, stream>>>(spool, w2f, b_c2, g_bn1, be_bn1, stats1, im_idx,
                                         segr, stats2, P, 1.f/((float)P*196.f),
                                         union_feat, muT);
  k_combine<<<B, dim3(256), 0, stream>>>(muT, wuT, b_union, segr, stats2, g_bn2, be_bn2, im_idx,
                                         tbf, P, 1.f/((float)P*49.f));
  k_mega3<<<72, dim3(256), 0, stream>>>(tbf, wvrT, b_vr, pfbf, wsoT, b_subj, b_obj, px, B);
  k_m1<<<dim3(8, 4), dim3(256), 0, stream>>>(px, wm1T, h, B);
  k_m2<<<B, dim3(512), 0, stream>>>(h, b_m1, w_m2, b_m2, out);
}

// Round 19
// 919.195 us; speedup vs baseline: 1.5809x; 1.2056x over previous
//
#include <hip/hip_runtime.h>

typedef unsigned short u16;
typedef unsigned int   u32;
typedef short s8v __attribute__((ext_vector_type(8)));   // 8 x bf16 MFMA operand
typedef float f4v __attribute__((ext_vector_type(4)));   // MFMA accumulator

#define DEV __device__ __forceinline__

DEV u16 f2b(float f){
  u32 x = __builtin_bit_cast(u32, f);
  u32 r = x + 0x7fffu + ((x >> 16) & 1u);
  return (u16)(r >> 16);
}
DEV float b2f(u16 u){ u32 x = ((u32)u) << 16; return __builtin_bit_cast(float, x); }
DEV f4v mfma16(s8v a, s8v b, f4v c){ return __builtin_amdgcn_mfma_f32_16x16x32_bf16(a, b, c, 0, 0, 0); }

DEV void segrange(const int* __restrict__ im, int P, int b, int& s0, int& s1){
  int lo = 0, hi = P;
  while (lo < hi){ int m = (lo + hi) >> 1; if (im[m] < b) lo = m + 1; else hi = m; }
  s0 = lo;
  int lo2 = lo; hi = P;
  while (lo2 < hi){ int m = (lo2 + hi) >> 1; if (im[m] < b + 1) lo2 = m + 1; else hi = m; }
  s1 = lo2;
}

DEV void transpose_body(const float* __restrict__ src, u16* __restrict__ dst,
                        int R, int C, int rb, int cb, int t, float* tile){
  int r0 = rb << 6, c0 = cb << 6;
  for (int i = t; i < 4096; i += 256){
    int rl = i >> 6, cl = i & 63;
    tile[rl*65 + cl] = src[(size_t)(r0 + rl)*C + c0 + cl];
  }
  __syncthreads();
  for (int i = t; i < 4096; i += 256){
    int cl = i >> 6, rl = i & 63;
    dst[(size_t)(c0 + cl)*R + r0 + rl] = f2b(tile[rl*65 + cl]);
  }
}

// ============ k_misc: conv1 [0,2P) + featpool + weight transforms ============
__global__ __launch_bounds__(256) void k_misc(
    const float* __restrict__ feat, const int* __restrict__ pidx, const int* __restrict__ im_idx,
    const float* __restrict__ w_c1, const float* __restrict__ w_c2, const float* __restrict__ w_u,
    const float* __restrict__ w_vr, const float* __restrict__ w_m1,
    const float* __restrict__ w_subj, const float* __restrict__ w_obj,
    const float* __restrict__ masks, const float* __restrict__ b1,
    float* __restrict__ stats1, u16* __restrict__ spool,
    u16* __restrict__ w2f, u16* __restrict__ wuT,
    u16* __restrict__ wvrT, u16* __restrict__ wm1T, u16* __restrict__ wsoT,
    u16* __restrict__ pfbf, int P){
  __shared__ u32 smem32[8192];             // conv1: lds32[1400] + s1n 25KB | transpose: 16.6KB
  int bid = blockIdx.x, t = threadIdx.x;
  int c1n = 2*P;                           // conv1 block count (10000)
  if (bid < c1n){
    // ---------------- conv1 v2 (7x7 s2 p3, 2->128), weights inline from w_c1 ----------------
    u32* lds32 = smem32;                   // in_bf [2][34][40] u16 (1360 u32 + 40 slack)
    u16* s1n = (u16*)&smem32[1408];        // [64 oc][196 pix], post-relu PRE-BN
    int p = bid >> 1, z = bid & 1;
    int lane = t & 63, w = t >> 6;
    int l15 = lane & 15, lhi = lane >> 4;
    int ocl = w*16 + l15;
    int oc  = z*64 + ocl;
    s8v Bf[4];
    #pragma unroll
    for (int kst = 0; kst < 4; ++kst){
      int ic = kst >> 1;
      int ky = (kst*4 + lhi) & 7;
      s8v bf = {};
      if (ky < 7){
        const float* wsrc = w_c1 + oc*98 + ic*49 + ky*7;
        #pragma unroll
        for (int j = 0; j < 7; ++j) bf[j] = (short)f2b(wsrc[j]);
      }
      Bf[kst] = bf;
    }
    for (int i = t; i < 1400; i += 256) lds32[i] = 0;
    __syncthreads();
    u16* in_bf = (u16*)lds32;
    for (int e = t; e < 1458; e += 256){
      int c = e >= 729; int r = e - c*729;
      int rr = r/27, cc = r - rr*27;
      in_bf[c*1360 + (rr + 3)*40 + cc + 3] = f2b(masks[(size_t)p*1458 + e]);
    }
    int rb[13];
    #pragma unroll
    for (int mt = 0; mt < 13; ++mt){
      int pix = mt*16 + l15;
      int oy = pix/14, ox = pix - oy*14;
      rb[mt] = oy*40 + ox;
    }
    __syncthreads();
    f4v acc[13] = {};
    #pragma unroll
    for (int kst = 0; kst < 4; ++kst){
      int kk = kst*32 + lhi*8;
      int kbase = (kk >> 6)*680 + ((kk >> 3) & 7)*20;
      #pragma unroll
      for (int mt = 0; mt < 13; ++mt){
        int a = kbase + rb[mt];
        union { u32 u[4]; s8v v; } cv;
        cv.u[0] = lds32[a];   cv.u[1] = lds32[a+1];
        cv.u[2] = lds32[a+2]; cv.u[3] = lds32[a+3];
        acc[mt] = mfma16(cv.v, Bf[kst], acc[mt]);
      }
    }
    float bias = b1[oc];
    float ss = 0.f, qq = 0.f;
    #pragma unroll
    for (int mt = 0; mt < 13; ++mt)
      #pragma unroll
      for (int v = 0; v < 4; ++v){
        int pix = mt*16 + lhi*4 + v;
        if (pix < 196){
          float r = fmaxf(acc[mt][v] + bias, 0.f);
          ss += r; qq += r*r;
          s1n[ocl*196 + pix] = f2b(r);
        }
      }
    ss += __shfl_xor(ss, 16); ss += __shfl_xor(ss, 32);
    qq += __shfl_xor(qq, 16); qq += __shfl_xor(qq, 32);
    if (lane < 16){
      atomicAdd(&stats1[z*64 + w*16 + lane], ss);
      atomicAdd(&stats1[128 + z*64 + w*16 + lane], qq);
    }
    __syncthreads();
    {  // maxpool 3x3 s2 p1, u16-bit-compare (relu => monotone), u32-pair reads
      int ocp = t & 63, pg = t >> 6;
      const u32* row32 = (const u32*)s1n;
      for (int pp = pg; pp < 49; pp += 4){
        int poy = pp/7, pox = pp - poy*7;
        u32 m = 0;
        #pragma unroll
        for (int dy = 0; dy < 3; ++dy){
          int iy = poy*2 - 1 + dy;
          if (iy < 0 || iy > 13) continue;
          int widx = ocp*98 + iy*7 + pox;
          u32 wB = row32[widx];
          u32 c1 = wB & 0xffffu, c2 = wB >> 16;
          m = c1 > m ? c1 : m;
          m = c2 > m ? c2 : m;
          if (pox > 0){
            u32 c0 = row32[widx - 1] >> 16;
            m = c0 > m ? c0 : m;
          }
        }
        spool[((size_t)p*49 + pp)*128 + z*64 + ocp] = (u16)m;
      }
    }
  } else if (bid < c1n + 200){
    int i = bid - c1n; int s = i/100, b = i - s*100;
    int s0, s1; segrange(im_idx, P, b, s0, s1);
    float inv = 1.f / fmaxf((float)(s1 - s0), 1.f);
    f4v a0 = {}, a1 = {};
    for (int p = s0; p < s1; ++p){
      int row = pidx[p*2 + s];
      const f4v* src = (const f4v*)(feat + (size_t)row*2048);
      a0 += src[t]; a1 += src[t+256];
    }
    u16* dst = pfbf + (size_t)(s*100 + b)*2048;
    #pragma unroll
    for (int j = 0; j < 4; ++j){
      dst[4*t + j]        = f2b(a0[j]*inv);
      dst[1024 + 4*t + j] = f2b(a1[j]*inv);
    }
  } else if (bid < c1n + 1352){
    int i = (bid - (c1n + 200))*256 + t;   // fragment-packed conv2 weights
    int frag = i >> 9, r = i & 511;
    int lane = r >> 3, j = r & 7;
    int kst = frag & 3, og = (frag >> 2) & 15, tap = frag >> 6;
    int oc = og*16 + (lane & 15);
    int k  = kst*32 + (lane >> 4)*8 + j;
    w2f[i] = f2b(w_c2[((size_t)(oc*128 + k))*9 + tap]);
  } else if (bid < c1n + 2376){
    int i = (bid - (c1n + 1352))*256 + t;
    wuT[i] = f2b(w_u[i]);
  } else if (bid < c1n + 3944){
    int idx = bid - (c1n + 2376);          // 196*8
    transpose_body(w_vr, wvrT, 12544, 512, idx >> 3, idx & 7, t, (float*)smem32);
  } else if (bid < c1n + 4712){
    int idx = bid - (c1n + 3944);          // 24*32
    transpose_body(w_m1, wm1T, 1536, 2048, idx >> 5, idx & 31, t, (float*)smem32);
  } else {
    int idx = bid - (c1n + 4712);          // 2 * 32*8
    int sel = idx >> 8; idx &= 255;
    transpose_body(sel ? w_obj : w_subj, wsoT + (size_t)sel*512*2048,
                   2048, 512, idx >> 3, idx & 7, t, (float*)smem32);
  }
}

// ============ k_c2up: conv2 v9 (tap-split B: 48-VGPR live panel -> 3 waves/SIMD) UNION upool ============
// q=5, 4:9 interleave (R15-measured optimum). B reloaded per (pair, tap-group) from L2-resident w2f
// (fragment-packed 1KB wave-loads); #pragma unroll 1 on group loop limits Bf live range to 12 regs x4.
__global__ __launch_bounds__(256) void k_c2up(
    const u16* __restrict__ spool, const u16* __restrict__ w2f, const float* __restrict__ b2,
    const float* __restrict__ g1, const float* __restrict__ be1,
    const float* __restrict__ stats1, const int* __restrict__ im_idx,
    float* __restrict__ segr, float* __restrict__ stats2, int P, float invN1,
    const float* __restrict__ uf, u16* __restrict__ muT){
  __shared__ u16 raw[2*82*128 + 512];      // conv2: inT dbuf + sc1/sh1 | upool: 3136 f32
  int bid = blockIdx.x, t = threadIdx.x;
  int g = bid/9, r9 = bid - g*9;

  if (r9 < 4){
    // ---------- upool: u = g*4 + r9; block (b, icb) pools 64 channels ----------
    float* smem = (float*)raw;
    int u = g*4 + r9;
    int b = u >> 4, icb = u & 15;
    int s0, s1; segrange(im_idx, P, b, s0, s1);
    float inv = 1.f / fmaxf((float)(s1 - s0), 1.f);
    f4v a0 = {}, a1 = {}, a2 = {}, a3 = {};
    int p = s0;
    for (; p + 1 < s1; p += 2){
      const f4v* x = (const f4v*)(uf + (size_t)p*50176 + icb*3136);
      const f4v* y = (const f4v*)(uf + (size_t)(p+1)*50176 + icb*3136);
      a0 += x[t] + y[t]; a1 += x[t+256] + y[t+256]; a2 += x[t+512] + y[t+512];
      if (t < 16) a3 += x[t+768] + y[t+768];
    }
    if (p < s1){
      const f4v* x = (const f4v*)(uf + (size_t)p*50176 + icb*3136);
      a0 += x[t]; a1 += x[t+256]; a2 += x[t+512];
      if (t < 16) a3 += x[t+768];
    }
    *(f4v*)&smem[4*t] = a0;
    *(f4v*)&smem[4*(t+256)] = a1;
    *(f4v*)&smem[4*(t+512)] = a2;
    if (t < 16) *(f4v*)&smem[4*(t+768)] = a3;
    __syncthreads();
    for (int o = t; o < 3136; o += 256){
      int pix = o >> 6, ics = o & 63;
      muT[(size_t)(b*49 + pix)*1024 + (icb<<6) + ics] = f2b(smem[ics*49 + pix]*inv);
    }
    return;
  }

  // ---------- conv2: idx = g*5 + (r9-4); b = idx/20, q = (idx%20)>>2 (0..4), z = idx&3 ----------
  int idx = g*5 + (r9 - 4);
  int b = idx/20, rem = idx - b*20;
  int q = rem >> 2, z = rem & 3;
  float* sc1 = (float*)&raw[2*82*128];
  float* sh1 = sc1 + 128;
  int lane = t & 63, w = t >> 6;
  int l15 = lane & 15, lhi = lane >> 4;
  int og = z*4 + w;                        // this wave's 16-oc group
  int oc = og*16 + l15;
  {
    f4v zv = {}; f4v* a4 = (f4v*)raw;
    for (int i = t; i < 2624; i += 256) a4[i] = zv;
  }
  if (t < 128){                            // folded bnfin1
    float mean = stats1[t]*invN1;
    float var  = stats1[128 + t]*invN1 - mean*mean;
    float sc = g1[t]*rsqrtf(var + 1e-5f);
    sc1[t] = sc; sh1[t] = be1[t] - mean*sc;
  }
  int s0, s1; segrange(im_idx, P, b, s0, s1);
  int cnt = s1 - s0, chunk = (cnt + 4)/5;
  int p0 = s0 + q*chunk, p1 = min(p0 + chunk, s1);
  if (p0 >= p1) return;
  int rowm[4]; bool okm[4];
  #pragma unroll
  for (int mt = 0; mt < 4; ++mt){
    int pix = mt*16 + l15;
    okm[mt] = pix < 49;
    int py = pix/7, px = pix - py*7;
    rowm[mt] = okm[mt] ? (py + 1)*9 + px + 1 : 81;
  }
  float bias = b2[oc];
  f4v segacc[4] = {};
  float ssum = 0.f, ssq = 0.f;
  u32 r13[13];
  const u32* sp32 = (const u32*)spool;
  auto LOADR = [&](int p){
    #pragma unroll
    for (int j = 0; j < 13; ++j){
      int i = j*256 + t;
      r13[j] = (i < 3136) ? sp32[(size_t)p*3136 + i] : 0u;
    }
  };
  auto WRITE = [&](int bb){
    u32* d = (u32*)&raw[bb*82*128];
    #pragma unroll
    for (int j = 0; j < 13; ++j){
      int i = j*256 + t;
      if (i < 3136){
        int pix = i >> 6, icp = i & 63;
        u32 v = r13[j];
        float lo = b2f((u16)v)*sc1[icp*2]          + sh1[icp*2];
        float hi = b2f((u16)(v >> 16))*sc1[icp*2+1] + sh1[icp*2+1];
        int py = pix/7;
        int row = (py + 1)*9 + (pix - py*7) + 1;
        d[(row*64 + icp) ^ ((row & 7) << 2)] = (u32)f2b(lo) | ((u32)f2b(hi) << 16);
      }
    }
  };
  LOADR(p0);
  __syncthreads();                         // zero-init + sc1 visible before first WRITE
  WRITE(0);
  int cur = 0;
  for (int p = p0; p < p1; ++p){
    __syncthreads();                       // buf[cur] writes visible to all
    if (p + 1 < p1) LOADR(p + 1);          // issue global prefetch: hides under MFMA
    f4v pacc[4] = {};
    const u16* buf = &raw[cur*82*128];
    #pragma unroll 1
    for (int tg = 0; tg < 3; ++tg){        // tap-group loop NOT unrolled: Bf live range = 48 VGPR
      s8v Bf[3][4];
      #pragma unroll
      for (int tt = 0; tt < 3; ++tt)
        #pragma unroll
        for (int kst = 0; kst < 4; ++kst)
          Bf[tt][kst] = *(const s8v*)&w2f[((((size_t)(tg*3 + tt)*16 + og)*4 + kst) << 9) + lane*8];
      #pragma unroll
      for (int tt = 0; tt < 3; ++tt){
        int doff = tg*9 + tt - 10;         // = (tap/3 - 1)*9 + (tap%3 - 1), tap = tg*3 + tt
        int rr[4];
        #pragma unroll
        for (int mt = 0; mt < 4; ++mt)
          rr[mt] = okm[mt] ? rowm[mt] + doff : 81;
        #pragma unroll
        for (int kst = 0; kst < 4; ++kst){
          int koff = kst*32 + lhi*8;
          #pragma unroll
          for (int mt = 0; mt < 4; ++mt){
            s8v A = *(const s8v*)&buf[(rr[mt]*128 + koff) ^ ((rr[mt] & 7) << 3)];
            pacc[mt] = mfma16(A, Bf[tt][kst], pacc[mt]);
          }
        }
      }
    }
    #pragma unroll
    for (int mt = 0; mt < 4; ++mt)
      #pragma unroll
      for (int v = 0; v < 4; ++v){
        int pix = mt*16 + lhi*4 + v;
        float r = fmaxf(pacc[mt][v] + bias, 0.f);
        r = (pix < 49) ? r : 0.f;
        segacc[mt][v] += r;
        ssum += r; ssq += r*r;
      }
    if (p + 1 < p1) WRITE(cur ^ 1);        // other buffer: safe, readers passed barrier
    cur ^= 1;
  }
  #pragma unroll
  for (int mt = 0; mt < 4; ++mt)
    #pragma unroll
    for (int v = 0; v < 4; ++v){
      int pix = mt*16 + lhi*4 + v;
      if (pix < 49)
        atomicAdd(&segr[(size_t)(b*256 + oc)*49 + pix], segacc[mt][v]);
    }
  float s = ssum, qd = ssq;
  s  += __shfl_xor(s, 16);  s  += __shfl_xor(s, 32);
  qd += __shfl_xor(qd, 16); qd += __shfl_xor(qd, 32);
  if (lane < 16){
    atomicAdd(&stats2[og*16 + lane], s);
    atomicAdd(&stats2[256 + og*16 + lane], qd);
  }
}

// ============ combine: union 1x1 conv + bn2(seg-mean relu2) -> tbf ============
__global__ __launch_bounds__(256) void k_combine(const u16* __restrict__ muT, const u16* __restrict__ wuT,
                                                 const float* __restrict__ b_u, const float* __restrict__ segr,
                                                 const float* __restrict__ stats2,
                                                 const float* __restrict__ g2, const float* __restrict__ be2,
                                                 const int* __restrict__ im_idx, u16* __restrict__ tbf,
                                                 int P, float invN2){
  __shared__ float sc2[256], sh2[256];
  int b = blockIdx.x, t = threadIdx.x;
  int lane = t & 63, w = t >> 6;
  int l15 = lane & 15, lhi = lane >> 4;
  {
    float mean = stats2[t]*invN2;
    float var  = stats2[256 + t]*invN2 - mean*mean;
    float sc = g2[t]*rsqrtf(var + 1e-5f);
    sc2[t] = sc; sh2[t] = be2[t] - mean*sc;
  }
  __syncthreads();
  int s0, s1; segrange(im_idx, P, b, s0, s1);
  float inv = 1.f / fmaxf((float)(s1 - s0), 1.f);
  int ocb = w*64;
  const u16* arow[4];
  #pragma unroll
  for (int mt = 0; mt < 4; ++mt){
    int pix = mt*16 + l15;
    arow[mt] = muT + (size_t)(b*49 + (pix < 49 ? pix : 0))*1024;
  }
  f4v acc[4][4] = {};
  for (int kst = 0; kst < 32; ++kst){
    int koff = kst*32 + lhi*8;
    s8v Bf[4];
    #pragma unroll
    for (int nt = 0; nt < 4; ++nt)
      Bf[nt] = *(const s8v*)&wuT[(ocb + nt*16 + l15)*1024 + koff];
    #pragma unroll
    for (int mt = 0; mt < 4; ++mt){
      s8v A = *(const s8v*)&arow[mt][koff];
      #pragma unroll
      for (int nt = 0; nt < 4; ++nt)
        acc[mt][nt] = mfma16(A, Bf[nt], acc[mt][nt]);
    }
  }
  #pragma unroll
  for (int nt = 0; nt < 4; ++nt){
    int oc = ocb + nt*16 + l15;
    float bu = b_u[oc], sc = sc2[oc], sh = sh2[oc];
    #pragma unroll
    for (int mt = 0; mt < 4; ++mt)
      #pragma unroll
      for (int v = 0; v < 4; ++v){
        int pix = mt*16 + lhi*4 + v;
        if (pix < 49){
          float val = acc[mt][nt][v] + bu + sc*segr[(size_t)(b*256 + oc)*49 + pix]*inv + sh;
          tbf[(size_t)b*12544 + oc*49 + pix] = f2b(val);
        }
      }
  }
}

// ============ mega3: vr GEMM (56 blocks) UNION subj/obj GEMM (16 blocks) ============
__global__ __launch_bounds__(256) void k_mega3(const u16* __restrict__ tbf, const u16* __restrict__ wvrT,
                                               const float* __restrict__ b_vr,
                                               const u16* __restrict__ pfbf, const u16* __restrict__ wsoT,
                                               const float* __restrict__ b_subj, const float* __restrict__ b_obj,
                                               float* __restrict__ px, int B){
  int bid = blockIdx.x, t = threadIdx.x;
  int lane = t & 63, w = t >> 6;
  int l15 = lane & 15, lhi = lane >> 4;
  if (bid < 56){
    int nb = bid & 1, kc = bid >> 1;
    int colb = nb*256 + w*64;
    int k0 = kc*448;
    f4v acc[7][4] = {};
    for (int kst = 0; kst < 14; ++kst){
      int koff = k0 + kst*32 + lhi*8;
      s8v Bf[4];
      #pragma unroll
      for (int nt = 0; nt < 4; ++nt)
        Bf[nt] = *(const s8v*)&wvrT[(size_t)(colb + nt*16 + l15)*12544 + koff];
      #pragma unroll
      for (int mt = 0; mt < 7; ++mt){
        s8v A = *(const s8v*)&tbf[(size_t)(mt*16 + l15)*12544 + koff];
        #pragma unroll
        for (int nt = 0; nt < 4; ++nt)
          acc[mt][nt] = mfma16(A, Bf[nt], acc[mt][nt]);
      }
    }
    #pragma unroll
    for (int nt = 0; nt < 4; ++nt){
      int col = colb + nt*16 + l15;
      float bias = (kc == 0) ? b_vr[col] : 0.f;
      #pragma unroll
      for (int mt = 0; mt < 7; ++mt)
        #pragma unroll
        for (int v = 0; v < 4; ++v){
          int row = mt*16 + lhi*4 + v;
          if (row < B) atomicAdd(&px[row*1536 + 1024 + col], acc[mt][nt][v] + bias);
        }
    }
  } else {
    int r = bid - 56;
    int nb = r & 1, s = (r >> 1) & 1, kc = r >> 2;
    int colb = nb*256 + w*64;
    int k0 = kc*512;
    const float* bi = s ? b_obj : b_subj;
    f4v acc[7][4] = {};
    for (int kst = 0; kst < 16; ++kst){
      int koff = k0 + kst*32 + lhi*8;
      s8v Bf[4];
      #pragma unroll
      for (int nt = 0; nt < 4; ++nt)
        Bf[nt] = *(const s8v*)&wsoT[(size_t)(s*512 + colb + nt*16 + l15)*2048 + koff];
      #pragma unroll
      for (int mt = 0; mt < 7; ++mt){
        int row = mt*16 + l15; row = row < B ? row : 0;
        s8v A = *(const s8v*)&pfbf[(size_t)(s*100 + row)*2048 + koff];
        #pragma unroll
        for (int nt = 0; nt < 4; ++nt)
          acc[mt][nt] = mfma16(A, Bf[nt], acc[mt][nt]);
      }
    }
    #pragma unroll
    for (int nt = 0; nt < 4; ++nt){
      int col = colb + nt*16 + l15;
      float bias = (kc == 0) ? bi[col] : 0.f;
      #pragma unroll
      for (int mt = 0; mt < 7; ++mt)
        #pragma unroll
        for (int v = 0; v < 4; ++v){
          int row = mt*16 + lhi*4 + v;
          if (row < B) atomicAdd(&px[row*1536 + s*512 + col], acc[mt][nt][v] + bias);
        }
    }
  }
}

// ============ MLP m1: [112,1536]@[1536,2048], k-split atomics, f32 A inline-cast ============
__global__ __launch_bounds__(256) void k_m1(const float* __restrict__ px, const u16* __restrict__ wm1T,
                                            float* __restrict__ h, int B){
  int nb = blockIdx.x, kc = blockIdx.y, t = threadIdx.x;
  int lane = t & 63, w = t >> 6;
  int l15 = lane & 15, lhi = lane >> 4;
  int colb = nb*256 + w*64;
  int k0 = kc*384;
  f4v acc[7][4] = {};
  for (int kst = 0; kst < 12; ++kst){
    int koff = k0 + kst*32 + lhi*8;
    s8v Bf[4];
    #pragma unroll
    for (int nt = 0; nt < 4; ++nt)
      Bf[nt] = *(const s8v*)&wm1T[(size_t)(colb + nt*16 + l15)*1536 + koff];
    #pragma unroll
    for (int mt = 0; mt < 7; ++mt){
      const float* ap = px + (size_t)(mt*16 + l15)*1536 + koff;
      f4v lo = *(const f4v*)ap;
      f4v hi = *(const f4v*)(ap + 4);
      s8v A;
      A[0] = (short)f2b(lo[0]); A[1] = (short)f2b(lo[1]);
      A[2] = (short)f2b(lo[2]); A[3] = (short)f2b(lo[3]);
      A[4] = (short)f2b(hi[0]); A[5] = (short)f2b(hi[1]);
      A[6] = (short)f2b(hi[2]); A[7] = (short)f2b(hi[3]);
      #pragma unroll
      for (int nt = 0; nt < 4; ++nt)
        acc[mt][nt] = mfma16(A, Bf[nt], acc[mt][nt]);
    }
  }
  #pragma unroll
  for (int nt = 0; nt < 4; ++nt){
    int col = colb + nt*16 + l15;
    #pragma unroll
    for (int mt = 0; mt < 7; ++mt)
      #pragma unroll
      for (int v = 0; v < 4; ++v){
        int row = mt*16 + lhi*4 + v;
        if (row < B) atomicAdd(&h[row*2048 + col], acc[mt][nt][v]);
      }
  }
}

// ============ m2 + bias1/relu + sigmoid, in-block k-split x2 ============
__global__ __launch_bounds__(512) void k_m2(const float* __restrict__ h, const float* __restrict__ bm1,
                                            const float* __restrict__ w_m2, const float* __restrict__ b_m2,
                                            float* __restrict__ out){
  __shared__ float part[160];
  int b = blockIdx.x, t = threadIdx.x;
  int col = t & 255, kg = t >> 8;
  float acc = 0.f;
  if (col < 157){
    const float* hb = h + (size_t)b*2048;
    int k0 = kg*1024;
    for (int k = k0; k < k0 + 1024; ++k)
      acc += fmaxf(hb[k] + bm1[k], 0.f) * w_m2[(size_t)k*157 + col];
  }
  if (kg == 1 && col < 157) part[col] = acc;
  __syncthreads();
  if (kg == 0 && col < 157){
    float s = acc + part[col] + b_m2[col];
    out[b*157 + col] = 1.f/(1.f + expf(-s));
  }
}

extern "C" void kernel_launch(void* const* d_in, const int* in_sizes, int n_in,
                              void* d_out, int out_size, void* d_ws, size_t ws_size,
                              hipStream_t stream){
  const float* features   = (const float*)d_in[0];
  const float* union_feat = (const float*)d_in[1];
  const float* masks      = (const float*)d_in[2];
  const float* w_union    = (const float*)d_in[3];
  const float* b_union    = (const float*)d_in[4];
  const float* w_c1       = (const float*)d_in[5];
  const float* b_c1       = (const float*)d_in[6];
  const float* g_bn1      = (const float*)d_in[7];
  const float* be_bn1     = (const float*)d_in[8];
  const float* w_c2       = (const float*)d_in[9];
  const float* b_c2       = (const float*)d_in[10];
  const float* g_bn2      = (const float*)d_in[11];
  const float* be_bn2     = (const float*)d_in[12];
  const float* w_subj     = (const float*)d_in[13];
  const float* b_subj     = (const float*)d_in[14];
  const float* w_obj      = (const float*)d_in[15];
  const float* b_obj      = (const float*)d_in[16];
  const float* w_vr       = (const float*)d_in[17];
  const float* b_vr       = (const float*)d_in[18];
  const float* w_m1       = (const float*)d_in[19];
  const float* b_m1       = (const float*)d_in[20];
  const float* w_m2       = (const float*)d_in[21];
  const float* b_m2       = (const float*)d_in[22];
  const int* pair_idx     = (const int*)d_in[23];
  const int* im_idx       = (const int*)d_in[24];
  float* out = (float*)d_out;
  const int P = in_sizes[24];
  const int B = out_size/157;

  char* ws = (char*)d_ws;
  size_t off = 0;
  auto alloc = [&](size_t bytes)->size_t{ size_t o = off; off += (bytes + 255) & ~(size_t)255; return o; };
  // zero-region (one memset): stats | segr | px | h
  size_t o_stats= alloc(3072);
  size_t o_segr = alloc((size_t)B*256*49*4);
  size_t o_px   = alloc((size_t)112*1536*4);
  size_t o_h    = alloc((size_t)B*2048*4);
  size_t zero_end = off;
  size_t o_muT  = alloc((size_t)B*49*1024*2);
  size_t o_spool= alloc((size_t)P*49*128*2);
  size_t o_w2f  = alloc(9*256*128*2);
  size_t o_wuT  = alloc(256*1024*2);
  size_t o_wvrT = alloc((size_t)512*12544*2);
  size_t o_wm1T = alloc((size_t)2048*1536*2);
  size_t o_wsoT = alloc((size_t)1024*2048*2);
  size_t o_pfbf = alloc((size_t)200*2048*2);
  size_t o_tbf  = alloc((size_t)112*12544*2);
  (void)ws_size; (void)n_in;

  float* stats1 = (float*)(ws + o_stats);
  float* stats2 = stats1 + 256;
  u16*   muT    = (u16*)(ws + o_muT);
  u16*   spool  = (u16*)(ws + o_spool);
  u16*   w2f    = (u16*)(ws + o_w2f);
  u16*   wuT    = (u16*)(ws + o_wuT);
  u16*   wvrT   = (u16*)(ws + o_wvrT);
  u16*   wm1T   = (u16*)(ws + o_wm1T);
  u16*   wsoT   = (u16*)(ws + o_wsoT);
  u16*   pfbf   = (u16*)(ws + o_pfbf);
  float* segr   = (float*)(ws + o_segr);
  u16*   tbf    = (u16*)(ws + o_tbf);
  float* px     = (float*)(ws + o_px);
  float* h      = (float*)(ws + o_h);

  hipMemsetAsync(ws, 0, zero_end, stream);

  k_misc<<<2*P + 5224, dim3(256), 0, stream>>>(features, pair_idx, im_idx, w_c1, w_c2, w_union,
                                               w_vr, w_m1, w_subj, w_obj,
                                               masks, b_c1, stats1, spool,
                                               w2f, wuT, wvrT, wm1T, wsoT, pfbf, P);
  k_c2up<<<3600, dim3(256), 0, stream>>>(spool, w2f, b_c2, g_bn1, be_bn1, stats1, im_idx,
                                         segr, stats2, P, 1.f/((float)P*196.f),
                                         union_feat, muT);
  k_combine<<<B, dim3(256), 0, stream>>>(muT, wuT, b_union, segr, stats2, g_bn2, be_bn2, im_idx,
                                         tbf, P, 1.f/((float)P*49.f));
  k_mega3<<<72, dim3(256), 0, stream>>>(tbf, wvrT, b_vr, pfbf, wsoT, b_subj, b_obj, px, B);
  k_m1<<<dim3(8, 4), dim3(256), 0, stream>>>(px, wm1T, h, B);
  k_m2<<<B, dim3(512), 0, stream>>>(h, b_m1, w_m2, b_m2, out);
}